// Round 6
// baseline (422.319 us; speedup 1.0000x reference)
//
#include <hip/hip_runtime.h>

#define DEVI __device__ __forceinline__

typedef __attribute__((ext_vector_type(8))) short short8v;
typedef __attribute__((ext_vector_type(4))) float f32x4;

DEVI float blo(unsigned u){ return __uint_as_float(u << 16); }
DEVI float bhi(unsigned u){ return __uint_as_float(u & 0xffff0000u); }
DEVI unsigned short f2bu(float f){          // f32 -> bf16 bits, RNE
  unsigned u = __float_as_uint(f);
  return (unsigned short)((u + 0x7fffu + ((u >> 16) & 1u)) >> 16);
}

// ---------------------------------------------------------------------------
// CSR build, batched over the 6 relations (all have exactly E edges).
// ---------------------------------------------------------------------------
struct CsrArgs {
  const int* src[6];
  const int* dst[6];
  int* cnt[6];
  int* offs[6];
  int* cur[6];
  int* csr[6];
  int  N[6];
};

__global__ __launch_bounds__(256)
void hist_all(CsrArgs a, int E, int ebks) {
  int r = blockIdx.x / ebks;
  int base = (blockIdx.x - r * ebks) * 1024 + threadIdx.x;
  const int* dst = a.dst[r];
  int* cnt = a.cnt[r];
#pragma unroll
  for (int k = 0; k < 4; ++k) {
    int e = base + k * 256;
    if (e < E) atomicAdd(&cnt[dst[e]], 1);
  }
}

__global__ __launch_bounds__(1024)
void scan_all(CsrArgs a) {
  __shared__ int psum[1024];
  int r = blockIdx.x;
  int N = a.N[r];
  const int* cnt = a.cnt[r];
  int* offs = a.offs[r];
  int t = threadIdx.x;
  int K = (N + 1023) / 1024;
  int i0 = t * K, i1 = min(i0 + K, N);
  int s = 0;
  for (int i = i0; i < i1; ++i) s += cnt[i];
  psum[t] = s;
  __syncthreads();
  for (int d = 1; d < 1024; d <<= 1) {
    int v = (t >= d) ? psum[t - d] : 0;
    __syncthreads();
    psum[t] += v;
    __syncthreads();
  }
  int run = (t == 0) ? 0 : psum[t - 1];
  for (int i = i0; i < i1; ++i) { offs[i] = run; run += cnt[i]; }
  if (t == 1023) offs[N] = run;
}

__global__ __launch_bounds__(256)
void scatter_all(CsrArgs a, int E, int ebks) {
  int r = blockIdx.x / ebks;
  int base = (blockIdx.x - r * ebks) * 1024 + threadIdx.x;
  const int* dst = a.dst[r];
  const int* src = a.src[r];
  const int* offs = a.offs[r];
  int* cur = a.cur[r];
  int* csr = a.csr[r];
#pragma unroll
  for (int k = 0; k < 4; ++k) {
    int e = base + k * 256;
    if (e < E) {
      int d = dst[e];
      int pos = atomicAdd(&cur[d], 1);
      csr[offs[d] + pos] = src[e];
    }
  }
}

// ---------------------------------------------------------------------------
// prep: per relation fold W@ar -> war and W@al -> wal (both [128][H]); convert
// W to bf16 in MFMA B-fragment order Wz[kc][c][j] (kc=k/8, j=k%8); combine
// biases. Blocks 0-5: layer1 rels; 6-8: layer2 rels (w = 0,5,4); 9: biases.
// ---------------------------------------------------------------------------
__global__ __launch_bounds__(256)
void prep(const float* __restrict__ W1, const float* __restrict__ al1,
          const float* __restrict__ ar1, const float* __restrict__ b1,
          const float* __restrict__ W2, const float* __restrict__ al2,
          const float* __restrict__ ar2, const float* __restrict__ b2,
          unsigned short* __restrict__ Wz1, unsigned short* __restrict__ Wz2,
          float* __restrict__ war1, float* __restrict__ wal1,
          float* __restrict__ war2, float* __restrict__ wal2,
          float* __restrict__ bcomb)
{
  int b = blockIdx.x, t = threadIdx.x;
  if (b < 6) {
    const float* W = W1 + b * 16384;
    unsigned short* Wz = Wz1 + b * 16384;
    for (int i = t; i < 16384; i += 256) {
      int j = i & 7, c = (i >> 3) & 127, kc = i >> 10;
      Wz[i] = f2bu(W[(kc * 8 + j) * 128 + c]);
    }
    for (int i = t; i < 512; i += 256) {
      int k = i >> 2, h = i & 3;
      float sr = 0.f, sl = 0.f;
      for (int f = 0; f < 32; ++f) {
        float w = W[k * 128 + h * 32 + f];
        sr += w * ar1[b * 128 + h * 32 + f];
        sl += w * al1[b * 128 + h * 32 + f];
      }
      war1[b * 512 + i] = sr;
      wal1[b * 512 + i] = sl;
    }
  } else if (b < 9) {
    int w = (b == 6) ? 0 : (b == 7) ? 5 : 4;
    const float* W = W2 + w * 8192;
    unsigned short* Wz = Wz2 + (b - 6) * 8192;
    for (int i = t; i < 8192; i += 256) {
      int j = i & 7, c = (i >> 3) & 63, kc = i >> 9;
      Wz[i] = f2bu(W[(kc * 8 + j) * 64 + c]);
    }
    if (t < 128) {
      float sr = 0.f, sl = 0.f;
      for (int f = 0; f < 64; ++f) {
        float x = W[t * 64 + f];
        sr += x * ar2[w * 64 + f];
        sl += x * al2[w * 64 + f];
      }
      war2[(b - 6) * 128 + t] = sr;
      wal2[(b - 6) * 128 + t] = sl;
    }
  } else {
    if (t < 128) {
      bcomb[t]       = b1[128 + t] + b1[256 + t] + b1[384 + t]; // user
      bcomb[128 + t] = b1[t] + b1[640 + t];                     // artist
      bcomb[256 + t] = b1[512 + t];                             // tag
    } else if (t < 192) {
      int x = t - 128;
      bcomb[384 + x] = b2[x] + b2[320 + x];                     // h2 artist
      bcomb[448 + x] = b2[256 + x];                             // h2 tag
    }
  }
}

// ---------------------------------------------------------------------------
// MFMA projection GEMM, batched over relations. Z[N,KOUT] = A[N,128] @ W.
// Block: 256 thr = 4 waves, 64-row tile, wave w owns cols [w*16*NCT, ...).
// A: f32 -> bf16 into LDS with 16B-chunk XOR swizzle (conflict-free reads).
// W: pre-swizzled bf16 frags (one dwordx4 per lane per frag), L1-resident.
// mfma_f32_16x16x32_bf16: A row=lane&15, k=(lane>>4)*8+j; B col=lane&15;
// C/D col=lane&15, row=(lane>>4)*4+reg.
// ---------------------------------------------------------------------------
struct GemmM {
  const float* A[6];
  const unsigned short* Wz[6];
  unsigned short* Z[6];
  int N[6];
  int pre[6];
};

template<int KOUT>
__global__ __launch_bounds__(256)
void gemm_mfma(GemmM g)
{
  constexpr int NCT = KOUT / 64;     // col-tiles per wave
  int r = 0;
#pragma unroll
  for (int i = 1; i < 6; ++i) if ((int)blockIdx.x >= g.pre[i]) r = i;
  const float* A = g.A[r];
  const short8v* Wp = (const short8v*)g.Wz[r];
  unsigned short* Z = g.Z[r];
  const int N = g.N[r];
  const int row0 = (blockIdx.x - g.pre[r]) * 64;

  __shared__ short8v a_lds[64 * 16];   // 64 rows x 128 bf16, chunk-XOR swizzled
  for (int i = threadIdx.x; i < 64 * 16; i += 256) {
    int row = i >> 4, c8 = i & 15;
    int grow = row0 + row;
    short8v v;
    if (grow < N) {
      const float4* ap = (const float4*)(A + (size_t)grow * 128 + c8 * 8);
      float4 x0 = ap[0], x1 = ap[1];
      v[0] = (short)f2bu(x0.x); v[1] = (short)f2bu(x0.y);
      v[2] = (short)f2bu(x0.z); v[3] = (short)f2bu(x0.w);
      v[4] = (short)f2bu(x1.x); v[5] = (short)f2bu(x1.y);
      v[6] = (short)f2bu(x1.z); v[7] = (short)f2bu(x1.w);
    } else {
      v = short8v{0, 0, 0, 0, 0, 0, 0, 0};
    }
    a_lds[row * 16 + (c8 ^ (row & 7))] = v;
  }
  __syncthreads();

  const int wv = threadIdx.x >> 6;
  const int lane = threadIdx.x & 63;
  const int lrow = lane & 15, lkg = lane >> 4;

  f32x4 acc[4][NCT];
#pragma unroll
  for (int rt = 0; rt < 4; ++rt)
#pragma unroll
    for (int c = 0; c < NCT; ++c) acc[rt][c] = f32x4{0.f, 0.f, 0.f, 0.f};

#pragma unroll
  for (int ks = 0; ks < 4; ++ks) {
    const int kc = ks * 4 + lkg;
    short8v bfr[NCT];
#pragma unroll
    for (int c = 0; c < NCT; ++c)
      bfr[c] = Wp[kc * KOUT + (wv * NCT + c) * 16 + lrow];
#pragma unroll
    for (int rt = 0; rt < 4; ++rt) {
      int row = rt * 16 + lrow;
      short8v afr = a_lds[row * 16 + (kc ^ (row & 7))];
#pragma unroll
      for (int c = 0; c < NCT; ++c)
        acc[rt][c] = __builtin_amdgcn_mfma_f32_16x16x32_bf16(afr, bfr[c], acc[rt][c], 0, 0, 0);
    }
  }

#pragma unroll
  for (int rt = 0; rt < 4; ++rt)
#pragma unroll
    for (int c = 0; c < NCT; ++c) {
      int col = (wv * NCT + c) * 16 + lrow;
#pragma unroll
      for (int q = 0; q < 4; ++q) {
        int grow = row0 + rt * 16 + lkg * 4 + q;
        if (grow < N) Z[(size_t)grow * KOUT + col] = f2bu(acc[rt][c][q]);
      }
    }
}

// ---------------------------------------------------------------------------
// node_dots: el[r][n,h] = X[n,:128] . wal_r[:,h]  (wave per node, batched
// over up to 3 tasks x up to 3 relations each).
// ---------------------------------------------------------------------------
struct DotB {
  const float* X[3];
  const float* wal[3][3];
  float* el[3][3];
  int NR[3];
  int N[3];
  int pre[3];
};

template<int H>
__global__ __launch_bounds__(256)
void node_dots(DotB g)
{
  int task = 0;
#pragma unroll
  for (int i = 1; i < 3; ++i) if ((int)blockIdx.x >= g.pre[i]) task = i;
  int n = (blockIdx.x - g.pre[task]) * 4 + (threadIdx.x >> 6);
  if (n >= g.N[task]) return;
  int lane = threadIdx.x & 63;
  float2 f2 = ((const float2*)(g.X[task] + (size_t)n * 128))[lane];
  int NR = g.NR[task];
  for (int rr = 0; rr < NR; ++rr) {
    const float* wal = g.wal[task][rr];
    float* el = g.el[task][rr];
#pragma unroll
    for (int h = 0; h < H; ++h) {
      float v = f2.x * wal[(2 * lane) * H + h] + f2.y * wal[(2 * lane + 1) * H + h];
#pragma unroll
      for (int m = 1; m < 64; m <<= 1) v += __shfl_xor(v, m, 64);
      if (lane == 0) el[n * H + h] = v;
    }
  }
}

// ---------------------------------------------------------------------------
// Fused multi-relation CSR aggregation (unchanged from round 5).
// ---------------------------------------------------------------------------
struct AggP {
  const int* offs[3];
  const int* csr[3];
  const float* el[3];
  const unsigned short* zs[3];
  const float* war[3];
  const float* bias;
  const float* dfeat;
  float* out;
  int Nd;
};

template<int H, int CPL, int NR>
__global__ __launch_bounds__(256)
void agg_multi(AggP a)
{
  constexpr int ELEMS = 64 * CPL;
  constexpr int F = ELEMS / H;
  __shared__ float war_s[NR * 128 * H];
  for (int i = threadIdx.x; i < NR * 128 * H; i += 256) {
    int rr = i / (128 * H);
    war_s[i] = a.war[rr][i - rr * 128 * H];
  }
  __syncthreads();
  const int lane = threadIdx.x & 63;
  const int n = blockIdx.x * 4 + (threadIdx.x >> 6);
  if (n >= a.Nd) return;

  float2 f2 = ((const float2*)(a.dfeat + (size_t)n * 128))[lane];
  const int hlane = (CPL * lane) / F;
  float vout[CPL];
#pragma unroll
  for (int j = 0; j < CPL; ++j) vout[j] = a.bias[CPL * lane + j];

#pragma unroll
  for (int r = 0; r < NR; ++r) {
    const float* ws = war_s + r * 128 * H;
    float er[H];
#pragma unroll
    for (int h = 0; h < H; ++h) {
      float v = f2.x * ws[(2 * lane) * H + h] + f2.y * ws[(2 * lane + 1) * H + h];
#pragma unroll
      for (int m = 1; m < 64; m <<= 1) v += __shfl_xor(v, m, 64);
      er[h] = v;
    }
    float erl = er[0];
#pragma unroll
    for (int h = 1; h < H; ++h) erl = (lane == h) ? er[h] : erl;

    const float* el = a.el[r];
    const int* csr = a.csr[r];
    float accA[CPL], accB[CPL];
#pragma unroll
    for (int j = 0; j < CPL; ++j) { accA[j] = 0.f; accB[j] = 0.f; }
    float denA = 0.f, denB = 0.f;
    const int e0 = a.offs[r][n], e1 = a.offs[r][n + 1];
    for (int eb = e0; eb < e1; eb += 64) {
      int sv = (eb + lane < e1) ? csr[eb + lane] : 0;
      int m = min(64, e1 - eb);
      int j = 0;
      for (; j + 2 <= m; j += 2) {
        int s0 = __shfl(sv, j, 64), s1 = __shfl(sv, j + 1, 64);
        float ex0 = 0.f, ex1 = 0.f;
        if (lane < H) {
          float v0 = el[s0 * H + lane] + erl;
          v0 = v0 > 0.f ? v0 : 0.2f * v0;
          ex0 = __expf(v0); denA += ex0;
          float v1 = el[s1 * H + lane] + erl;
          v1 = v1 > 0.f ? v1 : 0.2f * v1;
          ex1 = __expf(v1); denB += ex1;
        }
        float eh0 = __shfl(ex0, hlane, 64);
        float eh1 = __shfl(ex1, hlane, 64);
        if (CPL == 2) {
          unsigned z0 = ((const unsigned*)a.zs[r])[(size_t)s0 * (ELEMS / 2) + lane];
          unsigned z1 = ((const unsigned*)a.zs[r])[(size_t)s1 * (ELEMS / 2) + lane];
          accA[0] += eh0 * blo(z0); accA[CPL - 1] += eh0 * bhi(z0);
          accB[0] += eh1 * blo(z1); accB[CPL - 1] += eh1 * bhi(z1);
        } else {
          unsigned z0 = ((const unsigned short*)a.zs[r])[(size_t)s0 * ELEMS + lane];
          unsigned z1 = ((const unsigned short*)a.zs[r])[(size_t)s1 * ELEMS + lane];
          accA[0] += eh0 * blo(z0);
          accB[0] += eh1 * blo(z1);
        }
      }
      for (; j < m; ++j) {
        int s0 = __shfl(sv, j, 64);
        float ex0 = 0.f;
        if (lane < H) {
          float v0 = el[s0 * H + lane] + erl;
          v0 = v0 > 0.f ? v0 : 0.2f * v0;
          ex0 = __expf(v0); denA += ex0;
        }
        float eh0 = __shfl(ex0, hlane, 64);
        if (CPL == 2) {
          unsigned z0 = ((const unsigned*)a.zs[r])[(size_t)s0 * (ELEMS / 2) + lane];
          accA[0] += eh0 * blo(z0); accA[CPL - 1] += eh0 * bhi(z0);
        } else {
          unsigned z0 = ((const unsigned short*)a.zs[r])[(size_t)s0 * ELEMS + lane];
          accA[0] += eh0 * blo(z0);
        }
      }
    }
#pragma unroll
    for (int j = 0; j < CPL; ++j) {
      int x = CPL * lane + j;
      float dd = __shfl(denA + denB, x / F, 64);
      if (dd > 0.f) vout[j] += (accA[j] + accB[j]) / dd;
    }
  }
  if (CPL == 2) {
    float2 o; o.x = vout[0]; o.y = vout[CPL - 1];
    ((float2*)(a.out + (size_t)n * ELEMS))[lane] = o;
  } else {
    a.out[(size_t)n * ELEMS + lane] = vout[0];
  }
}

// ---------------------------------------------------------------------------
// Predictor: 16 lanes per edge, coalesced float4 row loads, shfl reduce.
// ---------------------------------------------------------------------------
__global__ __launch_bounds__(256)
void pred_dot(const float* __restrict__ h2a, const float* __restrict__ h2t,
              const int* __restrict__ ps, const int* __restrict__ pd,
              const int* __restrict__ ns, const int* __restrict__ nd,
              float* __restrict__ out, int Ep, int En)
{
  int t = blockIdx.x * 256 + threadIdx.x;
  int e = t >> 4, q = t & 15;
  if (e >= Ep + En) return;
  int s, d;
  if (e < Ep) { s = ps[e]; d = pd[e]; }
  else        { s = ns[e - Ep]; d = nd[e - Ep]; }
  float4 a = ((const float4*)(h2a + (size_t)s * 64))[q];
  float4 b = ((const float4*)(h2t + (size_t)d * 64))[q];
  float v = a.x * b.x + a.y * b.y + a.z * b.z + a.w * b.w;
  v += __shfl_xor(v, 8, 64);
  v += __shfl_xor(v, 4, 64);
  v += __shfl_xor(v, 2, 64);
  v += __shfl_xor(v, 1, 64);
  if (q == 0) out[e] = v;
}

// ---------------------------------------------------------------------------
extern "C" void kernel_launch(void* const* d_in, const int* in_sizes, int n_in,
                              void* d_out, int out_size, void* d_ws, size_t ws_size,
                              hipStream_t stream)
{
  (void)n_in; (void)out_size; (void)ws_size;
  const float* fUser = (const float*)d_in[0];
  const float* fArt  = (const float*)d_in[1];
  const float* fTag  = (const float*)d_in[2];
  const float* W1  = (const float*)d_in[3];
  const float* al1 = (const float*)d_in[4];
  const float* ar1 = (const float*)d_in[5];
  const float* b1  = (const float*)d_in[6];
  const float* W2  = (const float*)d_in[7];
  const float* al2 = (const float*)d_in[8];
  const float* ar2 = (const float*)d_in[9];
  const float* b2  = (const float*)d_in[10];
  const int* ix[14];
  for (int i = 0; i < 14; ++i) ix[i] = (const int*)d_in[11 + i];

  const int NU = in_sizes[0] / 128;
  const int NA = in_sizes[1] / 128;
  const int NT = in_sizes[2] / 128;
  const int E  = in_sizes[11];
  const int EN = in_sizes[23];

  char* p = (char*)d_ws;
  auto alloc = [&](size_t bytes) -> char* {
    char* r = p; p += (bytes + 255) & ~(size_t)255; return r;
  };

  const int dN1[6] = {NA, NU, NU, NU, NT, NA};
  const int sN1[6] = {NU, NA, NU, NU, NA, NT};
  const int sN2[3] = {NU, NT, NA};

  // ---- zero-init region: CSR counters + cursors ----
  char* zbase = p;
  CsrArgs ca;
  for (int r = 0; r < 6; ++r) ca.cnt[r] = (int*)alloc((size_t)dN1[r] * 4);
  for (int r = 0; r < 6; ++r) ca.cur[r] = (int*)alloc((size_t)dN1[r] * 4);
  size_t zbytes = (size_t)(p - zbase);

  // ---- non-zero scratch ----
  int* offs[6]; int* csr[6];
  for (int r = 0; r < 6; ++r) {
    offs[r] = (int*)alloc(((size_t)dN1[r] + 1) * 4);
    csr[r]  = (int*)alloc((size_t)E * 4);
    ca.src[r] = ix[2 * r]; ca.dst[r] = ix[2 * r + 1];
    ca.offs[r] = offs[r]; ca.csr[r] = csr[r]; ca.N[r] = dN1[r];
  }
  unsigned short* Wz1 = (unsigned short*)alloc(6 * 16384 * 2);
  unsigned short* Wz2 = (unsigned short*)alloc(3 * 8192 * 2);
  float* war1  = (float*)alloc(6 * 512 * 4);
  float* wal1  = (float*)alloc(6 * 512 * 4);
  float* war2  = (float*)alloc(3 * 128 * 4);
  float* wal2  = (float*)alloc(3 * 128 * 4);
  float* bcomb = (float*)alloc(512 * 4);
  unsigned short* zs1[6]; float* el1[6];
  for (int r = 0; r < 6; ++r) {
    zs1[r] = (unsigned short*)alloc((size_t)sN1[r] * 128 * 2);
    el1[r] = (float*)alloc((size_t)sN1[r] * 4 * 4);
  }
  float* hU  = (float*)alloc((size_t)NU * 128 * 4);
  float* hA  = (float*)alloc((size_t)NA * 128 * 4);
  float* hT  = (float*)alloc((size_t)NT * 128 * 4);
  unsigned short* zs2[3]; float* el2[3];
  for (int r = 0; r < 3; ++r) {
    zs2[r] = (unsigned short*)alloc((size_t)sN2[r] * 64 * 2);
    el2[r] = (float*)alloc((size_t)sN2[r] * 4);
  }
  float* h2a = (float*)alloc((size_t)NA * 64 * 4);
  float* h2t = (float*)alloc((size_t)NT * 64 * 4);

  hipMemsetAsync(zbase, 0, zbytes, stream);

  // ---- prep + CSR build ----
  prep<<<10, 256, 0, stream>>>(W1, al1, ar1, b1, W2, al2, ar2, b2,
                               Wz1, Wz2, war1, wal1, war2, wal2, bcomb);
  const int EB4 = (E + 1023) / 1024;
  hist_all<<<6 * EB4, 256, 0, stream>>>(ca, E, EB4);
  scan_all<<<6, 1024, 0, stream>>>(ca);
  scatter_all<<<6 * EB4, 256, 0, stream>>>(ca, E, EB4);

  // ---- layer 1: MFMA projections (Z bf16) ----
  {
    GemmM g;
    const float* sF1[6] = {fUser, fArt, fUser, fUser, fArt, fTag};
    int pre = 0;
    for (int r = 0; r < 6; ++r) {
      g.A[r] = sF1[r];
      g.Wz[r] = Wz1 + (size_t)r * 16384;
      g.Z[r] = zs1[r];
      g.N[r] = sN1[r];
      g.pre[r] = pre;
      pre += (sN1[r] + 63) / 64;
    }
    gemm_mfma<128><<<pre, 256, 0, stream>>>(g);
  }
  // ---- layer 1: attention el dots (folded W@al) ----
  {
    DotB g = {};
    g.X[0] = fUser; g.N[0] = NU; g.NR[0] = 3;   // rels 0 (ua), 2, 3
    g.wal[0][0] = wal1 + 0 * 512; g.el[0][0] = el1[0];
    g.wal[0][1] = wal1 + 2 * 512; g.el[0][1] = el1[2];
    g.wal[0][2] = wal1 + 3 * 512; g.el[0][2] = el1[3];
    g.X[1] = fArt; g.N[1] = NA; g.NR[1] = 2;    // rels 1 (au), 4 (at)
    g.wal[1][0] = wal1 + 1 * 512; g.el[1][0] = el1[1];
    g.wal[1][1] = wal1 + 4 * 512; g.el[1][1] = el1[4];
    g.X[2] = fTag; g.N[2] = NT; g.NR[2] = 1;    // rel 5 (ta)
    g.wal[2][0] = wal1 + 5 * 512; g.el[2][0] = el1[5];
    g.pre[0] = 0;
    g.pre[1] = (NU + 3) / 4;
    g.pre[2] = g.pre[1] + (NA + 3) / 4;
    int total = g.pre[2] + (NT + 3) / 4;
    node_dots<4><<<total, 256, 0, stream>>>(g);
  }

  // ---- layer 1: fused per-dst-type aggregation ----
  {
    AggP a; // artist: rels 0 (ua), 5 (ta)
    a.offs[0]=offs[0]; a.csr[0]=csr[0]; a.el[0]=el1[0]; a.zs[0]=zs1[0]; a.war[0]=war1+0*512;
    a.offs[1]=offs[5]; a.csr[1]=csr[5]; a.el[1]=el1[5]; a.zs[1]=zs1[5]; a.war[1]=war1+5*512;
    a.offs[2]=nullptr; a.csr[2]=nullptr; a.el[2]=nullptr; a.zs[2]=nullptr; a.war[2]=nullptr;
    a.bias = bcomb + 128; a.dfeat = fArt; a.out = hA; a.Nd = NA;
    agg_multi<4, 2, 2><<<(NA + 3) / 4, 256, 0, stream>>>(a);
  }
  {
    AggP a; // user: rels 1 (au), 2 (uu0), 3 (uu1)
    a.offs[0]=offs[1]; a.csr[0]=csr[1]; a.el[0]=el1[1]; a.zs[0]=zs1[1]; a.war[0]=war1+1*512;
    a.offs[1]=offs[2]; a.csr[1]=csr[2]; a.el[1]=el1[2]; a.zs[1]=zs1[2]; a.war[1]=war1+2*512;
    a.offs[2]=offs[3]; a.csr[2]=csr[3]; a.el[2]=el1[3]; a.zs[2]=zs1[3]; a.war[2]=war1+3*512;
    a.bias = bcomb; a.dfeat = fUser; a.out = hU; a.Nd = NU;
    agg_multi<4, 2, 3><<<(NU + 3) / 4, 256, 0, stream>>>(a);
  }
  {
    AggP a; // tag: rel 4 (at)
    a.offs[0]=offs[4]; a.csr[0]=csr[4]; a.el[0]=el1[4]; a.zs[0]=zs1[4]; a.war[0]=war1+4*512;
    a.offs[1]=nullptr; a.csr[1]=nullptr; a.el[1]=nullptr; a.zs[1]=nullptr; a.war[1]=nullptr;
    a.offs[2]=nullptr; a.csr[2]=nullptr; a.el[2]=nullptr; a.zs[2]=nullptr; a.war[2]=nullptr;
    a.bias = bcomb + 256; a.dfeat = fTag; a.out = hT; a.Nd = NT;
    agg_multi<4, 2, 1><<<(NT + 3) / 4, 256, 0, stream>>>(a);
  }

  // ---- layer 2: MFMA projections ----
  {
    GemmM g;
    const float* sF2[3] = {hU, hT, hA};
    int pre = 0;
    for (int r = 0; r < 3; ++r) {
      g.A[r] = sF2[r];
      g.Wz[r] = Wz2 + (size_t)r * 8192;
      g.Z[r] = zs2[r];
      g.N[r] = sN2[r];
      g.pre[r] = pre;
      pre += (sN2[r] + 63) / 64;
    }
    for (int r = 3; r < 6; ++r) {
      g.A[r] = nullptr; g.Wz[r] = nullptr; g.Z[r] = nullptr;
      g.N[r] = 0; g.pre[r] = 0x7fffffff;
    }
    gemm_mfma<64><<<pre, 256, 0, stream>>>(g);
  }
  // ---- layer 2: el dots ----
  {
    DotB g = {};
    g.X[0] = hU; g.N[0] = NU; g.NR[0] = 1;
    g.wal[0][0] = wal2 + 0 * 128; g.el[0][0] = el2[0];
    g.X[1] = hT; g.N[1] = NT; g.NR[1] = 1;
    g.wal[1][0] = wal2 + 1 * 128; g.el[1][0] = el2[1];
    g.X[2] = hA; g.N[2] = NA; g.NR[2] = 1;
    g.wal[2][0] = wal2 + 2 * 128; g.el[2][0] = el2[2];
    g.pre[0] = 0;
    g.pre[1] = (NU + 3) / 4;
    g.pre[2] = g.pre[1] + (NT + 3) / 4;
    int total = g.pre[2] + (NA + 3) / 4;
    node_dots<1><<<total, 256, 0, stream>>>(g);
  }

  // ---- layer 2: fused aggregation (reuses CSRs 0/5/4) ----
  {
    AggP a; // h2_artist: rels ua (csr0) + ta (csr5)
    a.offs[0]=offs[0]; a.csr[0]=csr[0]; a.el[0]=el2[0]; a.zs[0]=zs2[0]; a.war[0]=war2+0*128;
    a.offs[1]=offs[5]; a.csr[1]=csr[5]; a.el[1]=el2[1]; a.zs[1]=zs2[1]; a.war[1]=war2+1*128;
    a.offs[2]=nullptr; a.csr[2]=nullptr; a.el[2]=nullptr; a.zs[2]=nullptr; a.war[2]=nullptr;
    a.bias = bcomb + 384; a.dfeat = hA; a.out = h2a; a.Nd = NA;
    agg_multi<1, 1, 2><<<(NA + 3) / 4, 256, 0, stream>>>(a);
  }
  {
    AggP a; // h2_tag: rel at (csr4)
    a.offs[0]=offs[4]; a.csr[0]=csr[4]; a.el[0]=el2[2]; a.zs[0]=zs2[2]; a.war[0]=war2+2*128;
    a.offs[1]=nullptr; a.csr[1]=nullptr; a.el[1]=nullptr; a.zs[1]=nullptr; a.war[1]=nullptr;
    a.offs[2]=nullptr; a.csr[2]=nullptr; a.el[2]=nullptr; a.zs[2]=nullptr; a.war[2]=nullptr;
    a.bias = bcomb + 448; a.dfeat = hT; a.out = h2t; a.Nd = NT;
    agg_multi<1, 1, 1><<<(NT + 3) / 4, 256, 0, stream>>>(a);
  }

  // ---- predictor ----
  pred_dot<<<(int)(((size_t)(E + EN) * 16 + 255) / 256), 256, 0, stream>>>(
      h2a, h2t, ix[8], ix[9], ix[12], ix[13], (float*)d_out, E, EN);
}

// Round 7
// 355.048 us; speedup vs baseline: 1.1895x; 1.1895x over previous
//
#include <hip/hip_runtime.h>

#define DEVI __device__ __forceinline__

typedef __attribute__((ext_vector_type(8))) short short8v;
typedef __attribute__((ext_vector_type(4))) float f32x4;

DEVI float blo(unsigned u){ return __uint_as_float(u << 16); }
DEVI float bhi(unsigned u){ return __uint_as_float(u & 0xffff0000u); }
DEVI unsigned short f2bu(float f){          // f32 -> bf16 bits, RNE
  unsigned u = __float_as_uint(f);
  return (unsigned short)((u + 0x7fffu + ((u >> 16) & 1u)) >> 16);
}

// ---------------------------------------------------------------------------
// CSR build, batched over the 6 relations (all have exactly E edges).
// ---------------------------------------------------------------------------
struct CsrArgs {
  const int* src[6];
  const int* dst[6];
  int* cnt[6];
  int* offs[6];
  int* cur[6];
  int* csr[6];
  int  N[6];
};

__global__ __launch_bounds__(256)
void hist_all(CsrArgs a, int E, int ebks) {
  int r = blockIdx.x / ebks;
  int base = (blockIdx.x - r * ebks) * 1024 + threadIdx.x;
  const int* dst = a.dst[r];
  int* cnt = a.cnt[r];
#pragma unroll
  for (int k = 0; k < 4; ++k) {
    int e = base + k * 256;
    if (e < E) atomicAdd(&cnt[dst[e]], 1);
  }
}

__global__ __launch_bounds__(1024)
void scan_all(CsrArgs a) {
  __shared__ int psum[1024];
  int r = blockIdx.x;
  int N = a.N[r];
  const int* cnt = a.cnt[r];
  int* offs = a.offs[r];
  int t = threadIdx.x;
  int K = (N + 1023) / 1024;
  int i0 = t * K, i1 = min(i0 + K, N);
  int s = 0;
  for (int i = i0; i < i1; ++i) s += cnt[i];
  psum[t] = s;
  __syncthreads();
  for (int d = 1; d < 1024; d <<= 1) {
    int v = (t >= d) ? psum[t - d] : 0;
    __syncthreads();
    psum[t] += v;
    __syncthreads();
  }
  int run = (t == 0) ? 0 : psum[t - 1];
  for (int i = i0; i < i1; ++i) { offs[i] = run; run += cnt[i]; }
  if (t == 1023) offs[N] = run;
}

__global__ __launch_bounds__(256)
void scatter_all(CsrArgs a, int E, int ebks) {
  int r = blockIdx.x / ebks;
  int base = (blockIdx.x - r * ebks) * 1024 + threadIdx.x;
  const int* dst = a.dst[r];
  const int* src = a.src[r];
  const int* offs = a.offs[r];
  int* cur = a.cur[r];
  int* csr = a.csr[r];
#pragma unroll
  for (int k = 0; k < 4; ++k) {
    int e = base + k * 256;
    if (e < E) {
      int d = dst[e];
      int pos = atomicAdd(&cur[d], 1);
      csr[offs[d] + pos] = src[e];
    }
  }
}

// ---------------------------------------------------------------------------
// prep: per relation fold W@ar -> war and W@al -> wal (both [128][H]); convert
// W to bf16 in MFMA B-fragment order Wz[kc][c][j] (kc=k/8, j=k%8); combine
// biases. Blocks 0-5: layer1 rels; 6-8: layer2 rels (w = 0,5,4); 9: biases.
// ---------------------------------------------------------------------------
__global__ __launch_bounds__(256)
void prep(const float* __restrict__ W1, const float* __restrict__ al1,
          const float* __restrict__ ar1, const float* __restrict__ b1,
          const float* __restrict__ W2, const float* __restrict__ al2,
          const float* __restrict__ ar2, const float* __restrict__ b2,
          unsigned short* __restrict__ Wz1, unsigned short* __restrict__ Wz2,
          float* __restrict__ war1, float* __restrict__ wal1,
          float* __restrict__ war2, float* __restrict__ wal2,
          float* __restrict__ bcomb)
{
  int b = blockIdx.x, t = threadIdx.x;
  if (b < 6) {
    const float* W = W1 + b * 16384;
    unsigned short* Wz = Wz1 + b * 16384;
    for (int i = t; i < 16384; i += 256) {
      int j = i & 7, c = (i >> 3) & 127, kc = i >> 10;
      Wz[i] = f2bu(W[(kc * 8 + j) * 128 + c]);
    }
    for (int i = t; i < 512; i += 256) {
      int k = i >> 2, h = i & 3;
      float sr = 0.f, sl = 0.f;
      for (int f = 0; f < 32; ++f) {
        float w = W[k * 128 + h * 32 + f];
        sr += w * ar1[b * 128 + h * 32 + f];
        sl += w * al1[b * 128 + h * 32 + f];
      }
      war1[b * 512 + i] = sr;
      wal1[b * 512 + i] = sl;
    }
  } else if (b < 9) {
    int w = (b == 6) ? 0 : (b == 7) ? 5 : 4;
    const float* W = W2 + w * 8192;
    unsigned short* Wz = Wz2 + (b - 6) * 8192;
    for (int i = t; i < 8192; i += 256) {
      int j = i & 7, c = (i >> 3) & 63, kc = i >> 9;
      Wz[i] = f2bu(W[(kc * 8 + j) * 64 + c]);
    }
    if (t < 128) {
      float sr = 0.f, sl = 0.f;
      for (int f = 0; f < 64; ++f) {
        float x = W[t * 64 + f];
        sr += x * ar2[w * 64 + f];
        sl += x * al2[w * 64 + f];
      }
      war2[(b - 6) * 128 + t] = sr;
      wal2[(b - 6) * 128 + t] = sl;
    }
  } else {
    if (t < 128) {
      bcomb[t]       = b1[128 + t] + b1[256 + t] + b1[384 + t]; // user
      bcomb[128 + t] = b1[t] + b1[640 + t];                     // artist
      bcomb[256 + t] = b1[512 + t];                             // tag
    } else if (t < 192) {
      int x = t - 128;
      bcomb[384 + x] = b2[x] + b2[320 + x];                     // h2 artist
      bcomb[448 + x] = b2[256 + x];                             // h2 tag
    }
  }
}

// ---------------------------------------------------------------------------
// MFMA projection GEMM, batched over relations (unchanged from round 6).
// ---------------------------------------------------------------------------
struct GemmM {
  const float* A[6];
  const unsigned short* Wz[6];
  unsigned short* Z[6];
  int N[6];
  int pre[6];
};

template<int KOUT>
__global__ __launch_bounds__(256)
void gemm_mfma(GemmM g)
{
  constexpr int NCT = KOUT / 64;     // col-tiles per wave
  int r = 0;
#pragma unroll
  for (int i = 1; i < 6; ++i) if ((int)blockIdx.x >= g.pre[i]) r = i;
  const float* A = g.A[r];
  const short8v* Wp = (const short8v*)g.Wz[r];
  unsigned short* Z = g.Z[r];
  const int N = g.N[r];
  const int row0 = (blockIdx.x - g.pre[r]) * 64;

  __shared__ short8v a_lds[64 * 16];   // 64 rows x 128 bf16, chunk-XOR swizzled
  for (int i = threadIdx.x; i < 64 * 16; i += 256) {
    int row = i >> 4, c8 = i & 15;
    int grow = row0 + row;
    short8v v;
    if (grow < N) {
      const float4* ap = (const float4*)(A + (size_t)grow * 128 + c8 * 8);
      float4 x0 = ap[0], x1 = ap[1];
      v[0] = (short)f2bu(x0.x); v[1] = (short)f2bu(x0.y);
      v[2] = (short)f2bu(x0.z); v[3] = (short)f2bu(x0.w);
      v[4] = (short)f2bu(x1.x); v[5] = (short)f2bu(x1.y);
      v[6] = (short)f2bu(x1.z); v[7] = (short)f2bu(x1.w);
    } else {
      v = short8v{0, 0, 0, 0, 0, 0, 0, 0};
    }
    a_lds[row * 16 + (c8 ^ (row & 7))] = v;
  }
  __syncthreads();

  const int wv = threadIdx.x >> 6;
  const int lane = threadIdx.x & 63;
  const int lrow = lane & 15, lkg = lane >> 4;

  f32x4 acc[4][NCT];
#pragma unroll
  for (int rt = 0; rt < 4; ++rt)
#pragma unroll
    for (int c = 0; c < NCT; ++c) acc[rt][c] = f32x4{0.f, 0.f, 0.f, 0.f};

#pragma unroll
  for (int ks = 0; ks < 4; ++ks) {
    const int kc = ks * 4 + lkg;
    short8v bfr[NCT];
#pragma unroll
    for (int c = 0; c < NCT; ++c)
      bfr[c] = Wp[kc * KOUT + (wv * NCT + c) * 16 + lrow];
#pragma unroll
    for (int rt = 0; rt < 4; ++rt) {
      int row = rt * 16 + lrow;
      short8v afr = a_lds[row * 16 + (kc ^ (row & 7))];
#pragma unroll
      for (int c = 0; c < NCT; ++c)
        acc[rt][c] = __builtin_amdgcn_mfma_f32_16x16x32_bf16(afr, bfr[c], acc[rt][c], 0, 0, 0);
    }
  }

#pragma unroll
  for (int rt = 0; rt < 4; ++rt)
#pragma unroll
    for (int c = 0; c < NCT; ++c) {
      int col = (wv * NCT + c) * 16 + lrow;
#pragma unroll
      for (int q = 0; q < 4; ++q) {
        int grow = row0 + rt * 16 + lkg * 4 + q;
        if (grow < N) Z[(size_t)grow * KOUT + col] = f2bu(acc[rt][c][q]);
      }
    }
}

// ---------------------------------------------------------------------------
// node_dots v2: per node type compute ALL el/er columns at once.
// Y[n, c] = X[n,:128] . M_c   for C = NG*H columns (el and er groups).
// Block: 256 thr, 64 nodes. X staged in LDS with +1-padded stride (129:
// bank = (lane+k)%32 -> 2 lanes/bank = free). M staged in LDS; reads are
// wave-uniform broadcasts. NO cross-lane ops.
// ---------------------------------------------------------------------------
struct DotsB {
  const float* X[3];
  const float* M[3][6];     // per task, per group: [128][H] folded wal/war
  float* out[3][6];         // per task, per group: el/er array [N,H]
  int NG[3];
  int N[3];
  int pre[3];
};

template<int H, int MAXG>
__global__ __launch_bounds__(256)
void node_dots(DotsB g)
{
  int task = 0;
#pragma unroll
  for (int i = 1; i < 3; ++i) if ((int)blockIdx.x >= g.pre[i]) task = i;
  const int NG = g.NG[task];
  const int C = NG * H;
  const float* X = g.X[task];
  const int N = g.N[task];
  const int n0 = (blockIdx.x - g.pre[task]) * 64;

  __shared__ float Xs[64 * 129];
  __shared__ float Ms[128 * MAXG * H];
  for (int i = threadIdx.x; i < 128 * C; i += 256) {
    int k = i / C, c = i - k * C;
    int grp = c / H, h = c - grp * H;
    Ms[i] = g.M[task][grp][k * H + h];
  }
  for (int i = threadIdx.x; i < 64 * 32; i += 256) {
    int row = i >> 5, kk = i & 31;
    int n = n0 + row;
    float4 v;
    if (n < N) v = ((const float4*)(X + (size_t)n * 128))[kk];
    else { v.x = 0.f; v.y = 0.f; v.z = 0.f; v.w = 0.f; }
    float* xp = &Xs[row * 129 + kk * 4];
    xp[0] = v.x; xp[1] = v.y; xp[2] = v.z; xp[3] = v.w;
  }
  __syncthreads();

  const int lane = threadIdx.x & 63;
  const int wv = threadIdx.x >> 6;
  const int n = n0 + lane;
  const float* xp = &Xs[lane * 129];
  for (int c = wv; c < C; c += 4) {
    int grp = c / H, h = c - grp * H;
    const float* mp = &Ms[c];
    float a0 = 0.f, a1 = 0.f;
#pragma unroll 8
    for (int k = 0; k < 128; k += 2) {
      a0 = fmaf(xp[k],     mp[k * C],       a0);
      a1 = fmaf(xp[k + 1], mp[(k + 1) * C], a1);
    }
    if (n < N) g.out[task][grp][(size_t)n * H + h] = a0 + a1;
  }
}

// ---------------------------------------------------------------------------
// Fused multi-relation CSR aggregation. er now read directly (computed by
// node_dots) — no butterflies, no LDS, no syncthreads.
// ---------------------------------------------------------------------------
struct AggP {
  const int* offs[3];
  const int* csr[3];
  const float* el[3];
  const float* er[3];
  const unsigned short* zs[3];
  const float* bias;
  float* out;
  int Nd;
};

template<int H, int CPL, int NR>
__global__ __launch_bounds__(256)
void agg_multi(AggP a)
{
  constexpr int ELEMS = 64 * CPL;
  constexpr int F = ELEMS / H;
  const int lane = threadIdx.x & 63;
  const int n = blockIdx.x * 4 + (threadIdx.x >> 6);
  if (n >= a.Nd) return;

  const int hlane = (CPL * lane) / F;
  float vout[CPL];
#pragma unroll
  for (int j = 0; j < CPL; ++j) vout[j] = a.bias[CPL * lane + j];

#pragma unroll
  for (int r = 0; r < NR; ++r) {
    float erl = (lane < H) ? a.er[r][(size_t)n * H + lane] : 0.f;
    const float* el = a.el[r];
    const int* csr = a.csr[r];
    float accA[CPL], accB[CPL];
#pragma unroll
    for (int j = 0; j < CPL; ++j) { accA[j] = 0.f; accB[j] = 0.f; }
    float denA = 0.f, denB = 0.f;
    const int e0 = a.offs[r][n], e1 = a.offs[r][n + 1];
    for (int eb = e0; eb < e1; eb += 64) {
      int sv = (eb + lane < e1) ? csr[eb + lane] : 0;
      int m = min(64, e1 - eb);
      int j = 0;
      for (; j + 2 <= m; j += 2) {
        int s0 = __shfl(sv, j, 64), s1 = __shfl(sv, j + 1, 64);
        float ex0 = 0.f, ex1 = 0.f;
        if (lane < H) {
          float v0 = el[s0 * H + lane] + erl;
          v0 = v0 > 0.f ? v0 : 0.2f * v0;
          ex0 = __expf(v0); denA += ex0;
          float v1 = el[s1 * H + lane] + erl;
          v1 = v1 > 0.f ? v1 : 0.2f * v1;
          ex1 = __expf(v1); denB += ex1;
        }
        float eh0 = __shfl(ex0, hlane, 64);
        float eh1 = __shfl(ex1, hlane, 64);
        if (CPL == 2) {
          unsigned z0 = ((const unsigned*)a.zs[r])[(size_t)s0 * (ELEMS / 2) + lane];
          unsigned z1 = ((const unsigned*)a.zs[r])[(size_t)s1 * (ELEMS / 2) + lane];
          accA[0] += eh0 * blo(z0); accA[CPL - 1] += eh0 * bhi(z0);
          accB[0] += eh1 * blo(z1); accB[CPL - 1] += eh1 * bhi(z1);
        } else {
          unsigned z0 = ((const unsigned short*)a.zs[r])[(size_t)s0 * ELEMS + lane];
          unsigned z1 = ((const unsigned short*)a.zs[r])[(size_t)s1 * ELEMS + lane];
          accA[0] += eh0 * blo(z0);
          accB[0] += eh1 * blo(z1);
        }
      }
      for (; j < m; ++j) {
        int s0 = __shfl(sv, j, 64);
        float ex0 = 0.f;
        if (lane < H) {
          float v0 = el[s0 * H + lane] + erl;
          v0 = v0 > 0.f ? v0 : 0.2f * v0;
          ex0 = __expf(v0); denA += ex0;
        }
        float eh0 = __shfl(ex0, hlane, 64);
        if (CPL == 2) {
          unsigned z0 = ((const unsigned*)a.zs[r])[(size_t)s0 * (ELEMS / 2) + lane];
          accA[0] += eh0 * blo(z0); accA[CPL - 1] += eh0 * bhi(z0);
        } else {
          unsigned z0 = ((const unsigned short*)a.zs[r])[(size_t)s0 * ELEMS + lane];
          accA[0] += eh0 * blo(z0);
        }
      }
    }
#pragma unroll
    for (int j = 0; j < CPL; ++j) {
      int x = CPL * lane + j;
      float dd = __shfl(denA + denB, x / F, 64);
      if (dd > 0.f) vout[j] += (accA[j] + accB[j]) / dd;
    }
  }
  if (CPL == 2) {
    float2 o; o.x = vout[0]; o.y = vout[CPL - 1];
    ((float2*)(a.out + (size_t)n * ELEMS))[lane] = o;
  } else {
    a.out[(size_t)n * ELEMS + lane] = vout[0];
  }
}

// ---------------------------------------------------------------------------
// Predictor: 16 lanes per edge, coalesced float4 row loads, shfl reduce.
// ---------------------------------------------------------------------------
__global__ __launch_bounds__(256)
void pred_dot(const float* __restrict__ h2a, const float* __restrict__ h2t,
              const int* __restrict__ ps, const int* __restrict__ pd,
              const int* __restrict__ ns, const int* __restrict__ nd,
              float* __restrict__ out, int Ep, int En)
{
  int t = blockIdx.x * 256 + threadIdx.x;
  int e = t >> 4, q = t & 15;
  if (e >= Ep + En) return;
  int s, d;
  if (e < Ep) { s = ps[e]; d = pd[e]; }
  else        { s = ns[e - Ep]; d = nd[e - Ep]; }
  float4 a = ((const float4*)(h2a + (size_t)s * 64))[q];
  float4 b = ((const float4*)(h2t + (size_t)d * 64))[q];
  float v = a.x * b.x + a.y * b.y + a.z * b.z + a.w * b.w;
  v += __shfl_xor(v, 8, 64);
  v += __shfl_xor(v, 4, 64);
  v += __shfl_xor(v, 2, 64);
  v += __shfl_xor(v, 1, 64);
  if (q == 0) out[e] = v;
}

// ---------------------------------------------------------------------------
extern "C" void kernel_launch(void* const* d_in, const int* in_sizes, int n_in,
                              void* d_out, int out_size, void* d_ws, size_t ws_size,
                              hipStream_t stream)
{
  (void)n_in; (void)out_size; (void)ws_size;
  const float* fUser = (const float*)d_in[0];
  const float* fArt  = (const float*)d_in[1];
  const float* fTag  = (const float*)d_in[2];
  const float* W1  = (const float*)d_in[3];
  const float* al1 = (const float*)d_in[4];
  const float* ar1 = (const float*)d_in[5];
  const float* b1  = (const float*)d_in[6];
  const float* W2  = (const float*)d_in[7];
  const float* al2 = (const float*)d_in[8];
  const float* ar2 = (const float*)d_in[9];
  const float* b2  = (const float*)d_in[10];
  const int* ix[14];
  for (int i = 0; i < 14; ++i) ix[i] = (const int*)d_in[11 + i];

  const int NU = in_sizes[0] / 128;
  const int NA = in_sizes[1] / 128;
  const int NT = in_sizes[2] / 128;
  const int E  = in_sizes[11];
  const int EN = in_sizes[23];

  char* p = (char*)d_ws;
  auto alloc = [&](size_t bytes) -> char* {
    char* r = p; p += (bytes + 255) & ~(size_t)255; return r;
  };

  const int dN1[6] = {NA, NU, NU, NU, NT, NA};
  const int sN1[6] = {NU, NA, NU, NU, NA, NT};
  const int sN2[3] = {NU, NT, NA};

  // ---- zero-init region: CSR counters + cursors ----
  char* zbase = p;
  CsrArgs ca;
  for (int r = 0; r < 6; ++r) ca.cnt[r] = (int*)alloc((size_t)dN1[r] * 4);
  for (int r = 0; r < 6; ++r) ca.cur[r] = (int*)alloc((size_t)dN1[r] * 4);
  size_t zbytes = (size_t)(p - zbase);

  // ---- non-zero scratch ----
  int* offs[6]; int* csr[6];
  for (int r = 0; r < 6; ++r) {
    offs[r] = (int*)alloc(((size_t)dN1[r] + 1) * 4);
    csr[r]  = (int*)alloc((size_t)E * 4);
    ca.src[r] = ix[2 * r]; ca.dst[r] = ix[2 * r + 1];
    ca.offs[r] = offs[r]; ca.csr[r] = csr[r]; ca.N[r] = dN1[r];
  }
  unsigned short* Wz1 = (unsigned short*)alloc(6 * 16384 * 2);
  unsigned short* Wz2 = (unsigned short*)alloc(3 * 8192 * 2);
  float* war1  = (float*)alloc(6 * 512 * 4);
  float* wal1  = (float*)alloc(6 * 512 * 4);
  float* war2  = (float*)alloc(3 * 128 * 4);
  float* wal2  = (float*)alloc(3 * 128 * 4);
  float* bcomb = (float*)alloc(512 * 4);
  unsigned short* zs1[6]; float* el1[6]; float* er1[6];
  for (int r = 0; r < 6; ++r) {
    zs1[r] = (unsigned short*)alloc((size_t)sN1[r] * 128 * 2);
    el1[r] = (float*)alloc((size_t)sN1[r] * 4 * 4);
    er1[r] = (float*)alloc((size_t)dN1[r] * 4 * 4);
  }
  float* hU  = (float*)alloc((size_t)NU * 128 * 4);
  float* hA  = (float*)alloc((size_t)NA * 128 * 4);
  float* hT  = (float*)alloc((size_t)NT * 128 * 4);
  unsigned short* zs2[3]; float* el2[3]; float* er2[3];
  const int dN2[3] = {NA, NA, NT};   // l2 rels: r0=ua->A, r1=ta->A, r2=at->T
  for (int r = 0; r < 3; ++r) {
    zs2[r] = (unsigned short*)alloc((size_t)sN2[r] * 64 * 2);
    el2[r] = (float*)alloc((size_t)sN2[r] * 4);
    er2[r] = (float*)alloc((size_t)dN2[r] * 4);
  }
  float* h2a = (float*)alloc((size_t)NA * 64 * 4);
  float* h2t = (float*)alloc((size_t)NT * 64 * 4);

  hipMemsetAsync(zbase, 0, zbytes, stream);

  // ---- prep + CSR build ----
  prep<<<10, 256, 0, stream>>>(W1, al1, ar1, b1, W2, al2, ar2, b2,
                               Wz1, Wz2, war1, wal1, war2, wal2, bcomb);
  const int EB4 = (E + 1023) / 1024;
  hist_all<<<6 * EB4, 256, 0, stream>>>(ca, E, EB4);
  scan_all<<<6, 1024, 0, stream>>>(ca);
  scatter_all<<<6 * EB4, 256, 0, stream>>>(ca, E, EB4);

  // ---- layer 1: MFMA projections (Z bf16) ----
  {
    GemmM g;
    const float* sF1[6] = {fUser, fArt, fUser, fUser, fArt, fTag};
    int pre = 0;
    for (int r = 0; r < 6; ++r) {
      g.A[r] = sF1[r];
      g.Wz[r] = Wz1 + (size_t)r * 16384;
      g.Z[r] = zs1[r];
      g.N[r] = sN1[r];
      g.pre[r] = pre;
      pre += (sN1[r] + 63) / 64;
    }
    gemm_mfma<128><<<pre, 256, 0, stream>>>(g);
  }
  // ---- layer 1: all el/er dots (no cross-lane) ----
  {
    DotsB g = {};
    // user: el rels 0,2,3 ; er rels 1,2,3
    g.X[0] = fUser; g.N[0] = NU; g.NG[0] = 6;
    g.M[0][0] = wal1 + 0 * 512; g.out[0][0] = el1[0];
    g.M[0][1] = wal1 + 2 * 512; g.out[0][1] = el1[2];
    g.M[0][2] = wal1 + 3 * 512; g.out[0][2] = el1[3];
    g.M[0][3] = war1 + 1 * 512; g.out[0][3] = er1[1];
    g.M[0][4] = war1 + 2 * 512; g.out[0][4] = er1[2];
    g.M[0][5] = war1 + 3 * 512; g.out[0][5] = er1[3];
    // artist: el rels 1,4 ; er rels 0,5
    g.X[1] = fArt; g.N[1] = NA; g.NG[1] = 4;
    g.M[1][0] = wal1 + 1 * 512; g.out[1][0] = el1[1];
    g.M[1][1] = wal1 + 4 * 512; g.out[1][1] = el1[4];
    g.M[1][2] = war1 + 0 * 512; g.out[1][2] = er1[0];
    g.M[1][3] = war1 + 5 * 512; g.out[1][3] = er1[5];
    // tag: el rel 5 ; er rel 4
    g.X[2] = fTag; g.N[2] = NT; g.NG[2] = 2;
    g.M[2][0] = wal1 + 5 * 512; g.out[2][0] = el1[5];
    g.M[2][1] = war1 + 4 * 512; g.out[2][1] = er1[4];
    g.pre[0] = 0;
    g.pre[1] = (NU + 63) / 64;
    g.pre[2] = g.pre[1] + (NA + 63) / 64;
    int total = g.pre[2] + (NT + 63) / 64;
    node_dots<4, 6><<<total, 256, 0, stream>>>(g);
  }

  // ---- layer 1: fused per-dst-type aggregation ----
  {
    AggP a = {}; // artist: rels 0 (ua), 5 (ta)
    a.offs[0]=offs[0]; a.csr[0]=csr[0]; a.el[0]=el1[0]; a.er[0]=er1[0]; a.zs[0]=zs1[0];
    a.offs[1]=offs[5]; a.csr[1]=csr[5]; a.el[1]=el1[5]; a.er[1]=er1[5]; a.zs[1]=zs1[5];
    a.bias = bcomb + 128; a.out = hA; a.Nd = NA;
    agg_multi<4, 2, 2><<<(NA + 3) / 4, 256, 0, stream>>>(a);
  }
  {
    AggP a = {}; // user: rels 1 (au), 2 (uu0), 3 (uu1)
    a.offs[0]=offs[1]; a.csr[0]=csr[1]; a.el[0]=el1[1]; a.er[0]=er1[1]; a.zs[0]=zs1[1];
    a.offs[1]=offs[2]; a.csr[1]=csr[2]; a.el[1]=el1[2]; a.er[1]=er1[2]; a.zs[1]=zs1[2];
    a.offs[2]=offs[3]; a.csr[2]=csr[3]; a.el[2]=el1[3]; a.er[2]=er1[3]; a.zs[2]=zs1[3];
    a.bias = bcomb; a.out = hU; a.Nd = NU;
    agg_multi<4, 2, 3><<<(NU + 3) / 4, 256, 0, stream>>>(a);
  }
  {
    AggP a = {}; // tag: rel 4 (at)
    a.offs[0]=offs[4]; a.csr[0]=csr[4]; a.el[0]=el1[4]; a.er[0]=er1[4]; a.zs[0]=zs1[4];
    a.bias = bcomb + 256; a.out = hT; a.Nd = NT;
    agg_multi<4, 2, 1><<<(NT + 3) / 4, 256, 0, stream>>>(a);
  }

  // ---- layer 2: MFMA projections ----
  {
    GemmM g;
    const float* sF2[3] = {hU, hT, hA};
    int pre = 0;
    for (int r = 0; r < 3; ++r) {
      g.A[r] = sF2[r];
      g.Wz[r] = Wz2 + (size_t)r * 8192;
      g.Z[r] = zs2[r];
      g.N[r] = sN2[r];
      g.pre[r] = pre;
      pre += (sN2[r] + 63) / 64;
    }
    for (int r = 3; r < 6; ++r) {
      g.A[r] = nullptr; g.Wz[r] = nullptr; g.Z[r] = nullptr;
      g.N[r] = 0; g.pre[r] = 0x7fffffff;
    }
    gemm_mfma<64><<<pre, 256, 0, stream>>>(g);
  }
  // ---- layer 2: el/er dots ----
  {
    DotsB g = {};
    // artist: el of rel at (wal2[2]); er of rels ua (war2[0]), ta (war2[1])
    g.X[0] = hA; g.N[0] = NA; g.NG[0] = 3;
    g.M[0][0] = wal2 + 2 * 128; g.out[0][0] = el2[2];
    g.M[0][1] = war2 + 0 * 128; g.out[0][1] = er2[0];
    g.M[0][2] = war2 + 1 * 128; g.out[0][2] = er2[1];
    // user: el of rel ua (wal2[0])
    g.X[1] = hU; g.N[1] = NU; g.NG[1] = 1;
    g.M[1][0] = wal2 + 0 * 128; g.out[1][0] = el2[0];
    // tag: el of rel ta (wal2[1]); er of rel at (war2[2])
    g.X[2] = hT; g.N[2] = NT; g.NG[2] = 2;
    g.M[2][0] = wal2 + 1 * 128; g.out[2][0] = el2[1];
    g.M[2][1] = war2 + 2 * 128; g.out[2][1] = er2[2];
    g.pre[0] = 0;
    g.pre[1] = (NA + 63) / 64;
    g.pre[2] = g.pre[1] + (NU + 63) / 64;
    int total = g.pre[2] + (NT + 63) / 64;
    node_dots<1, 3><<<total, 256, 0, stream>>>(g);
  }

  // ---- layer 2: fused aggregation (reuses CSRs 0/5/4) ----
  {
    AggP a = {}; // h2_artist: rels ua (csr0) + ta (csr5)
    a.offs[0]=offs[0]; a.csr[0]=csr[0]; a.el[0]=el2[0]; a.er[0]=er2[0]; a.zs[0]=zs2[0];
    a.offs[1]=offs[5]; a.csr[1]=csr[5]; a.el[1]=el2[1]; a.er[1]=er2[1]; a.zs[1]=zs2[1];
    a.bias = bcomb + 384; a.out = h2a; a.Nd = NA;
    agg_multi<1, 1, 2><<<(NA + 3) / 4, 256, 0, stream>>>(a);
  }
  {
    AggP a = {}; // h2_tag: rel at (csr4)
    a.offs[0]=offs[4]; a.csr[0]=csr[4]; a.el[0]=el2[2]; a.er[0]=er2[2]; a.zs[0]=zs2[2];
    a.bias = bcomb + 448; a.out = h2t; a.Nd = NT;
    agg_multi<1, 1, 1><<<(NT + 3) / 4, 256, 0, stream>>>(a);
  }

  // ---- predictor ----
  pred_dot<<<(int)(((size_t)(E + EN) * 16 + 255) / 256), 256, 0, stream>>>(
      h2a, h2t, ix[8], ix[9], ix[12], ix[13], (float*)d_out, E, EN);
}

// Round 8
// 273.053 us; speedup vs baseline: 1.5467x; 1.3003x over previous
//
#include <hip/hip_runtime.h>

#define DEVI __device__ __forceinline__

typedef __attribute__((ext_vector_type(8))) short short8v;
typedef __attribute__((ext_vector_type(4))) float f32x4;

DEVI float blo(unsigned u){ return __uint_as_float(u << 16); }
DEVI float bhi(unsigned u){ return __uint_as_float(u & 0xffff0000u); }
DEVI unsigned short f2bu(float f){          // f32 -> bf16 bits, RNE
  unsigned u = __float_as_uint(f);
  return (unsigned short)((u + 0x7fffu + ((u >> 16) & 1u)) >> 16);
}

#define MAXB 160          // max buckets per relation (ceil(20000/128)=157)
#define BKE  4096         // edges per block in bucket passes

// ---------------------------------------------------------------------------
// Bucketed CSR build: all global writes are contiguous runs (no random 4B
// global scatter). Bucket = dst>>7 (128 nodes). Entries packed (src<<7|dstlow).
// ---------------------------------------------------------------------------
struct BArgs {
  const int* src[6];
  const int* dst[6];
  int* bcnt;           // [6*MAXB] bucket counts
  int* bbase;          // [6*MAXB] bucket bases (exclusive scan)
  int* gcur;           // [6*MAXB] run-reservation cursors
  unsigned* stage[6];  // [E] bucket-major packed staging
  int* csr[6];         // [E] final per-node-contiguous src lists
  int* st[6];          // [N] per-node segment start
  int* en[6];          // [N] per-node segment end
  int nb[6];           // buckets per relation
  int N[6];            // dst-node count per relation
  int bpre[6];         // bucket-grid prefix for bbuild
};

__global__ __launch_bounds__(256)
void bhist(BArgs a, int E, int ebks) {
  __shared__ int h[MAXB];
  int r = blockIdx.x / ebks;
  int base = (blockIdx.x - r * ebks) * BKE;
  for (int i = threadIdx.x; i < MAXB; i += 256) h[i] = 0;
  __syncthreads();
  const int* dst = a.dst[r];
#pragma unroll
  for (int k = 0; k < 16; ++k) {
    int e = base + threadIdx.x + k * 256;
    if (e < E) atomicAdd(&h[dst[e] >> 7], 1);
  }
  __syncthreads();
  int NB = a.nb[r];
  for (int i = threadIdx.x; i < NB; i += 256)
    if (h[i]) atomicAdd(&a.bcnt[r * MAXB + i], h[i]);
}

__global__ __launch_bounds__(256)
void bscan(BArgs a) {
  __shared__ int ps[256];
  int r = blockIdx.x;
  int NB = a.nb[r];
  int t = threadIdx.x;
  int v = (t < NB) ? a.bcnt[r * MAXB + t] : 0;
  ps[t] = v;
  __syncthreads();
  for (int d = 1; d < 256; d <<= 1) {
    int x = (t >= d) ? ps[t - d] : 0;
    __syncthreads();
    ps[t] += x;
    __syncthreads();
  }
  if (t < NB) a.bbase[r * MAXB + t] = ps[t] - v;   // exclusive
}

__global__ __launch_bounds__(256)
void bscatter(BArgs a, int E, int ebks) {
  __shared__ int hist[MAXB];
  __shared__ int pref[MAXB];
  __shared__ int cur[MAXB];
  __shared__ int runb[MAXB];
  __shared__ int ps[256];
  __shared__ unsigned stag[BKE];
  __shared__ unsigned char dig8[BKE];
  int r = blockIdx.x / ebks;
  int base = (blockIdx.x - r * ebks) * BKE;
  int cnt = min(BKE, E - base);
  int NB = a.nb[r];
  for (int i = threadIdx.x; i < MAXB; i += 256) hist[i] = 0;
  __syncthreads();
  const int* dst = a.dst[r];
  const int* src = a.src[r];
  int ed[16], sd[16];
#pragma unroll
  for (int k = 0; k < 16; ++k) {
    int e = base + threadIdx.x + k * 256;
    if (e < E) { ed[k] = dst[e]; sd[k] = src[e]; atomicAdd(&hist[ed[k] >> 7], 1); }
    else ed[k] = -1;
  }
  __syncthreads();
  {
    int t = threadIdx.x;
    int v = (t < NB) ? hist[t] : 0;
    ps[t] = v;
    __syncthreads();
    for (int d = 1; d < 256; d <<= 1) {
      int x = (t >= d) ? ps[t - d] : 0;
      __syncthreads();
      ps[t] += x;
      __syncthreads();
    }
    if (t < NB) { pref[t] = ps[t] - v; cur[t] = ps[t] - v; }
  }
  __syncthreads();
#pragma unroll
  for (int k = 0; k < 16; ++k) {
    if (ed[k] >= 0) {
      int dg = ed[k] >> 7;
      int pos = atomicAdd(&cur[dg], 1);
      stag[pos] = ((unsigned)sd[k] << 7) | (unsigned)(ed[k] & 127);
      dig8[pos] = (unsigned char)dg;
    }
  }
  __syncthreads();
  for (int i = threadIdx.x; i < NB; i += 256) {
    int len = hist[i];
    runb[i] = len ? (a.bbase[r * MAXB + i] + atomicAdd(&a.gcur[r * MAXB + i], len)) : 0;
  }
  __syncthreads();
  unsigned* sg = a.stage[r];
  for (int i = threadIdx.x; i < cnt; i += 256) {
    int dg = dig8[i];
    sg[runb[dg] + (i - pref[dg])] = stag[i];   // contiguous runs
  }
}

__global__ __launch_bounds__(256)
void bbuild(BArgs a) {
  __shared__ int hist[128];
  __shared__ int pref[129];
  __shared__ int cur[128];
  __shared__ int ps[256];
  __shared__ int loc[8192];
  int r = 0;
#pragma unroll
  for (int i = 1; i < 6; ++i) if ((int)blockIdx.x >= a.bpre[i]) r = i;
  int b = (int)blockIdx.x - a.bpre[r];
  int cnt = a.bcnt[r * MAXB + b];
  int base = a.bbase[r * MAXB + b];
  int n0 = b << 7;
  int N = a.N[r];
  for (int i = threadIdx.x; i < 128; i += 256) hist[i] = 0;
  __syncthreads();
  const unsigned* sg = a.stage[r] + base;
  for (int i = threadIdx.x; i < cnt; i += 256) atomicAdd(&hist[sg[i] & 127], 1);
  __syncthreads();
  {
    int t = threadIdx.x;
    int v = (t < 128) ? hist[t] : 0;
    ps[t] = v;
    __syncthreads();
    for (int d = 1; d < 128; d <<= 1) {
      int x = (t >= d) ? ps[t - d] : 0;
      __syncthreads();
      ps[t] += x;
      __syncthreads();
    }
    if (t < 128) { pref[t] = ps[t] - v; cur[t] = ps[t] - v; }
    if (t == 127) pref[128] = ps[127];
  }
  __syncthreads();
  for (int i = threadIdx.x; i < cnt; i += 256) {
    unsigned v = sg[i];
    int pos = atomicAdd(&cur[v & 127], 1);
    loc[pos] = (int)(v >> 7);
  }
  __syncthreads();
  int* csr = a.csr[r];
  for (int i = threadIdx.x; i < cnt; i += 256) csr[base + i] = loc[i];
  if (threadIdx.x < 128) {
    int n = n0 + threadIdx.x;
    if (n < N) {
      a.st[r][n] = base + pref[threadIdx.x];
      a.en[r][n] = base + pref[threadIdx.x + 1];
    }
  }
}

// ---------------------------------------------------------------------------
// prep: fold W@ar -> war, W@al -> wal; W -> bf16 MFMA-fragment order; biases.
// ---------------------------------------------------------------------------
__global__ __launch_bounds__(256)
void prep(const float* __restrict__ W1, const float* __restrict__ al1,
          const float* __restrict__ ar1, const float* __restrict__ b1,
          const float* __restrict__ W2, const float* __restrict__ al2,
          const float* __restrict__ ar2, const float* __restrict__ b2,
          unsigned short* __restrict__ Wz1, unsigned short* __restrict__ Wz2,
          float* __restrict__ war1, float* __restrict__ wal1,
          float* __restrict__ war2, float* __restrict__ wal2,
          float* __restrict__ bcomb)
{
  int b = blockIdx.x, t = threadIdx.x;
  if (b < 6) {
    const float* W = W1 + b * 16384;
    unsigned short* Wz = Wz1 + b * 16384;
    for (int i = t; i < 16384; i += 256) {
      int j = i & 7, c = (i >> 3) & 127, kc = i >> 10;
      Wz[i] = f2bu(W[(kc * 8 + j) * 128 + c]);
    }
    for (int i = t; i < 512; i += 256) {
      int k = i >> 2, h = i & 3;
      float sr = 0.f, sl = 0.f;
      for (int f = 0; f < 32; ++f) {
        float w = W[k * 128 + h * 32 + f];
        sr += w * ar1[b * 128 + h * 32 + f];
        sl += w * al1[b * 128 + h * 32 + f];
      }
      war1[b * 512 + i] = sr;
      wal1[b * 512 + i] = sl;
    }
  } else if (b < 9) {
    int w = (b == 6) ? 0 : (b == 7) ? 5 : 4;
    const float* W = W2 + w * 8192;
    unsigned short* Wz = Wz2 + (b - 6) * 8192;
    for (int i = t; i < 8192; i += 256) {
      int j = i & 7, c = (i >> 3) & 63, kc = i >> 9;
      Wz[i] = f2bu(W[(kc * 8 + j) * 64 + c]);
    }
    if (t < 128) {
      float sr = 0.f, sl = 0.f;
      for (int f = 0; f < 64; ++f) {
        float x = W[t * 64 + f];
        sr += x * ar2[w * 64 + f];
        sl += x * al2[w * 64 + f];
      }
      war2[(b - 6) * 128 + t] = sr;
      wal2[(b - 6) * 128 + t] = sl;
    }
  } else {
    if (t < 128) {
      bcomb[t]       = b1[128 + t] + b1[256 + t] + b1[384 + t]; // user
      bcomb[128 + t] = b1[t] + b1[640 + t];                     // artist
      bcomb[256 + t] = b1[512 + t];                             // tag
    } else if (t < 192) {
      int x = t - 128;
      bcomb[384 + x] = b2[x] + b2[320 + x];                     // h2 artist
      bcomb[448 + x] = b2[256 + x];                             // h2 tag
    }
  }
}

// ---------------------------------------------------------------------------
// MFMA projection GEMM, batched over relations.
// ---------------------------------------------------------------------------
struct GemmM {
  const float* A[6];
  const unsigned short* Wz[6];
  unsigned short* Z[6];
  int N[6];
  int pre[6];
};

template<int KOUT>
__global__ __launch_bounds__(256)
void gemm_mfma(GemmM g)
{
  constexpr int NCT = KOUT / 64;
  int r = 0;
#pragma unroll
  for (int i = 1; i < 6; ++i) if ((int)blockIdx.x >= g.pre[i]) r = i;
  const float* A = g.A[r];
  const short8v* Wp = (const short8v*)g.Wz[r];
  unsigned short* Z = g.Z[r];
  const int N = g.N[r];
  const int row0 = (blockIdx.x - g.pre[r]) * 64;

  __shared__ short8v a_lds[64 * 16];
  for (int i = threadIdx.x; i < 64 * 16; i += 256) {
    int row = i >> 4, c8 = i & 15;
    int grow = row0 + row;
    short8v v;
    if (grow < N) {
      const float4* ap = (const float4*)(A + (size_t)grow * 128 + c8 * 8);
      float4 x0 = ap[0], x1 = ap[1];
      v[0] = (short)f2bu(x0.x); v[1] = (short)f2bu(x0.y);
      v[2] = (short)f2bu(x0.z); v[3] = (short)f2bu(x0.w);
      v[4] = (short)f2bu(x1.x); v[5] = (short)f2bu(x1.y);
      v[6] = (short)f2bu(x1.z); v[7] = (short)f2bu(x1.w);
    } else {
      v = short8v{0, 0, 0, 0, 0, 0, 0, 0};
    }
    a_lds[row * 16 + (c8 ^ (row & 7))] = v;
  }
  __syncthreads();

  const int wv = threadIdx.x >> 6;
  const int lane = threadIdx.x & 63;
  const int lrow = lane & 15, lkg = lane >> 4;

  f32x4 acc[4][NCT];
#pragma unroll
  for (int rt = 0; rt < 4; ++rt)
#pragma unroll
    for (int c = 0; c < NCT; ++c) acc[rt][c] = f32x4{0.f, 0.f, 0.f, 0.f};

#pragma unroll
  for (int ks = 0; ks < 4; ++ks) {
    const int kc = ks * 4 + lkg;
    short8v bfr[NCT];
#pragma unroll
    for (int c = 0; c < NCT; ++c)
      bfr[c] = Wp[kc * KOUT + (wv * NCT + c) * 16 + lrow];
#pragma unroll
    for (int rt = 0; rt < 4; ++rt) {
      int row = rt * 16 + lrow;
      short8v afr = a_lds[row * 16 + (kc ^ (row & 7))];
#pragma unroll
      for (int c = 0; c < NCT; ++c)
        acc[rt][c] = __builtin_amdgcn_mfma_f32_16x16x32_bf16(afr, bfr[c], acc[rt][c], 0, 0, 0);
    }
  }

#pragma unroll
  for (int rt = 0; rt < 4; ++rt)
#pragma unroll
    for (int c = 0; c < NCT; ++c) {
      int col = (wv * NCT + c) * 16 + lrow;
#pragma unroll
      for (int q = 0; q < 4; ++q) {
        int grow = row0 + rt * 16 + lkg * 4 + q;
        if (grow < N) Z[(size_t)grow * KOUT + col] = f2bu(acc[rt][c][q]);
      }
    }
}

// ---------------------------------------------------------------------------
// node_dots: all el/er columns per node type; no cross-lane ops.
// ---------------------------------------------------------------------------
struct DotsB {
  const float* X[3];
  const float* M[3][6];
  float* out[3][6];
  int NG[3];
  int N[3];
  int pre[3];
};

template<int H, int MAXG>
__global__ __launch_bounds__(256)
void node_dots(DotsB g)
{
  int task = 0;
#pragma unroll
  for (int i = 1; i < 3; ++i) if ((int)blockIdx.x >= g.pre[i]) task = i;
  const int NG = g.NG[task];
  const int C = NG * H;
  const float* X = g.X[task];
  const int N = g.N[task];
  const int n0 = (blockIdx.x - g.pre[task]) * 64;

  __shared__ float Xs[64 * 129];
  __shared__ float Ms[128 * MAXG * H];
  for (int i = threadIdx.x; i < 128 * C; i += 256) {
    int k = i / C, c = i - k * C;
    int grp = c / H, h = c - grp * H;
    Ms[i] = g.M[task][grp][k * H + h];
  }
  for (int i = threadIdx.x; i < 64 * 32; i += 256) {
    int row = i >> 5, kk = i & 31;
    int n = n0 + row;
    float4 v;
    if (n < N) v = ((const float4*)(X + (size_t)n * 128))[kk];
    else { v.x = 0.f; v.y = 0.f; v.z = 0.f; v.w = 0.f; }
    float* xp = &Xs[row * 129 + kk * 4];
    xp[0] = v.x; xp[1] = v.y; xp[2] = v.z; xp[3] = v.w;
  }
  __syncthreads();

  const int lane = threadIdx.x & 63;
  const int wv = threadIdx.x >> 6;
  const int n = n0 + lane;
  const float* xp = &Xs[lane * 129];
  for (int c = wv; c < C; c += 4) {
    int grp = c / H, h = c - grp * H;
    const float* mp = &Ms[c];
    float a0 = 0.f, a1 = 0.f;
#pragma unroll 8
    for (int k = 0; k < 128; k += 2) {
      a0 = fmaf(xp[k],     mp[k * C],       a0);
      a1 = fmaf(xp[k + 1], mp[(k + 1) * C], a1);
    }
    if (n < N) g.out[task][grp][(size_t)n * H + h] = a0 + a1;
  }
}

// ---------------------------------------------------------------------------
// Fused multi-relation CSR aggregation (start/end segment arrays).
// ---------------------------------------------------------------------------
struct AggP {
  const int* st[3];
  const int* en[3];
  const int* csr[3];
  const float* el[3];
  const float* er[3];
  const unsigned short* zs[3];
  const float* bias;
  float* out;
  int Nd;
};

template<int H, int CPL, int NR>
__global__ __launch_bounds__(256)
void agg_multi(AggP a)
{
  constexpr int ELEMS = 64 * CPL;
  constexpr int F = ELEMS / H;
  const int lane = threadIdx.x & 63;
  const int n = blockIdx.x * 4 + (threadIdx.x >> 6);
  if (n >= a.Nd) return;

  const int hlane = (CPL * lane) / F;
  float vout[CPL];
#pragma unroll
  for (int j = 0; j < CPL; ++j) vout[j] = a.bias[CPL * lane + j];

#pragma unroll
  for (int r = 0; r < NR; ++r) {
    float erl = (lane < H) ? a.er[r][(size_t)n * H + lane] : 0.f;
    const float* el = a.el[r];
    const int* csr = a.csr[r];
    float accA[CPL], accB[CPL];
#pragma unroll
    for (int j = 0; j < CPL; ++j) { accA[j] = 0.f; accB[j] = 0.f; }
    float denA = 0.f, denB = 0.f;
    const int e0 = a.st[r][n], e1 = a.en[r][n];
    for (int eb = e0; eb < e1; eb += 64) {
      int sv = (eb + lane < e1) ? csr[eb + lane] : 0;
      int m = min(64, e1 - eb);
      int j = 0;
      for (; j + 2 <= m; j += 2) {
        int s0 = __shfl(sv, j, 64), s1 = __shfl(sv, j + 1, 64);
        float ex0 = 0.f, ex1 = 0.f;
        if (lane < H) {
          float v0 = el[s0 * H + lane] + erl;
          v0 = v0 > 0.f ? v0 : 0.2f * v0;
          ex0 = __expf(v0); denA += ex0;
          float v1 = el[s1 * H + lane] + erl;
          v1 = v1 > 0.f ? v1 : 0.2f * v1;
          ex1 = __expf(v1); denB += ex1;
        }
        float eh0 = __shfl(ex0, hlane, 64);
        float eh1 = __shfl(ex1, hlane, 64);
        if (CPL == 2) {
          unsigned z0 = ((const unsigned*)a.zs[r])[(size_t)s0 * (ELEMS / 2) + lane];
          unsigned z1 = ((const unsigned*)a.zs[r])[(size_t)s1 * (ELEMS / 2) + lane];
          accA[0] += eh0 * blo(z0); accA[CPL - 1] += eh0 * bhi(z0);
          accB[0] += eh1 * blo(z1); accB[CPL - 1] += eh1 * bhi(z1);
        } else {
          unsigned z0 = ((const unsigned short*)a.zs[r])[(size_t)s0 * ELEMS + lane];
          unsigned z1 = ((const unsigned short*)a.zs[r])[(size_t)s1 * ELEMS + lane];
          accA[0] += eh0 * blo(z0);
          accB[0] += eh1 * blo(z1);
        }
      }
      for (; j < m; ++j) {
        int s0 = __shfl(sv, j, 64);
        float ex0 = 0.f;
        if (lane < H) {
          float v0 = el[s0 * H + lane] + erl;
          v0 = v0 > 0.f ? v0 : 0.2f * v0;
          ex0 = __expf(v0); denA += ex0;
        }
        float eh0 = __shfl(ex0, hlane, 64);
        if (CPL == 2) {
          unsigned z0 = ((const unsigned*)a.zs[r])[(size_t)s0 * (ELEMS / 2) + lane];
          accA[0] += eh0 * blo(z0); accA[CPL - 1] += eh0 * bhi(z0);
        } else {
          unsigned z0 = ((const unsigned short*)a.zs[r])[(size_t)s0 * ELEMS + lane];
          accA[0] += eh0 * blo(z0);
        }
      }
    }
#pragma unroll
    for (int j = 0; j < CPL; ++j) {
      int x = CPL * lane + j;
      float dd = __shfl(denA + denB, x / F, 64);
      if (dd > 0.f) vout[j] += (accA[j] + accB[j]) / dd;
    }
  }
  if (CPL == 2) {
    float2 o; o.x = vout[0]; o.y = vout[CPL - 1];
    ((float2*)(a.out + (size_t)n * ELEMS))[lane] = o;
  } else {
    a.out[(size_t)n * ELEMS + lane] = vout[0];
  }
}

// ---------------------------------------------------------------------------
// Predictor: 16 lanes per edge, coalesced float4 row loads, shfl reduce.
// ---------------------------------------------------------------------------
__global__ __launch_bounds__(256)
void pred_dot(const float* __restrict__ h2a, const float* __restrict__ h2t,
              const int* __restrict__ ps, const int* __restrict__ pd,
              const int* __restrict__ ns, const int* __restrict__ nd,
              float* __restrict__ out, int Ep, int En)
{
  int t = blockIdx.x * 256 + threadIdx.x;
  int e = t >> 4, q = t & 15;
  if (e >= Ep + En) return;
  int s, d;
  if (e < Ep) { s = ps[e]; d = pd[e]; }
  else        { s = ns[e - Ep]; d = nd[e - Ep]; }
  float4 a = ((const float4*)(h2a + (size_t)s * 64))[q];
  float4 b = ((const float4*)(h2t + (size_t)d * 64))[q];
  float v = a.x * b.x + a.y * b.y + a.z * b.z + a.w * b.w;
  v += __shfl_xor(v, 8, 64);
  v += __shfl_xor(v, 4, 64);
  v += __shfl_xor(v, 2, 64);
  v += __shfl_xor(v, 1, 64);
  if (q == 0) out[e] = v;
}

// ---------------------------------------------------------------------------
extern "C" void kernel_launch(void* const* d_in, const int* in_sizes, int n_in,
                              void* d_out, int out_size, void* d_ws, size_t ws_size,
                              hipStream_t stream)
{
  (void)n_in; (void)out_size; (void)ws_size;
  const float* fUser = (const float*)d_in[0];
  const float* fArt  = (const float*)d_in[1];
  const float* fTag  = (const float*)d_in[2];
  const float* W1  = (const float*)d_in[3];
  const float* al1 = (const float*)d_in[4];
  const float* ar1 = (const float*)d_in[5];
  const float* b1  = (const float*)d_in[6];
  const float* W2  = (const float*)d_in[7];
  const float* al2 = (const float*)d_in[8];
  const float* ar2 = (const float*)d_in[9];
  const float* b2  = (const float*)d_in[10];
  const int* ix[14];
  for (int i = 0; i < 14; ++i) ix[i] = (const int*)d_in[11 + i];

  const int NU = in_sizes[0] / 128;
  const int NA = in_sizes[1] / 128;
  const int NT = in_sizes[2] / 128;
  const int E  = in_sizes[11];
  const int EN = in_sizes[23];

  char* p = (char*)d_ws;
  auto alloc = [&](size_t bytes) -> char* {
    char* r = p; p += (bytes + 255) & ~(size_t)255; return r;
  };

  const int dN1[6] = {NA, NU, NU, NU, NT, NA};
  const int sN1[6] = {NU, NA, NU, NU, NA, NT};
  const int sN2[3] = {NU, NT, NA};

  // ---- zero-init region: bucket counters + run cursors ----
  char* zbase = p;
  BArgs ba;
  ba.bcnt = (int*)alloc(6 * MAXB * 4);
  ba.gcur = (int*)alloc(6 * MAXB * 4);
  size_t zbytes = (size_t)(p - zbase);

  // ---- non-zero scratch ----
  ba.bbase = (int*)alloc(6 * MAXB * 4);
  int bpre = 0;
  for (int r = 0; r < 6; ++r) {
    ba.src[r] = ix[2 * r];
    ba.dst[r] = ix[2 * r + 1];
    ba.N[r] = dN1[r];
    ba.nb[r] = (dN1[r] + 127) >> 7;
    ba.bpre[r] = bpre;
    bpre += ba.nb[r];
    ba.stage[r] = (unsigned*)alloc((size_t)E * 4);
    ba.csr[r]   = (int*)alloc((size_t)E * 4);
    ba.st[r]    = (int*)alloc((size_t)dN1[r] * 4);
    ba.en[r]    = (int*)alloc((size_t)dN1[r] * 4);
  }
  unsigned short* Wz1 = (unsigned short*)alloc(6 * 16384 * 2);
  unsigned short* Wz2 = (unsigned short*)alloc(3 * 8192 * 2);
  float* war1  = (float*)alloc(6 * 512 * 4);
  float* wal1  = (float*)alloc(6 * 512 * 4);
  float* war2  = (float*)alloc(3 * 128 * 4);
  float* wal2  = (float*)alloc(3 * 128 * 4);
  float* bcomb = (float*)alloc(512 * 4);
  unsigned short* zs1[6]; float* el1[6]; float* er1[6];
  for (int r = 0; r < 6; ++r) {
    zs1[r] = (unsigned short*)alloc((size_t)sN1[r] * 128 * 2);
    el1[r] = (float*)alloc((size_t)sN1[r] * 4 * 4);
    er1[r] = (float*)alloc((size_t)dN1[r] * 4 * 4);
  }
  float* hU  = (float*)alloc((size_t)NU * 128 * 4);
  float* hA  = (float*)alloc((size_t)NA * 128 * 4);
  float* hT  = (float*)alloc((size_t)NT * 128 * 4);
  unsigned short* zs2[3]; float* el2[3]; float* er2[3];
  const int dN2[3] = {NA, NA, NT};
  for (int r = 0; r < 3; ++r) {
    zs2[r] = (unsigned short*)alloc((size_t)sN2[r] * 64 * 2);
    el2[r] = (float*)alloc((size_t)sN2[r] * 4);
    er2[r] = (float*)alloc((size_t)dN2[r] * 4);
  }
  float* h2a = (float*)alloc((size_t)NA * 64 * 4);
  float* h2t = (float*)alloc((size_t)NT * 64 * 4);

  hipMemsetAsync(zbase, 0, zbytes, stream);

  // ---- prep + bucketed CSR build ----
  prep<<<10, 256, 0, stream>>>(W1, al1, ar1, b1, W2, al2, ar2, b2,
                               Wz1, Wz2, war1, wal1, war2, wal2, bcomb);
  const int EBK = (E + BKE - 1) / BKE;
  bhist<<<6 * EBK, 256, 0, stream>>>(ba, E, EBK);
  bscan<<<6, 256, 0, stream>>>(ba);
  bscatter<<<6 * EBK, 256, 0, stream>>>(ba, E, EBK);
  bbuild<<<bpre, 256, 0, stream>>>(ba);

  // ---- layer 1: MFMA projections (Z bf16) ----
  {
    GemmM g;
    const float* sF1[6] = {fUser, fArt, fUser, fUser, fArt, fTag};
    int pre = 0;
    for (int r = 0; r < 6; ++r) {
      g.A[r] = sF1[r];
      g.Wz[r] = Wz1 + (size_t)r * 16384;
      g.Z[r] = zs1[r];
      g.N[r] = sN1[r];
      g.pre[r] = pre;
      pre += (sN1[r] + 63) / 64;
    }
    gemm_mfma<128><<<pre, 256, 0, stream>>>(g);
  }
  // ---- layer 1: all el/er dots ----
  {
    DotsB g = {};
    g.X[0] = fUser; g.N[0] = NU; g.NG[0] = 6;
    g.M[0][0] = wal1 + 0 * 512; g.out[0][0] = el1[0];
    g.M[0][1] = wal1 + 2 * 512; g.out[0][1] = el1[2];
    g.M[0][2] = wal1 + 3 * 512; g.out[0][2] = el1[3];
    g.M[0][3] = war1 + 1 * 512; g.out[0][3] = er1[1];
    g.M[0][4] = war1 + 2 * 512; g.out[0][4] = er1[2];
    g.M[0][5] = war1 + 3 * 512; g.out[0][5] = er1[3];
    g.X[1] = fArt; g.N[1] = NA; g.NG[1] = 4;
    g.M[1][0] = wal1 + 1 * 512; g.out[1][0] = el1[1];
    g.M[1][1] = wal1 + 4 * 512; g.out[1][1] = el1[4];
    g.M[1][2] = war1 + 0 * 512; g.out[1][2] = er1[0];
    g.M[1][3] = war1 + 5 * 512; g.out[1][3] = er1[5];
    g.X[2] = fTag; g.N[2] = NT; g.NG[2] = 2;
    g.M[2][0] = wal1 + 5 * 512; g.out[2][0] = el1[5];
    g.M[2][1] = war1 + 4 * 512; g.out[2][1] = er1[4];
    g.pre[0] = 0;
    g.pre[1] = (NU + 63) / 64;
    g.pre[2] = g.pre[1] + (NA + 63) / 64;
    int total = g.pre[2] + (NT + 63) / 64;
    node_dots<4, 6><<<total, 256, 0, stream>>>(g);
  }

  // ---- layer 1: fused per-dst-type aggregation ----
  {
    AggP a = {}; // artist: rels 0 (ua), 5 (ta)
    a.st[0]=ba.st[0]; a.en[0]=ba.en[0]; a.csr[0]=ba.csr[0]; a.el[0]=el1[0]; a.er[0]=er1[0]; a.zs[0]=zs1[0];
    a.st[1]=ba.st[5]; a.en[1]=ba.en[5]; a.csr[1]=ba.csr[5]; a.el[1]=el1[5]; a.er[1]=er1[5]; a.zs[1]=zs1[5];
    a.bias = bcomb + 128; a.out = hA; a.Nd = NA;
    agg_multi<4, 2, 2><<<(NA + 3) / 4, 256, 0, stream>>>(a);
  }
  {
    AggP a = {}; // user: rels 1 (au), 2 (uu0), 3 (uu1)
    a.st[0]=ba.st[1]; a.en[0]=ba.en[1]; a.csr[0]=ba.csr[1]; a.el[0]=el1[1]; a.er[0]=er1[1]; a.zs[0]=zs1[1];
    a.st[1]=ba.st[2]; a.en[1]=ba.en[2]; a.csr[1]=ba.csr[2]; a.el[1]=el1[2]; a.er[1]=er1[2]; a.zs[1]=zs1[2];
    a.st[2]=ba.st[3]; a.en[2]=ba.en[3]; a.csr[2]=ba.csr[3]; a.el[2]=el1[3]; a.er[2]=er1[3]; a.zs[2]=zs1[3];
    a.bias = bcomb; a.out = hU; a.Nd = NU;
    agg_multi<4, 2, 3><<<(NU + 3) / 4, 256, 0, stream>>>(a);
  }
  {
    AggP a = {}; // tag: rel 4 (at)
    a.st[0]=ba.st[4]; a.en[0]=ba.en[4]; a.csr[0]=ba.csr[4]; a.el[0]=el1[4]; a.er[0]=er1[4]; a.zs[0]=zs1[4];
    a.bias = bcomb + 256; a.out = hT; a.Nd = NT;
    agg_multi<4, 2, 1><<<(NT + 3) / 4, 256, 0, stream>>>(a);
  }

  // ---- layer 2: MFMA projections ----
  {
    GemmM g;
    const float* sF2[3] = {hU, hT, hA};
    int pre = 0;
    for (int r = 0; r < 3; ++r) {
      g.A[r] = sF2[r];
      g.Wz[r] = Wz2 + (size_t)r * 8192;
      g.Z[r] = zs2[r];
      g.N[r] = sN2[r];
      g.pre[r] = pre;
      pre += (sN2[r] + 63) / 64;
    }
    for (int r = 3; r < 6; ++r) {
      g.A[r] = nullptr; g.Wz[r] = nullptr; g.Z[r] = nullptr;
      g.N[r] = 0; g.pre[r] = 0x7fffffff;
    }
    gemm_mfma<64><<<pre, 256, 0, stream>>>(g);
  }
  // ---- layer 2: el/er dots ----
  {
    DotsB g = {};
    g.X[0] = hA; g.N[0] = NA; g.NG[0] = 3;
    g.M[0][0] = wal2 + 2 * 128; g.out[0][0] = el2[2];
    g.M[0][1] = war2 + 0 * 128; g.out[0][1] = er2[0];
    g.M[0][2] = war2 + 1 * 128; g.out[0][2] = er2[1];
    g.X[1] = hU; g.N[1] = NU; g.NG[1] = 1;
    g.M[1][0] = wal2 + 0 * 128; g.out[1][0] = el2[0];
    g.X[2] = hT; g.N[2] = NT; g.NG[2] = 2;
    g.M[2][0] = wal2 + 1 * 128; g.out[2][0] = el2[1];
    g.M[2][1] = war2 + 2 * 128; g.out[2][1] = er2[2];
    g.pre[0] = 0;
    g.pre[1] = (NA + 63) / 64;
    g.pre[2] = g.pre[1] + (NU + 63) / 64;
    int total = g.pre[2] + (NT + 63) / 64;
    node_dots<1, 3><<<total, 256, 0, stream>>>(g);
  }

  // ---- layer 2: fused aggregation (reuses CSRs 0/5/4) ----
  {
    AggP a = {}; // h2_artist: rels ua (csr0) + ta (csr5)
    a.st[0]=ba.st[0]; a.en[0]=ba.en[0]; a.csr[0]=ba.csr[0]; a.el[0]=el2[0]; a.er[0]=er2[0]; a.zs[0]=zs2[0];
    a.st[1]=ba.st[5]; a.en[1]=ba.en[5]; a.csr[1]=ba.csr[5]; a.el[1]=el2[1]; a.er[1]=er2[1]; a.zs[1]=zs2[1];
    a.bias = bcomb + 384; a.out = h2a; a.Nd = NA;
    agg_multi<1, 1, 2><<<(NA + 3) / 4, 256, 0, stream>>>(a);
  }
  {
    AggP a = {}; // h2_tag: rel at (csr4)
    a.st[0]=ba.st[4]; a.en[0]=ba.en[4]; a.csr[0]=ba.csr[4]; a.el[0]=el2[2]; a.er[0]=er2[2]; a.zs[0]=zs2[2];
    a.bias = bcomb + 448; a.out = h2t; a.Nd = NT;
    agg_multi<1, 1, 1><<<(NT + 3) / 4, 256, 0, stream>>>(a);
  }

  // ---- predictor ----
  pred_dot<<<(int)(((size_t)(E + EN) * 16 + 255) / 256), 256, 0, stream>>>(
      h2a, h2t, ix[8], ix[9], ix[12], ix[13], (float*)d_out, E, EN);
}

// Round 10
// 227.383 us; speedup vs baseline: 1.8573x; 1.2008x over previous
//
#include <hip/hip_runtime.h>

#define DEVI __device__ __forceinline__

typedef __attribute__((ext_vector_type(8))) short short8v;
typedef __attribute__((ext_vector_type(4))) float f32x4;

DEVI float blo(unsigned u){ return __uint_as_float(u << 16); }
DEVI float bhi(unsigned u){ return __uint_as_float(u & 0xffff0000u); }
DEVI unsigned short f2bu(float f){          // f32 -> bf16 bits, RNE
  unsigned u = __float_as_uint(f);
  return (unsigned short)((u + 0x7fffu + ((u >> 16) & 1u)) >> 16);
}

#define MAXB 160          // max buckets per relation (ceil(20000/128)=157)
#define BKE  4096         // edges per block in bucket passes

// ---------------------------------------------------------------------------
// Bucketed CSR build: contiguous-run global writes only.
// ---------------------------------------------------------------------------
struct BArgs {
  const int* src[6];
  const int* dst[6];
  int* bcnt;
  int* bbase;
  int* gcur;
  unsigned* stage[6];
  int* csr[6];
  int* st[6];
  int* en[6];
  int nb[6];
  int N[6];
  int bpre[6];
};

__global__ __launch_bounds__(256)
void bhist(BArgs a, int E, int ebks) {
  __shared__ int h[MAXB];
  int r = blockIdx.x / ebks;
  int base = (blockIdx.x - r * ebks) * BKE;
  for (int i = threadIdx.x; i < MAXB; i += 256) h[i] = 0;
  __syncthreads();
  const int* dst = a.dst[r];
#pragma unroll
  for (int k = 0; k < 16; ++k) {
    int e = base + threadIdx.x + k * 256;
    if (e < E) atomicAdd(&h[dst[e] >> 7], 1);
  }
  __syncthreads();
  int NB = a.nb[r];
  for (int i = threadIdx.x; i < NB; i += 256)
    if (h[i]) atomicAdd(&a.bcnt[r * MAXB + i], h[i]);
}

__global__ __launch_bounds__(256)
void bscan(BArgs a) {
  __shared__ int ps[256];
  int r = blockIdx.x;
  int NB = a.nb[r];
  int t = threadIdx.x;
  int v = (t < NB) ? a.bcnt[r * MAXB + t] : 0;
  ps[t] = v;
  __syncthreads();
  for (int d = 1; d < 256; d <<= 1) {
    int x = (t >= d) ? ps[t - d] : 0;
    __syncthreads();
    ps[t] += x;
    __syncthreads();
  }
  if (t < NB) a.bbase[r * MAXB + t] = ps[t] - v;
}

__global__ __launch_bounds__(256)
void bscatter(BArgs a, int E, int ebks) {
  __shared__ int hist[MAXB];
  __shared__ int pref[MAXB];
  __shared__ int cur[MAXB];
  __shared__ int runb[MAXB];
  __shared__ int ps[256];
  __shared__ unsigned stag[BKE];
  __shared__ unsigned char dig8[BKE];
  int r = blockIdx.x / ebks;
  int base = (blockIdx.x - r * ebks) * BKE;
  int cnt = min(BKE, E - base);
  int NB = a.nb[r];
  for (int i = threadIdx.x; i < MAXB; i += 256) hist[i] = 0;
  __syncthreads();
  const int* dst = a.dst[r];
  const int* src = a.src[r];
  int ed[16], sd[16];
#pragma unroll
  for (int k = 0; k < 16; ++k) {
    int e = base + threadIdx.x + k * 256;
    if (e < E) { ed[k] = dst[e]; sd[k] = src[e]; atomicAdd(&hist[ed[k] >> 7], 1); }
    else ed[k] = -1;
  }
  __syncthreads();
  {
    int t = threadIdx.x;
    int v = (t < NB) ? hist[t] : 0;
    ps[t] = v;
    __syncthreads();
    for (int d = 1; d < 256; d <<= 1) {
      int x = (t >= d) ? ps[t - d] : 0;
      __syncthreads();
      ps[t] += x;
      __syncthreads();
    }
    if (t < NB) { pref[t] = ps[t] - v; cur[t] = ps[t] - v; }
  }
  __syncthreads();
#pragma unroll
  for (int k = 0; k < 16; ++k) {
    if (ed[k] >= 0) {
      int dg = ed[k] >> 7;
      int pos = atomicAdd(&cur[dg], 1);
      stag[pos] = ((unsigned)sd[k] << 7) | (unsigned)(ed[k] & 127);
      dig8[pos] = (unsigned char)dg;
    }
  }
  __syncthreads();
  for (int i = threadIdx.x; i < NB; i += 256) {
    int len = hist[i];
    runb[i] = len ? (a.bbase[r * MAXB + i] + atomicAdd(&a.gcur[r * MAXB + i], len)) : 0;
  }
  __syncthreads();
  unsigned* sg = a.stage[r];
  for (int i = threadIdx.x; i < cnt; i += 256) {
    int dg = dig8[i];
    sg[runb[dg] + (i - pref[dg])] = stag[i];
  }
}

__global__ __launch_bounds__(256)
void bbuild(BArgs a) {
  __shared__ int hist[128];
  __shared__ int pref[129];
  __shared__ int cur[128];
  __shared__ int ps[256];
  __shared__ int loc[8192];
  int r = 0;
#pragma unroll
  for (int i = 1; i < 6; ++i) if ((int)blockIdx.x >= a.bpre[i]) r = i;
  int b = (int)blockIdx.x - a.bpre[r];
  int cnt = a.bcnt[r * MAXB + b];
  int base = a.bbase[r * MAXB + b];
  int n0 = b << 7;
  int N = a.N[r];
  for (int i = threadIdx.x; i < 128; i += 256) hist[i] = 0;
  __syncthreads();
  const unsigned* sg = a.stage[r] + base;
  for (int i = threadIdx.x; i < cnt; i += 256) atomicAdd(&hist[sg[i] & 127], 1);
  __syncthreads();
  {
    int t = threadIdx.x;
    int v = (t < 128) ? hist[t] : 0;
    ps[t] = v;
    __syncthreads();
    for (int d = 1; d < 128; d <<= 1) {
      int x = (t >= d) ? ps[t - d] : 0;
      __syncthreads();
      ps[t] += x;
      __syncthreads();
    }
    if (t < 128) { pref[t] = ps[t] - v; cur[t] = ps[t] - v; }
    if (t == 127) pref[128] = ps[127];
  }
  __syncthreads();
  for (int i = threadIdx.x; i < cnt; i += 256) {
    unsigned v = sg[i];
    int pos = atomicAdd(&cur[v & 127], 1);
    loc[pos] = (int)(v >> 7);
  }
  __syncthreads();
  int* csr = a.csr[r];
  for (int i = threadIdx.x; i < cnt; i += 256) csr[base + i] = loc[i];
  if (threadIdx.x < 128) {
    int n = n0 + threadIdx.x;
    if (n < N) {
      a.st[r][n] = base + pref[threadIdx.x];
      a.en[r][n] = base + pref[threadIdx.x + 1];
    }
  }
}

// ---------------------------------------------------------------------------
// prep: fold W@ar -> war, W@al -> wal; W -> bf16 MFMA-fragment order; biases.
// ---------------------------------------------------------------------------
__global__ __launch_bounds__(256)
void prep(const float* __restrict__ W1, const float* __restrict__ al1,
          const float* __restrict__ ar1, const float* __restrict__ b1,
          const float* __restrict__ W2, const float* __restrict__ al2,
          const float* __restrict__ ar2, const float* __restrict__ b2,
          unsigned short* __restrict__ Wz1, unsigned short* __restrict__ Wz2,
          float* __restrict__ war1, float* __restrict__ wal1,
          float* __restrict__ war2, float* __restrict__ wal2,
          float* __restrict__ bcomb)
{
  int b = blockIdx.x, t = threadIdx.x;
  if (b < 6) {
    const float* W = W1 + b * 16384;
    unsigned short* Wz = Wz1 + b * 16384;
    for (int i = t; i < 16384; i += 256) {
      int j = i & 7, c = (i >> 3) & 127, kc = i >> 10;
      Wz[i] = f2bu(W[(kc * 8 + j) * 128 + c]);
    }
    for (int i = t; i < 512; i += 256) {
      int k = i >> 2, h = i & 3;
      float sr = 0.f, sl = 0.f;
      for (int f = 0; f < 32; ++f) {
        float w = W[k * 128 + h * 32 + f];
        sr += w * ar1[b * 128 + h * 32 + f];
        sl += w * al1[b * 128 + h * 32 + f];
      }
      war1[b * 512 + i] = sr;
      wal1[b * 512 + i] = sl;
    }
  } else if (b < 9) {
    int w = (b == 6) ? 0 : (b == 7) ? 5 : 4;
    const float* W = W2 + w * 8192;
    unsigned short* Wz = Wz2 + (b - 6) * 8192;
    for (int i = t; i < 8192; i += 256) {
      int j = i & 7, c = (i >> 3) & 63, kc = i >> 9;
      Wz[i] = f2bu(W[(kc * 8 + j) * 64 + c]);
    }
    if (t < 128) {
      float sr = 0.f, sl = 0.f;
      for (int f = 0; f < 64; ++f) {
        float x = W[t * 64 + f];
        sr += x * ar2[w * 64 + f];
        sl += x * al2[w * 64 + f];
      }
      war2[(b - 6) * 128 + t] = sr;
      wal2[(b - 6) * 128 + t] = sl;
    }
  } else {
    if (t < 128) {
      bcomb[t]       = b1[128 + t] + b1[256 + t] + b1[384 + t]; // user
      bcomb[128 + t] = b1[t] + b1[640 + t];                     // artist
      bcomb[256 + t] = b1[512 + t];                             // tag
    } else if (t < 192) {
      int x = t - 128;
      bcomb[384 + x] = b2[x] + b2[320 + x];                     // h2 artist
      bcomb[448 + x] = b2[256 + x];                             // h2 tag
    }
  }
}

// ---------------------------------------------------------------------------
// MFMA projection GEMM, batched over relations.
// ---------------------------------------------------------------------------
struct GemmM {
  const float* A[6];
  const unsigned short* Wz[6];
  unsigned short* Z[6];
  int N[6];
  int pre[6];
};

template<int KOUT>
__global__ __launch_bounds__(256)
void gemm_mfma(GemmM g)
{
  constexpr int NCT = KOUT / 64;
  int r = 0;
#pragma unroll
  for (int i = 1; i < 6; ++i) if ((int)blockIdx.x >= g.pre[i]) r = i;
  const float* A = g.A[r];
  const short8v* Wp = (const short8v*)g.Wz[r];
  unsigned short* Z = g.Z[r];
  const int N = g.N[r];
  const int row0 = (blockIdx.x - g.pre[r]) * 64;

  __shared__ short8v a_lds[64 * 16];
  for (int i = threadIdx.x; i < 64 * 16; i += 256) {
    int row = i >> 4, c8 = i & 15;
    int grow = row0 + row;
    short8v v;
    if (grow < N) {
      const float4* ap = (const float4*)(A + (size_t)grow * 128 + c8 * 8);
      float4 x0 = ap[0], x1 = ap[1];
      v[0] = (short)f2bu(x0.x); v[1] = (short)f2bu(x0.y);
      v[2] = (short)f2bu(x0.z); v[3] = (short)f2bu(x0.w);
      v[4] = (short)f2bu(x1.x); v[5] = (short)f2bu(x1.y);
      v[6] = (short)f2bu(x1.z); v[7] = (short)f2bu(x1.w);
    } else {
      v = short8v{0, 0, 0, 0, 0, 0, 0, 0};
    }
    a_lds[row * 16 + (c8 ^ (row & 7))] = v;
  }
  __syncthreads();

  const int wv = threadIdx.x >> 6;
  const int lane = threadIdx.x & 63;
  const int lrow = lane & 15, lkg = lane >> 4;

  f32x4 acc[4][NCT];
#pragma unroll
  for (int rt = 0; rt < 4; ++rt)
#pragma unroll
    for (int c = 0; c < NCT; ++c) acc[rt][c] = f32x4{0.f, 0.f, 0.f, 0.f};

#pragma unroll
  for (int ks = 0; ks < 4; ++ks) {
    const int kc = ks * 4 + lkg;
    short8v bfr[NCT];
#pragma unroll
    for (int c = 0; c < NCT; ++c)
      bfr[c] = Wp[kc * KOUT + (wv * NCT + c) * 16 + lrow];
#pragma unroll
    for (int rt = 0; rt < 4; ++rt) {
      int row = rt * 16 + lrow;
      short8v afr = a_lds[row * 16 + (kc ^ (row & 7))];
#pragma unroll
      for (int c = 0; c < NCT; ++c)
        acc[rt][c] = __builtin_amdgcn_mfma_f32_16x16x32_bf16(afr, bfr[c], acc[rt][c], 0, 0, 0);
    }
  }

#pragma unroll
  for (int rt = 0; rt < 4; ++rt)
#pragma unroll
    for (int c = 0; c < NCT; ++c) {
      int col = (wv * NCT + c) * 16 + lrow;
#pragma unroll
      for (int q = 0; q < 4; ++q) {
        int grow = row0 + rt * 16 + lkg * 4 + q;
        if (grow < N) Z[(size_t)grow * KOUT + col] = f2bu(acc[rt][c][q]);
      }
    }
}

// ---------------------------------------------------------------------------
// node_dots: all el/er columns per node type; no cross-lane ops.
// ---------------------------------------------------------------------------
struct DotsB {
  const float* X[3];
  const float* M[3][6];
  float* out[3][6];
  int NG[3];
  int N[3];
  int pre[3];
};

template<int H, int MAXG>
__global__ __launch_bounds__(256)
void node_dots(DotsB g)
{
  int task = 0;
#pragma unroll
  for (int i = 1; i < 3; ++i) if ((int)blockIdx.x >= g.pre[i]) task = i;
  const int NG = g.NG[task];
  const int C = NG * H;
  const float* X = g.X[task];
  const int N = g.N[task];
  const int n0 = (blockIdx.x - g.pre[task]) * 64;

  __shared__ float Xs[64 * 129];
  __shared__ float Ms[128 * MAXG * H];
  for (int i = threadIdx.x; i < 128 * C; i += 256) {
    int k = i / C, c = i - k * C;
    int grp = c / H, h = c - grp * H;
    Ms[i] = g.M[task][grp][k * H + h];
  }
  for (int i = threadIdx.x; i < 64 * 32; i += 256) {
    int row = i >> 5, kk = i & 31;
    int n = n0 + row;
    float4 v;
    if (n < N) v = ((const float4*)(X + (size_t)n * 128))[kk];
    else { v.x = 0.f; v.y = 0.f; v.z = 0.f; v.w = 0.f; }
    float* xp = &Xs[row * 129 + kk * 4];
    xp[0] = v.x; xp[1] = v.y; xp[2] = v.z; xp[3] = v.w;
  }
  __syncthreads();

  const int lane = threadIdx.x & 63;
  const int wv = threadIdx.x >> 6;
  const int n = n0 + lane;
  const float* xp = &Xs[lane * 129];
  for (int c = wv; c < C; c += 4) {
    int grp = c / H, h = c - grp * H;
    const float* mp = &Ms[c];
    float a0 = 0.f, a1 = 0.f;
#pragma unroll 8
    for (int k = 0; k < 128; k += 2) {
      a0 = fmaf(xp[k],     mp[k * C],       a0);
      a1 = fmaf(xp[k + 1], mp[(k + 1) * C], a1);
    }
    if (n < N) g.out[task][grp][(size_t)n * H + h] = a0 + a1;
  }
}

// ---------------------------------------------------------------------------
// Fused multi-relation CSR aggregation, v3 (fixed): every lane computes exp
// for its own head (broadcast el load), per-lane den; 4-edge ILP.
// ---------------------------------------------------------------------------
struct AggP {
  const int* st[3];
  const int* en[3];
  const int* csr[3];
  const float* el[3];
  const float* er[3];
  const unsigned short* zs[3];
  const float* bias;
  float* out;
  int Nd;
};

template<int H, int CPL, int NR>
__global__ __launch_bounds__(256)
void agg_multi(AggP a)
{
  constexpr int ELEMS = 64 * CPL;
  constexpr int F = ELEMS / H;        // cols per head
  constexpr int LPH = F / CPL;        // lanes per head
  const int lane = threadIdx.x & 63;
  const int n = blockIdx.x * 4 + (threadIdx.x >> 6);
  if (n >= a.Nd) return;
  const int hl = lane / LPH;          // this lane's head

  float vout[CPL];
#pragma unroll
  for (int j = 0; j < CPL; ++j) vout[j] = a.bias[CPL * lane + j];

#pragma unroll
  for (int r = 0; r < NR; ++r) {
    const float erl = a.er[r][(size_t)n * H + hl];
    const float* el = a.el[r];
    const int* csr = a.csr[r];
    const unsigned* zp2 = (const unsigned*)a.zs[r];
    const unsigned short* zp1 = a.zs[r];
    float accA[CPL], accB[CPL];
#pragma unroll
    for (int j = 0; j < CPL; ++j) { accA[j] = 0.f; accB[j] = 0.f; }
    float denA = 0.f, denB = 0.f;
    const int e0 = a.st[r][n], e1 = a.en[r][n];
    for (int eb = e0; eb < e1; eb += 64) {
      int sv = (eb + lane < e1) ? csr[eb + lane] : 0;
      int m = min(64, e1 - eb);
      int j = 0;
      for (; j + 4 <= m; j += 4) {
        int s0 = __shfl(sv, j, 64),     s1 = __shfl(sv, j + 1, 64);
        int s2 = __shfl(sv, j + 2, 64), s3 = __shfl(sv, j + 3, 64);
        float q0 = el[s0 * H + hl], q1 = el[s1 * H + hl];
        float q2 = el[s2 * H + hl], q3 = el[s3 * H + hl];
        if (CPL == 2) {
          unsigned z0 = zp2[(size_t)s0 * 64 + lane];
          unsigned z1 = zp2[(size_t)s1 * 64 + lane];
          unsigned z2 = zp2[(size_t)s2 * 64 + lane];
          unsigned z3 = zp2[(size_t)s3 * 64 + lane];
          float v0 = q0 + erl; v0 = v0 > 0.f ? v0 : 0.2f * v0;
          float v1 = q1 + erl; v1 = v1 > 0.f ? v1 : 0.2f * v1;
          float v2 = q2 + erl; v2 = v2 > 0.f ? v2 : 0.2f * v2;
          float v3 = q3 + erl; v3 = v3 > 0.f ? v3 : 0.2f * v3;
          float ex0 = __expf(v0), ex1 = __expf(v1);
          float ex2 = __expf(v2), ex3 = __expf(v3);
          denA += ex0 + ex2; denB += ex1 + ex3;
          accA[0] += ex0 * blo(z0); accA[CPL - 1] += ex0 * bhi(z0);
          accB[0] += ex1 * blo(z1); accB[CPL - 1] += ex1 * bhi(z1);
          accA[0] += ex2 * blo(z2); accA[CPL - 1] += ex2 * bhi(z2);
          accB[0] += ex3 * blo(z3); accB[CPL - 1] += ex3 * bhi(z3);
        } else {
          unsigned z0 = zp1[(size_t)s0 * 64 + lane];
          unsigned z1 = zp1[(size_t)s1 * 64 + lane];
          unsigned z2 = zp1[(size_t)s2 * 64 + lane];
          unsigned z3 = zp1[(size_t)s3 * 64 + lane];
          float v0 = q0 + erl; v0 = v0 > 0.f ? v0 : 0.2f * v0;
          float v1 = q1 + erl; v1 = v1 > 0.f ? v1 : 0.2f * v1;
          float v2 = q2 + erl; v2 = v2 > 0.f ? v2 : 0.2f * v2;
          float v3 = q3 + erl; v3 = v3 > 0.f ? v3 : 0.2f * v3;
          float ex0 = __expf(v0), ex1 = __expf(v1);
          float ex2 = __expf(v2), ex3 = __expf(v3);
          denA += ex0 + ex2; denB += ex1 + ex3;
          accA[0] += ex0 * blo(z0);   // z in low 16 bits; blo() does the <<16
          accB[0] += ex1 * blo(z1);
          accA[0] += ex2 * blo(z2);
          accB[0] += ex3 * blo(z3);
        }
      }
      for (; j < m; ++j) {
        int s0 = __shfl(sv, j, 64);
        float q0 = el[s0 * H + hl];
        float v0 = q0 + erl; v0 = v0 > 0.f ? v0 : 0.2f * v0;
        float ex0 = __expf(v0);
        denA += ex0;
        if (CPL == 2) {
          unsigned z0 = zp2[(size_t)s0 * 64 + lane];
          accA[0] += ex0 * blo(z0); accA[CPL - 1] += ex0 * bhi(z0);
        } else {
          unsigned z0 = zp1[(size_t)s0 * 64 + lane];
          accA[0] += ex0 * blo(z0);
        }
      }
    }
    float dd = denA + denB;   // full per-head denom (every lane has it)
    if (dd > 0.f) {
#pragma unroll
      for (int j = 0; j < CPL; ++j) vout[j] += (accA[j] + accB[j]) / dd;
    }
  }
  if (CPL == 2) {
    float2 o; o.x = vout[0]; o.y = vout[CPL - 1];
    ((float2*)(a.out + (size_t)n * ELEMS))[lane] = o;
  } else {
    a.out[(size_t)n * ELEMS + lane] = vout[0];
  }
}

// ---------------------------------------------------------------------------
// Predictor: 16 lanes per edge, coalesced float4 row loads, shfl reduce.
// ---------------------------------------------------------------------------
__global__ __launch_bounds__(256)
void pred_dot(const float* __restrict__ h2a, const float* __restrict__ h2t,
              const int* __restrict__ ps, const int* __restrict__ pd,
              const int* __restrict__ ns, const int* __restrict__ nd,
              float* __restrict__ out, int Ep, int En)
{
  int t = blockIdx.x * 256 + threadIdx.x;
  int e = t >> 4, q = t & 15;
  if (e >= Ep + En) return;
  int s, d;
  if (e < Ep) { s = ps[e]; d = pd[e]; }
  else        { s = ns[e - Ep]; d = nd[e - Ep]; }
  float4 a = ((const float4*)(h2a + (size_t)s * 64))[q];
  float4 b = ((const float4*)(h2t + (size_t)d * 64))[q];
  float v = a.x * b.x + a.y * b.y + a.z * b.z + a.w * b.w;
  v += __shfl_xor(v, 8, 64);
  v += __shfl_xor(v, 4, 64);
  v += __shfl_xor(v, 2, 64);
  v += __shfl_xor(v, 1, 64);
  if (q == 0) out[e] = v;
}

// ---------------------------------------------------------------------------
extern "C" void kernel_launch(void* const* d_in, const int* in_sizes, int n_in,
                              void* d_out, int out_size, void* d_ws, size_t ws_size,
                              hipStream_t stream)
{
  (void)n_in; (void)out_size; (void)ws_size;
  const float* fUser = (const float*)d_in[0];
  const float* fArt  = (const float*)d_in[1];
  const float* fTag  = (const float*)d_in[2];
  const float* W1  = (const float*)d_in[3];
  const float* al1 = (const float*)d_in[4];
  const float* ar1 = (const float*)d_in[5];
  const float* b1  = (const float*)d_in[6];
  const float* W2  = (const float*)d_in[7];
  const float* al2 = (const float*)d_in[8];
  const float* ar2 = (const float*)d_in[9];
  const float* b2  = (const float*)d_in[10];
  const int* ix[14];
  for (int i = 0; i < 14; ++i) ix[i] = (const int*)d_in[11 + i];

  const int NU = in_sizes[0] / 128;
  const int NA = in_sizes[1] / 128;
  const int NT = in_sizes[2] / 128;
  const int E  = in_sizes[11];
  const int EN = in_sizes[23];

  char* p = (char*)d_ws;
  auto alloc = [&](size_t bytes) -> char* {
    char* r = p; p += (bytes + 255) & ~(size_t)255; return r;
  };

  const int dN1[6] = {NA, NU, NU, NU, NT, NA};
  const int sN1[6] = {NU, NA, NU, NU, NA, NT};
  const int sN2[3] = {NU, NT, NA};

  // ---- zero-init region: bucket counters + run cursors ----
  char* zbase = p;
  BArgs ba;
  ba.bcnt = (int*)alloc(6 * MAXB * 4);
  ba.gcur = (int*)alloc(6 * MAXB * 4);
  size_t zbytes = (size_t)(p - zbase);

  // ---- non-zero scratch ----
  ba.bbase = (int*)alloc(6 * MAXB * 4);
  int bpre = 0;
  for (int r = 0; r < 6; ++r) {
    ba.src[r] = ix[2 * r];
    ba.dst[r] = ix[2 * r + 1];
    ba.N[r] = dN1[r];
    ba.nb[r] = (dN1[r] + 127) >> 7;
    ba.bpre[r] = bpre;
    bpre += ba.nb[r];
    ba.stage[r] = (unsigned*)alloc((size_t)E * 4);
    ba.csr[r]   = (int*)alloc((size_t)E * 4);
    ba.st[r]    = (int*)alloc((size_t)dN1[r] * 4);
    ba.en[r]    = (int*)alloc((size_t)dN1[r] * 4);
  }
  unsigned short* Wz1 = (unsigned short*)alloc(6 * 16384 * 2);
  unsigned short* Wz2 = (unsigned short*)alloc(3 * 8192 * 2);
  float* war1  = (float*)alloc(6 * 512 * 4);
  float* wal1  = (float*)alloc(6 * 512 * 4);
  float* war2  = (float*)alloc(3 * 128 * 4);
  float* wal2  = (float*)alloc(3 * 128 * 4);
  float* bcomb = (float*)alloc(512 * 4);
  unsigned short* zs1[6]; float* el1[6]; float* er1[6];
  for (int r = 0; r < 6; ++r) {
    zs1[r] = (unsigned short*)alloc((size_t)sN1[r] * 128 * 2);
    el1[r] = (float*)alloc((size_t)sN1[r] * 4 * 4);
    er1[r] = (float*)alloc((size_t)dN1[r] * 4 * 4);
  }
  float* hU  = (float*)alloc((size_t)NU * 128 * 4);
  float* hA  = (float*)alloc((size_t)NA * 128 * 4);
  float* hT  = (float*)alloc((size_t)NT * 128 * 4);
  unsigned short* zs2[3]; float* el2[3]; float* er2[3];
  const int dN2[3] = {NA, NA, NT};
  for (int r = 0; r < 3; ++r) {
    zs2[r] = (unsigned short*)alloc((size_t)sN2[r] * 64 * 2);
    el2[r] = (float*)alloc((size_t)sN2[r] * 4);
    er2[r] = (float*)alloc((size_t)dN2[r] * 4);
  }
  float* h2a = (float*)alloc((size_t)NA * 64 * 4);
  float* h2t = (float*)alloc((size_t)NT * 64 * 4);

  hipMemsetAsync(zbase, 0, zbytes, stream);

  // ---- prep + bucketed CSR build ----
  prep<<<10, 256, 0, stream>>>(W1, al1, ar1, b1, W2, al2, ar2, b2,
                               Wz1, Wz2, war1, wal1, war2, wal2, bcomb);
  const int EBK = (E + BKE - 1) / BKE;
  bhist<<<6 * EBK, 256, 0, stream>>>(ba, E, EBK);
  bscan<<<6, 256, 0, stream>>>(ba);
  bscatter<<<6 * EBK, 256, 0, stream>>>(ba, E, EBK);
  bbuild<<<bpre, 256, 0, stream>>>(ba);

  // ---- layer 1: MFMA projections (Z bf16) ----
  {
    GemmM g;
    const float* sF1[6] = {fUser, fArt, fUser, fUser, fArt, fTag};
    int pre = 0;
    for (int r = 0; r < 6; ++r) {
      g.A[r] = sF1[r];
      g.Wz[r] = Wz1 + (size_t)r * 16384;
      g.Z[r] = zs1[r];
      g.N[r] = sN1[r];
      g.pre[r] = pre;
      pre += (sN1[r] + 63) / 64;
    }
    gemm_mfma<128><<<pre, 256, 0, stream>>>(g);
  }
  // ---- layer 1: all el/er dots ----
  {
    DotsB g = {};
    g.X[0] = fUser; g.N[0] = NU; g.NG[0] = 6;
    g.M[0][0] = wal1 + 0 * 512; g.out[0][0] = el1[0];
    g.M[0][1] = wal1 + 2 * 512; g.out[0][1] = el1[2];
    g.M[0][2] = wal1 + 3 * 512; g.out[0][2] = el1[3];
    g.M[0][3] = war1 + 1 * 512; g.out[0][3] = er1[1];
    g.M[0][4] = war1 + 2 * 512; g.out[0][4] = er1[2];
    g.M[0][5] = war1 + 3 * 512; g.out[0][5] = er1[3];
    g.X[1] = fArt; g.N[1] = NA; g.NG[1] = 4;
    g.M[1][0] = wal1 + 1 * 512; g.out[1][0] = el1[1];
    g.M[1][1] = wal1 + 4 * 512; g.out[1][1] = el1[4];
    g.M[1][2] = war1 + 0 * 512; g.out[1][2] = er1[0];
    g.M[1][3] = war1 + 5 * 512; g.out[1][3] = er1[5];
    g.X[2] = fTag; g.N[2] = NT; g.NG[2] = 2;
    g.M[2][0] = wal1 + 5 * 512; g.out[2][0] = el1[5];
    g.M[2][1] = war1 + 4 * 512; g.out[2][1] = er1[4];
    g.pre[0] = 0;
    g.pre[1] = (NU + 63) / 64;
    g.pre[2] = g.pre[1] + (NA + 63) / 64;
    int total = g.pre[2] + (NT + 63) / 64;
    node_dots<4, 6><<<total, 256, 0, stream>>>(g);
  }

  // ---- layer 1: fused per-dst-type aggregation ----
  {
    AggP a = {}; // artist: rels 0 (ua), 5 (ta)
    a.st[0]=ba.st[0]; a.en[0]=ba.en[0]; a.csr[0]=ba.csr[0]; a.el[0]=el1[0]; a.er[0]=er1[0]; a.zs[0]=zs1[0];
    a.st[1]=ba.st[5]; a.en[1]=ba.en[5]; a.csr[1]=ba.csr[5]; a.el[1]=el1[5]; a.er[1]=er1[5]; a.zs[1]=zs1[5];
    a.bias = bcomb + 128; a.out = hA; a.Nd = NA;
    agg_multi<4, 2, 2><<<(NA + 3) / 4, 256, 0, stream>>>(a);
  }
  {
    AggP a = {}; // user: rels 1 (au), 2 (uu0), 3 (uu1)
    a.st[0]=ba.st[1]; a.en[0]=ba.en[1]; a.csr[0]=ba.csr[1]; a.el[0]=el1[1]; a.er[0]=er1[1]; a.zs[0]=zs1[1];
    a.st[1]=ba.st[2]; a.en[1]=ba.en[2]; a.csr[1]=ba.csr[2]; a.el[1]=el1[2]; a.er[1]=er1[2]; a.zs[1]=zs1[2];
    a.st[2]=ba.st[3]; a.en[2]=ba.en[3]; a.csr[2]=ba.csr[3]; a.el[2]=el1[3]; a.er[2]=er1[3]; a.zs[2]=zs1[3];
    a.bias = bcomb; a.out = hU; a.Nd = NU;
    agg_multi<4, 2, 3><<<(NU + 3) / 4, 256, 0, stream>>>(a);
  }
  {
    AggP a = {}; // tag: rel 4 (at)
    a.st[0]=ba.st[4]; a.en[0]=ba.en[4]; a.csr[0]=ba.csr[4]; a.el[0]=el1[4]; a.er[0]=er1[4]; a.zs[0]=zs1[4];
    a.bias = bcomb + 256; a.out = hT; a.Nd = NT;
    agg_multi<4, 2, 1><<<(NT + 3) / 4, 256, 0, stream>>>(a);
  }

  // ---- layer 2: MFMA projections ----
  {
    GemmM g;
    const float* sF2[3] = {hU, hT, hA};
    int pre = 0;
    for (int r = 0; r < 3; ++r) {
      g.A[r] = sF2[r];
      g.Wz[r] = Wz2 + (size_t)r * 8192;
      g.Z[r] = zs2[r];
      g.N[r] = sN2[r];
      g.pre[r] = pre;
      pre += (sN2[r] + 63) / 64;
    }
    for (int r = 3; r < 6; ++r) {
      g.A[r] = nullptr; g.Wz[r] = nullptr; g.Z[r] = nullptr;
      g.N[r] = 0; g.pre[r] = 0x7fffffff;
    }
    gemm_mfma<64><<<pre, 256, 0, stream>>>(g);
  }
  // ---- layer 2: el/er dots ----
  {
    DotsB g = {};
    g.X[0] = hA; g.N[0] = NA; g.NG[0] = 3;
    g.M[0][0] = wal2 + 2 * 128; g.out[0][0] = el2[2];
    g.M[0][1] = war2 + 0 * 128; g.out[0][1] = er2[0];
    g.M[0][2] = war2 + 1 * 128; g.out[0][2] = er2[1];
    g.X[1] = hU; g.N[1] = NU; g.NG[1] = 1;
    g.M[1][0] = wal2 + 0 * 128; g.out[1][0] = el2[0];
    g.X[2] = hT; g.N[2] = NT; g.NG[2] = 2;
    g.M[2][0] = wal2 + 1 * 128; g.out[2][0] = el2[1];
    g.M[2][1] = war2 + 2 * 128; g.out[2][1] = er2[2];
    g.pre[0] = 0;
    g.pre[1] = (NA + 63) / 64;
    g.pre[2] = g.pre[1] + (NU + 63) / 64;
    int total = g.pre[2] + (NT + 63) / 64;
    node_dots<1, 3><<<total, 256, 0, stream>>>(g);
  }

  // ---- layer 2: fused aggregation (reuses CSRs 0/5/4) ----
  {
    AggP a = {}; // h2_artist: rels ua (csr0) + ta (csr5)
    a.st[0]=ba.st[0]; a.en[0]=ba.en[0]; a.csr[0]=ba.csr[0]; a.el[0]=el2[0]; a.er[0]=er2[0]; a.zs[0]=zs2[0];
    a.st[1]=ba.st[5]; a.en[1]=ba.en[5]; a.csr[1]=ba.csr[5]; a.el[1]=el2[1]; a.er[1]=er2[1]; a.zs[1]=zs2[1];
    a.bias = bcomb + 384; a.out = h2a; a.Nd = NA;
    agg_multi<1, 1, 2><<<(NA + 3) / 4, 256, 0, stream>>>(a);
  }
  {
    AggP a = {}; // h2_tag: rel at (csr4)
    a.st[0]=ba.st[4]; a.en[0]=ba.en[4]; a.csr[0]=ba.csr[4]; a.el[0]=el2[2]; a.er[0]=er2[2]; a.zs[0]=zs2[2];
    a.bias = bcomb + 448; a.out = h2t; a.Nd = NT;
    agg_multi<1, 1, 1><<<(NT + 3) / 4, 256, 0, stream>>>(a);
  }

  // ---- predictor ----
  pred_dot<<<(int)(((size_t)(E + EN) * 16 + 255) / 256), 256, 0, stream>>>(
      h2a, h2t, ix[8], ix[9], ix[12], ix[13], (float*)d_out, E, EN);
}

// Round 11
// 201.559 us; speedup vs baseline: 2.0953x; 1.1281x over previous
//
#include <hip/hip_runtime.h>

#define DEVI __device__ __forceinline__

typedef __attribute__((ext_vector_type(8))) short short8v;
typedef __attribute__((ext_vector_type(4))) float f32x4;

DEVI float blo(unsigned u){ return __uint_as_float(u << 16); }
DEVI float bhi(unsigned u){ return __uint_as_float(u & 0xffff0000u); }
DEVI unsigned short f2bu(float f){          // f32 -> bf16 bits, RNE
  unsigned u = __float_as_uint(f);
  return (unsigned short)((u + 0x7fffu + ((u >> 16) & 1u)) >> 16);
}

#define MAXB 160          // max buckets per relation (ceil(20000/128)=157)
#define BKE  4096         // edges per block in bucket passes

// ---------------------------------------------------------------------------
// Bucketed CSR build: contiguous-run global writes only.
// ---------------------------------------------------------------------------
struct BArgs {
  const int* src[6];
  const int* dst[6];
  int* bcnt;
  int* bbase;
  int* gcur;
  unsigned* stage[6];
  int* csr[6];
  int* st[6];
  int* en[6];
  int nb[6];
  int N[6];
  int bpre[6];
};

__global__ __launch_bounds__(256)
void bhist(BArgs a, int E, int ebks) {
  __shared__ int h[MAXB];
  int r = blockIdx.x / ebks;
  int base = (blockIdx.x - r * ebks) * BKE;
  for (int i = threadIdx.x; i < MAXB; i += 256) h[i] = 0;
  __syncthreads();
  const int* dst = a.dst[r];
#pragma unroll
  for (int k = 0; k < 16; ++k) {
    int e = base + threadIdx.x + k * 256;
    if (e < E) atomicAdd(&h[dst[e] >> 7], 1);
  }
  __syncthreads();
  int NB = a.nb[r];
  for (int i = threadIdx.x; i < NB; i += 256)
    if (h[i]) atomicAdd(&a.bcnt[r * MAXB + i], h[i]);
}

__global__ __launch_bounds__(256)
void bscan(BArgs a) {
  __shared__ int ps[256];
  int r = blockIdx.x;
  int NB = a.nb[r];
  int t = threadIdx.x;
  int v = (t < NB) ? a.bcnt[r * MAXB + t] : 0;
  ps[t] = v;
  __syncthreads();
  for (int d = 1; d < 256; d <<= 1) {
    int x = (t >= d) ? ps[t - d] : 0;
    __syncthreads();
    ps[t] += x;
    __syncthreads();
  }
  if (t < NB) a.bbase[r * MAXB + t] = ps[t] - v;
}

__global__ __launch_bounds__(256)
void bscatter(BArgs a, int E, int ebks) {
  __shared__ int hist[MAXB];
  __shared__ int pref[MAXB];
  __shared__ int cur[MAXB];
  __shared__ int runb[MAXB];
  __shared__ int ps[256];
  __shared__ unsigned stag[BKE];
  __shared__ unsigned char dig8[BKE];
  int r = blockIdx.x / ebks;
  int base = (blockIdx.x - r * ebks) * BKE;
  int cnt = min(BKE, E - base);
  int NB = a.nb[r];
  for (int i = threadIdx.x; i < MAXB; i += 256) hist[i] = 0;
  __syncthreads();
  const int* dst = a.dst[r];
  const int* src = a.src[r];
  int ed[16], sd[16];
#pragma unroll
  for (int k = 0; k < 16; ++k) {
    int e = base + threadIdx.x + k * 256;
    if (e < E) { ed[k] = dst[e]; sd[k] = src[e]; atomicAdd(&hist[ed[k] >> 7], 1); }
    else ed[k] = -1;
  }
  __syncthreads();
  {
    int t = threadIdx.x;
    int v = (t < NB) ? hist[t] : 0;
    ps[t] = v;
    __syncthreads();
    for (int d = 1; d < 256; d <<= 1) {
      int x = (t >= d) ? ps[t - d] : 0;
      __syncthreads();
      ps[t] += x;
      __syncthreads();
    }
    if (t < NB) { pref[t] = ps[t] - v; cur[t] = ps[t] - v; }
  }
  __syncthreads();
#pragma unroll
  for (int k = 0; k < 16; ++k) {
    if (ed[k] >= 0) {
      int dg = ed[k] >> 7;
      int pos = atomicAdd(&cur[dg], 1);
      stag[pos] = ((unsigned)sd[k] << 7) | (unsigned)(ed[k] & 127);
      dig8[pos] = (unsigned char)dg;
    }
  }
  __syncthreads();
  for (int i = threadIdx.x; i < NB; i += 256) {
    int len = hist[i];
    runb[i] = len ? (a.bbase[r * MAXB + i] + atomicAdd(&a.gcur[r * MAXB + i], len)) : 0;
  }
  __syncthreads();
  unsigned* sg = a.stage[r];
  for (int i = threadIdx.x; i < cnt; i += 256) {
    int dg = dig8[i];
    sg[runb[dg] + (i - pref[dg])] = stag[i];
  }
}

__global__ __launch_bounds__(256)
void bbuild(BArgs a) {
  __shared__ int hist[128];
  __shared__ int pref[129];
  __shared__ int cur[128];
  __shared__ int ps[256];
  __shared__ int loc[8192];
  int r = 0;
#pragma unroll
  for (int i = 1; i < 6; ++i) if ((int)blockIdx.x >= a.bpre[i]) r = i;
  int b = (int)blockIdx.x - a.bpre[r];
  int cnt = a.bcnt[r * MAXB + b];
  int base = a.bbase[r * MAXB + b];
  int n0 = b << 7;
  int N = a.N[r];
  for (int i = threadIdx.x; i < 128; i += 256) hist[i] = 0;
  __syncthreads();
  const unsigned* sg = a.stage[r] + base;
  for (int i = threadIdx.x; i < cnt; i += 256) atomicAdd(&hist[sg[i] & 127], 1);
  __syncthreads();
  {
    int t = threadIdx.x;
    int v = (t < 128) ? hist[t] : 0;
    ps[t] = v;
    __syncthreads();
    for (int d = 1; d < 128; d <<= 1) {
      int x = (t >= d) ? ps[t - d] : 0;
      __syncthreads();
      ps[t] += x;
      __syncthreads();
    }
    if (t < 128) { pref[t] = ps[t] - v; cur[t] = ps[t] - v; }
    if (t == 127) pref[128] = ps[127];
  }
  __syncthreads();
  for (int i = threadIdx.x; i < cnt; i += 256) {
    unsigned v = sg[i];
    int pos = atomicAdd(&cur[v & 127], 1);
    loc[pos] = (int)(v >> 7);
  }
  __syncthreads();
  int* csr = a.csr[r];
  for (int i = threadIdx.x; i < cnt; i += 256) csr[base + i] = loc[i];
  if (threadIdx.x < 128) {
    int n = n0 + threadIdx.x;
    if (n < N) {
      a.st[r][n] = base + pref[threadIdx.x];
      a.en[r][n] = base + pref[threadIdx.x + 1];
    }
  }
}

// ---------------------------------------------------------------------------
// prep: fold W@ar -> war, W@al -> wal; W -> bf16 MFMA-fragment order; biases.
// ---------------------------------------------------------------------------
__global__ __launch_bounds__(256)
void prep(const float* __restrict__ W1, const float* __restrict__ al1,
          const float* __restrict__ ar1, const float* __restrict__ b1,
          const float* __restrict__ W2, const float* __restrict__ al2,
          const float* __restrict__ ar2, const float* __restrict__ b2,
          unsigned short* __restrict__ Wz1, unsigned short* __restrict__ Wz2,
          float* __restrict__ war1, float* __restrict__ wal1,
          float* __restrict__ war2, float* __restrict__ wal2,
          float* __restrict__ bcomb)
{
  int b = blockIdx.x, t = threadIdx.x;
  if (b < 6) {
    const float* W = W1 + b * 16384;
    unsigned short* Wz = Wz1 + b * 16384;
    for (int i = t; i < 16384; i += 256) {
      int j = i & 7, c = (i >> 3) & 127, kc = i >> 10;
      Wz[i] = f2bu(W[(kc * 8 + j) * 128 + c]);
    }
    for (int i = t; i < 512; i += 256) {
      int k = i >> 2, h = i & 3;
      float sr = 0.f, sl = 0.f;
      for (int f = 0; f < 32; ++f) {
        float w = W[k * 128 + h * 32 + f];
        sr += w * ar1[b * 128 + h * 32 + f];
        sl += w * al1[b * 128 + h * 32 + f];
      }
      war1[b * 512 + i] = sr;
      wal1[b * 512 + i] = sl;
    }
  } else if (b < 9) {
    int w = (b == 6) ? 0 : (b == 7) ? 5 : 4;
    const float* W = W2 + w * 8192;
    unsigned short* Wz = Wz2 + (b - 6) * 8192;
    for (int i = t; i < 8192; i += 256) {
      int j = i & 7, c = (i >> 3) & 63, kc = i >> 9;
      Wz[i] = f2bu(W[(kc * 8 + j) * 64 + c]);
    }
    if (t < 128) {
      float sr = 0.f, sl = 0.f;
      for (int f = 0; f < 64; ++f) {
        float x = W[t * 64 + f];
        sr += x * ar2[w * 64 + f];
        sl += x * al2[w * 64 + f];
      }
      war2[(b - 6) * 128 + t] = sr;
      wal2[(b - 6) * 128 + t] = sl;
    }
  } else {
    if (t < 128) {
      bcomb[t]       = b1[128 + t] + b1[256 + t] + b1[384 + t]; // user
      bcomb[128 + t] = b1[t] + b1[640 + t];                     // artist
      bcomb[256 + t] = b1[512 + t];                             // tag
    } else if (t < 192) {
      int x = t - 128;
      bcomb[384 + x] = b2[x] + b2[320 + x];                     // h2 artist
      bcomb[448 + x] = b2[256 + x];                             // h2 tag
    }
  }
}

// ---------------------------------------------------------------------------
// MFMA projection GEMM, batched over relations.
// ---------------------------------------------------------------------------
struct GemmM {
  const float* A[6];
  const unsigned short* Wz[6];
  unsigned short* Z[6];
  int N[6];
  int pre[6];
};

template<int KOUT>
__global__ __launch_bounds__(256)
void gemm_mfma(GemmM g)
{
  constexpr int NCT = KOUT / 64;
  int r = 0;
#pragma unroll
  for (int i = 1; i < 6; ++i) if ((int)blockIdx.x >= g.pre[i]) r = i;
  const float* A = g.A[r];
  const short8v* Wp = (const short8v*)g.Wz[r];
  unsigned short* Z = g.Z[r];
  const int N = g.N[r];
  const int row0 = (blockIdx.x - g.pre[r]) * 64;

  __shared__ short8v a_lds[64 * 16];
  for (int i = threadIdx.x; i < 64 * 16; i += 256) {
    int row = i >> 4, c8 = i & 15;
    int grow = row0 + row;
    short8v v;
    if (grow < N) {
      const float4* ap = (const float4*)(A + (size_t)grow * 128 + c8 * 8);
      float4 x0 = ap[0], x1 = ap[1];
      v[0] = (short)f2bu(x0.x); v[1] = (short)f2bu(x0.y);
      v[2] = (short)f2bu(x0.z); v[3] = (short)f2bu(x0.w);
      v[4] = (short)f2bu(x1.x); v[5] = (short)f2bu(x1.y);
      v[6] = (short)f2bu(x1.z); v[7] = (short)f2bu(x1.w);
    } else {
      v = short8v{0, 0, 0, 0, 0, 0, 0, 0};
    }
    a_lds[row * 16 + (c8 ^ (row & 7))] = v;
  }
  __syncthreads();

  const int wv = threadIdx.x >> 6;
  const int lane = threadIdx.x & 63;
  const int lrow = lane & 15, lkg = lane >> 4;

  f32x4 acc[4][NCT];
#pragma unroll
  for (int rt = 0; rt < 4; ++rt)
#pragma unroll
    for (int c = 0; c < NCT; ++c) acc[rt][c] = f32x4{0.f, 0.f, 0.f, 0.f};

#pragma unroll
  for (int ks = 0; ks < 4; ++ks) {
    const int kc = ks * 4 + lkg;
    short8v bfr[NCT];
#pragma unroll
    for (int c = 0; c < NCT; ++c)
      bfr[c] = Wp[kc * KOUT + (wv * NCT + c) * 16 + lrow];
#pragma unroll
    for (int rt = 0; rt < 4; ++rt) {
      int row = rt * 16 + lrow;
      short8v afr = a_lds[row * 16 + (kc ^ (row & 7))];
#pragma unroll
      for (int c = 0; c < NCT; ++c)
        acc[rt][c] = __builtin_amdgcn_mfma_f32_16x16x32_bf16(afr, bfr[c], acc[rt][c], 0, 0, 0);
    }
  }

#pragma unroll
  for (int rt = 0; rt < 4; ++rt)
#pragma unroll
    for (int c = 0; c < NCT; ++c) {
      int col = (wv * NCT + c) * 16 + lrow;
#pragma unroll
      for (int q = 0; q < 4; ++q) {
        int grow = row0 + rt * 16 + lkg * 4 + q;
        if (grow < N) Z[(size_t)grow * KOUT + col] = f2bu(acc[rt][c][q]);
      }
    }
}

// ---------------------------------------------------------------------------
// node_dots: all el/er columns per node type; no cross-lane ops.
// ---------------------------------------------------------------------------
struct DotsB {
  const float* X[3];
  const float* M[3][6];
  float* out[3][6];
  int NG[3];
  int N[3];
  int pre[3];
};

template<int H, int MAXG>
__global__ __launch_bounds__(256)
void node_dots(DotsB g)
{
  int task = 0;
#pragma unroll
  for (int i = 1; i < 3; ++i) if ((int)blockIdx.x >= g.pre[i]) task = i;
  const int NG = g.NG[task];
  const int C = NG * H;
  const float* X = g.X[task];
  const int N = g.N[task];
  const int n0 = (blockIdx.x - g.pre[task]) * 64;

  __shared__ float Xs[64 * 129];
  __shared__ float Ms[128 * MAXG * H];
  for (int i = threadIdx.x; i < 128 * C; i += 256) {
    int k = i / C, c = i - k * C;
    int grp = c / H, h = c - grp * H;
    Ms[i] = g.M[task][grp][k * H + h];
  }
  for (int i = threadIdx.x; i < 64 * 32; i += 256) {
    int row = i >> 5, kk = i & 31;
    int n = n0 + row;
    float4 v;
    if (n < N) v = ((const float4*)(X + (size_t)n * 128))[kk];
    else { v.x = 0.f; v.y = 0.f; v.z = 0.f; v.w = 0.f; }
    float* xp = &Xs[row * 129 + kk * 4];
    xp[0] = v.x; xp[1] = v.y; xp[2] = v.z; xp[3] = v.w;
  }
  __syncthreads();

  const int lane = threadIdx.x & 63;
  const int wv = threadIdx.x >> 6;
  const int n = n0 + lane;
  const float* xp = &Xs[lane * 129];
  for (int c = wv; c < C; c += 4) {
    int grp = c / H, h = c - grp * H;
    const float* mp = &Ms[c];
    float a0 = 0.f, a1 = 0.f;
#pragma unroll 8
    for (int k = 0; k < 128; k += 2) {
      a0 = fmaf(xp[k],     mp[k * C],       a0);
      a1 = fmaf(xp[k + 1], mp[(k + 1) * C], a1);
    }
    if (n < N) g.out[task][grp][(size_t)n * H + h] = a0 + a1;
  }
}

// ---------------------------------------------------------------------------
// Fused multi-relation CSR aggregation, v3: every lane computes exp for its
// own head (broadcast el load), per-lane den; 4-edge ILP. BOUT selects bf16
// output (layer 2 -> predictor tables).
// ---------------------------------------------------------------------------
struct AggP {
  const int* st[3];
  const int* en[3];
  const int* csr[3];
  const float* el[3];
  const float* er[3];
  const unsigned short* zs[3];
  const float* bias;
  float* out;
  unsigned short* outb;
  int Nd;
};

template<int H, int CPL, int NR, bool BOUT>
__global__ __launch_bounds__(256)
void agg_multi(AggP a)
{
  constexpr int ELEMS = 64 * CPL;
  constexpr int F = ELEMS / H;        // cols per head
  constexpr int LPH = F / CPL;        // lanes per head
  const int lane = threadIdx.x & 63;
  const int n = blockIdx.x * 4 + (threadIdx.x >> 6);
  if (n >= a.Nd) return;
  const int hl = lane / LPH;          // this lane's head

  float vout[CPL];
#pragma unroll
  for (int j = 0; j < CPL; ++j) vout[j] = a.bias[CPL * lane + j];

#pragma unroll
  for (int r = 0; r < NR; ++r) {
    const float erl = a.er[r][(size_t)n * H + hl];
    const float* el = a.el[r];
    const int* csr = a.csr[r];
    const unsigned* zp2 = (const unsigned*)a.zs[r];
    const unsigned short* zp1 = a.zs[r];
    float accA[CPL], accB[CPL];
#pragma unroll
    for (int j = 0; j < CPL; ++j) { accA[j] = 0.f; accB[j] = 0.f; }
    float denA = 0.f, denB = 0.f;
    const int e0 = a.st[r][n], e1 = a.en[r][n];
    for (int eb = e0; eb < e1; eb += 64) {
      int sv = (eb + lane < e1) ? csr[eb + lane] : 0;
      int m = min(64, e1 - eb);
      int j = 0;
      for (; j + 4 <= m; j += 4) {
        int s0 = __shfl(sv, j, 64),     s1 = __shfl(sv, j + 1, 64);
        int s2 = __shfl(sv, j + 2, 64), s3 = __shfl(sv, j + 3, 64);
        float q0 = el[s0 * H + hl], q1 = el[s1 * H + hl];
        float q2 = el[s2 * H + hl], q3 = el[s3 * H + hl];
        if (CPL == 2) {
          unsigned z0 = zp2[(size_t)s0 * 64 + lane];
          unsigned z1 = zp2[(size_t)s1 * 64 + lane];
          unsigned z2 = zp2[(size_t)s2 * 64 + lane];
          unsigned z3 = zp2[(size_t)s3 * 64 + lane];
          float v0 = q0 + erl; v0 = v0 > 0.f ? v0 : 0.2f * v0;
          float v1 = q1 + erl; v1 = v1 > 0.f ? v1 : 0.2f * v1;
          float v2 = q2 + erl; v2 = v2 > 0.f ? v2 : 0.2f * v2;
          float v3 = q3 + erl; v3 = v3 > 0.f ? v3 : 0.2f * v3;
          float ex0 = __expf(v0), ex1 = __expf(v1);
          float ex2 = __expf(v2), ex3 = __expf(v3);
          denA += ex0 + ex2; denB += ex1 + ex3;
          accA[0] += ex0 * blo(z0); accA[CPL - 1] += ex0 * bhi(z0);
          accB[0] += ex1 * blo(z1); accB[CPL - 1] += ex1 * bhi(z1);
          accA[0] += ex2 * blo(z2); accA[CPL - 1] += ex2 * bhi(z2);
          accB[0] += ex3 * blo(z3); accB[CPL - 1] += ex3 * bhi(z3);
        } else {
          unsigned z0 = zp1[(size_t)s0 * 64 + lane];
          unsigned z1 = zp1[(size_t)s1 * 64 + lane];
          unsigned z2 = zp1[(size_t)s2 * 64 + lane];
          unsigned z3 = zp1[(size_t)s3 * 64 + lane];
          float v0 = q0 + erl; v0 = v0 > 0.f ? v0 : 0.2f * v0;
          float v1 = q1 + erl; v1 = v1 > 0.f ? v1 : 0.2f * v1;
          float v2 = q2 + erl; v2 = v2 > 0.f ? v2 : 0.2f * v2;
          float v3 = q3 + erl; v3 = v3 > 0.f ? v3 : 0.2f * v3;
          float ex0 = __expf(v0), ex1 = __expf(v1);
          float ex2 = __expf(v2), ex3 = __expf(v3);
          denA += ex0 + ex2; denB += ex1 + ex3;
          accA[0] += ex0 * blo(z0);   // z in low 16 bits; blo() does the <<16
          accB[0] += ex1 * blo(z1);
          accA[0] += ex2 * blo(z2);
          accB[0] += ex3 * blo(z3);
        }
      }
      for (; j < m; ++j) {
        int s0 = __shfl(sv, j, 64);
        float q0 = el[s0 * H + hl];
        float v0 = q0 + erl; v0 = v0 > 0.f ? v0 : 0.2f * v0;
        float ex0 = __expf(v0);
        denA += ex0;
        if (CPL == 2) {
          unsigned z0 = zp2[(size_t)s0 * 64 + lane];
          accA[0] += ex0 * blo(z0); accA[CPL - 1] += ex0 * bhi(z0);
        } else {
          unsigned z0 = zp1[(size_t)s0 * 64 + lane];
          accA[0] += ex0 * blo(z0);
        }
      }
    }
    float dd = denA + denB;   // full per-head denom (every lane has it)
    if (dd > 0.f) {
#pragma unroll
      for (int j = 0; j < CPL; ++j) vout[j] += (accA[j] + accB[j]) / dd;
    }
  }
  if (CPL == 2) {
    float2 o; o.x = vout[0]; o.y = vout[CPL - 1];
    ((float2*)(a.out + (size_t)n * ELEMS))[lane] = o;
  } else {
    if (BOUT) a.outb[(size_t)n * ELEMS + lane] = f2bu(vout[0]);
    else      a.out[(size_t)n * ELEMS + lane] = vout[0];
  }
}

// ---------------------------------------------------------------------------
// Predictor: bf16 tables, 4 lanes per edge, 4x16B loads/thread, 2-hop reduce.
// ---------------------------------------------------------------------------
__global__ __launch_bounds__(256)
void pred_dot(const unsigned short* __restrict__ h2a,
              const unsigned short* __restrict__ h2t,
              const int* __restrict__ ps, const int* __restrict__ pd,
              const int* __restrict__ ns, const int* __restrict__ nd,
              float* __restrict__ out, int Ep, int En)
{
  int t = blockIdx.x * 256 + threadIdx.x;
  int e = t >> 2, q = t & 3;
  if (e >= Ep + En) return;
  int s, d;
  if (e < Ep) { s = ps[e]; d = pd[e]; }
  else        { s = ns[e - Ep]; d = nd[e - Ep]; }
  const uint4* pa = (const uint4*)(h2a + (size_t)s * 64);
  const uint4* pb = (const uint4*)(h2t + (size_t)d * 64);
  uint4 a0 = pa[2 * q], a1 = pa[2 * q + 1];
  uint4 b0 = pb[2 * q], b1 = pb[2 * q + 1];
  float v = blo(a0.x) * blo(b0.x) + bhi(a0.x) * bhi(b0.x)
          + blo(a0.y) * blo(b0.y) + bhi(a0.y) * bhi(b0.y)
          + blo(a0.z) * blo(b0.z) + bhi(a0.z) * bhi(b0.z)
          + blo(a0.w) * blo(b0.w) + bhi(a0.w) * bhi(b0.w)
          + blo(a1.x) * blo(b1.x) + bhi(a1.x) * bhi(b1.x)
          + blo(a1.y) * blo(b1.y) + bhi(a1.y) * bhi(b1.y)
          + blo(a1.z) * blo(b1.z) + bhi(a1.z) * bhi(b1.z)
          + blo(a1.w) * blo(b1.w) + bhi(a1.w) * bhi(b1.w);
  v += __shfl_xor(v, 2, 64);
  v += __shfl_xor(v, 1, 64);
  if (q == 0) out[e] = v;
}

// ---------------------------------------------------------------------------
extern "C" void kernel_launch(void* const* d_in, const int* in_sizes, int n_in,
                              void* d_out, int out_size, void* d_ws, size_t ws_size,
                              hipStream_t stream)
{
  (void)n_in; (void)out_size; (void)ws_size;
  const float* fUser = (const float*)d_in[0];
  const float* fArt  = (const float*)d_in[1];
  const float* fTag  = (const float*)d_in[2];
  const float* W1  = (const float*)d_in[3];
  const float* al1 = (const float*)d_in[4];
  const float* ar1 = (const float*)d_in[5];
  const float* b1  = (const float*)d_in[6];
  const float* W2  = (const float*)d_in[7];
  const float* al2 = (const float*)d_in[8];
  const float* ar2 = (const float*)d_in[9];
  const float* b2  = (const float*)d_in[10];
  const int* ix[14];
  for (int i = 0; i < 14; ++i) ix[i] = (const int*)d_in[11 + i];

  const int NU = in_sizes[0] / 128;
  const int NA = in_sizes[1] / 128;
  const int NT = in_sizes[2] / 128;
  const int E  = in_sizes[11];
  const int EN = in_sizes[23];

  char* p = (char*)d_ws;
  auto alloc = [&](size_t bytes) -> char* {
    char* r = p; p += (bytes + 255) & ~(size_t)255; return r;
  };

  const int dN1[6] = {NA, NU, NU, NU, NT, NA};
  const int sN1[6] = {NU, NA, NU, NU, NA, NT};
  const int sN2[3] = {NU, NT, NA};

  // ---- zero-init region: bucket counters + run cursors ----
  char* zbase = p;
  BArgs ba;
  ba.bcnt = (int*)alloc(6 * MAXB * 4);
  ba.gcur = (int*)alloc(6 * MAXB * 4);
  size_t zbytes = (size_t)(p - zbase);

  // ---- non-zero scratch ----
  ba.bbase = (int*)alloc(6 * MAXB * 4);
  int bpre = 0;
  for (int r = 0; r < 6; ++r) {
    ba.src[r] = ix[2 * r];
    ba.dst[r] = ix[2 * r + 1];
    ba.N[r] = dN1[r];
    ba.nb[r] = (dN1[r] + 127) >> 7;
    ba.bpre[r] = bpre;
    bpre += ba.nb[r];
    ba.stage[r] = (unsigned*)alloc((size_t)E * 4);
    ba.csr[r]   = (int*)alloc((size_t)E * 4);
    ba.st[r]    = (int*)alloc((size_t)dN1[r] * 4);
    ba.en[r]    = (int*)alloc((size_t)dN1[r] * 4);
  }
  unsigned short* Wz1 = (unsigned short*)alloc(6 * 16384 * 2);
  unsigned short* Wz2 = (unsigned short*)alloc(3 * 8192 * 2);
  float* war1  = (float*)alloc(6 * 512 * 4);
  float* wal1  = (float*)alloc(6 * 512 * 4);
  float* war2  = (float*)alloc(3 * 128 * 4);
  float* wal2  = (float*)alloc(3 * 128 * 4);
  float* bcomb = (float*)alloc(512 * 4);
  unsigned short* zs1[6]; float* el1[6]; float* er1[6];
  for (int r = 0; r < 6; ++r) {
    zs1[r] = (unsigned short*)alloc((size_t)sN1[r] * 128 * 2);
    el1[r] = (float*)alloc((size_t)sN1[r] * 4 * 4);
    er1[r] = (float*)alloc((size_t)dN1[r] * 4 * 4);
  }
  float* hU  = (float*)alloc((size_t)NU * 128 * 4);
  float* hA  = (float*)alloc((size_t)NA * 128 * 4);
  float* hT  = (float*)alloc((size_t)NT * 128 * 4);
  unsigned short* zs2[3]; float* el2[3]; float* er2[3];
  const int dN2[3] = {NA, NA, NT};
  for (int r = 0; r < 3; ++r) {
    zs2[r] = (unsigned short*)alloc((size_t)sN2[r] * 64 * 2);
    el2[r] = (float*)alloc((size_t)sN2[r] * 4);
    er2[r] = (float*)alloc((size_t)dN2[r] * 4);
  }
  unsigned short* h2a = (unsigned short*)alloc((size_t)NA * 64 * 2);
  unsigned short* h2t = (unsigned short*)alloc((size_t)NT * 64 * 2);

  hipMemsetAsync(zbase, 0, zbytes, stream);

  // ---- prep + bucketed CSR build ----
  prep<<<10, 256, 0, stream>>>(W1, al1, ar1, b1, W2, al2, ar2, b2,
                               Wz1, Wz2, war1, wal1, war2, wal2, bcomb);
  const int EBK = (E + BKE - 1) / BKE;
  bhist<<<6 * EBK, 256, 0, stream>>>(ba, E, EBK);
  bscan<<<6, 256, 0, stream>>>(ba);
  bscatter<<<6 * EBK, 256, 0, stream>>>(ba, E, EBK);
  bbuild<<<bpre, 256, 0, stream>>>(ba);

  // ---- layer 1: MFMA projections (Z bf16) ----
  {
    GemmM g;
    const float* sF1[6] = {fUser, fArt, fUser, fUser, fArt, fTag};
    int pre = 0;
    for (int r = 0; r < 6; ++r) {
      g.A[r] = sF1[r];
      g.Wz[r] = Wz1 + (size_t)r * 16384;
      g.Z[r] = zs1[r];
      g.N[r] = sN1[r];
      g.pre[r] = pre;
      pre += (sN1[r] + 63) / 64;
    }
    gemm_mfma<128><<<pre, 256, 0, stream>>>(g);
  }
  // ---- layer 1: all el/er dots ----
  {
    DotsB g = {};
    g.X[0] = fUser; g.N[0] = NU; g.NG[0] = 6;
    g.M[0][0] = wal1 + 0 * 512; g.out[0][0] = el1[0];
    g.M[0][1] = wal1 + 2 * 512; g.out[0][1] = el1[2];
    g.M[0][2] = wal1 + 3 * 512; g.out[0][2] = el1[3];
    g.M[0][3] = war1 + 1 * 512; g.out[0][3] = er1[1];
    g.M[0][4] = war1 + 2 * 512; g.out[0][4] = er1[2];
    g.M[0][5] = war1 + 3 * 512; g.out[0][5] = er1[3];
    g.X[1] = fArt; g.N[1] = NA; g.NG[1] = 4;
    g.M[1][0] = wal1 + 1 * 512; g.out[1][0] = el1[1];
    g.M[1][1] = wal1 + 4 * 512; g.out[1][1] = el1[4];
    g.M[1][2] = war1 + 0 * 512; g.out[1][2] = er1[0];
    g.M[1][3] = war1 + 5 * 512; g.out[1][3] = er1[5];
    g.X[2] = fTag; g.N[2] = NT; g.NG[2] = 2;
    g.M[2][0] = wal1 + 5 * 512; g.out[2][0] = el1[5];
    g.M[2][1] = war1 + 4 * 512; g.out[2][1] = er1[4];
    g.pre[0] = 0;
    g.pre[1] = (NU + 63) / 64;
    g.pre[2] = g.pre[1] + (NA + 63) / 64;
    int total = g.pre[2] + (NT + 63) / 64;
    node_dots<4, 6><<<total, 256, 0, stream>>>(g);
  }

  // ---- layer 1: fused per-dst-type aggregation ----
  {
    AggP a = {}; // artist: rels 0 (ua), 5 (ta)
    a.st[0]=ba.st[0]; a.en[0]=ba.en[0]; a.csr[0]=ba.csr[0]; a.el[0]=el1[0]; a.er[0]=er1[0]; a.zs[0]=zs1[0];
    a.st[1]=ba.st[5]; a.en[1]=ba.en[5]; a.csr[1]=ba.csr[5]; a.el[1]=el1[5]; a.er[1]=er1[5]; a.zs[1]=zs1[5];
    a.bias = bcomb + 128; a.out = hA; a.Nd = NA;
    agg_multi<4, 2, 2, false><<<(NA + 3) / 4, 256, 0, stream>>>(a);
  }
  {
    AggP a = {}; // user: rels 1 (au), 2 (uu0), 3 (uu1)
    a.st[0]=ba.st[1]; a.en[0]=ba.en[1]; a.csr[0]=ba.csr[1]; a.el[0]=el1[1]; a.er[0]=er1[1]; a.zs[0]=zs1[1];
    a.st[1]=ba.st[2]; a.en[1]=ba.en[2]; a.csr[1]=ba.csr[2]; a.el[1]=el1[2]; a.er[1]=er1[2]; a.zs[1]=zs1[2];
    a.st[2]=ba.st[3]; a.en[2]=ba.en[3]; a.csr[2]=ba.csr[3]; a.el[2]=el1[3]; a.er[2]=er1[3]; a.zs[2]=zs1[3];
    a.bias = bcomb; a.out = hU; a.Nd = NU;
    agg_multi<4, 2, 3, false><<<(NU + 3) / 4, 256, 0, stream>>>(a);
  }
  {
    AggP a = {}; // tag: rel 4 (at)
    a.st[0]=ba.st[4]; a.en[0]=ba.en[4]; a.csr[0]=ba.csr[4]; a.el[0]=el1[4]; a.er[0]=er1[4]; a.zs[0]=zs1[4];
    a.bias = bcomb + 256; a.out = hT; a.Nd = NT;
    agg_multi<4, 2, 1, false><<<(NT + 3) / 4, 256, 0, stream>>>(a);
  }

  // ---- layer 2: MFMA projections ----
  {
    GemmM g;
    const float* sF2[3] = {hU, hT, hA};
    int pre = 0;
    for (int r = 0; r < 3; ++r) {
      g.A[r] = sF2[r];
      g.Wz[r] = Wz2 + (size_t)r * 8192;
      g.Z[r] = zs2[r];
      g.N[r] = sN2[r];
      g.pre[r] = pre;
      pre += (sN2[r] + 63) / 64;
    }
    for (int r = 3; r < 6; ++r) {
      g.A[r] = nullptr; g.Wz[r] = nullptr; g.Z[r] = nullptr;
      g.N[r] = 0; g.pre[r] = 0x7fffffff;
    }
    gemm_mfma<64><<<pre, 256, 0, stream>>>(g);
  }
  // ---- layer 2: el/er dots ----
  {
    DotsB g = {};
    g.X[0] = hA; g.N[0] = NA; g.NG[0] = 3;
    g.M[0][0] = wal2 + 2 * 128; g.out[0][0] = el2[2];
    g.M[0][1] = war2 + 0 * 128; g.out[0][1] = er2[0];
    g.M[0][2] = war2 + 1 * 128; g.out[0][2] = er2[1];
    g.X[1] = hU; g.N[1] = NU; g.NG[1] = 1;
    g.M[1][0] = wal2 + 0 * 128; g.out[1][0] = el2[0];
    g.X[2] = hT; g.N[2] = NT; g.NG[2] = 2;
    g.M[2][0] = wal2 + 1 * 128; g.out[2][0] = el2[1];
    g.M[2][1] = war2 + 2 * 128; g.out[2][1] = er2[2];
    g.pre[0] = 0;
    g.pre[1] = (NA + 63) / 64;
    g.pre[2] = g.pre[1] + (NU + 63) / 64;
    int total = g.pre[2] + (NT + 63) / 64;
    node_dots<1, 3><<<total, 256, 0, stream>>>(g);
  }

  // ---- layer 2: fused aggregation (bf16 outputs for the predictor) ----
  {
    AggP a = {}; // h2_artist: rels ua (csr0) + ta (csr5)
    a.st[0]=ba.st[0]; a.en[0]=ba.en[0]; a.csr[0]=ba.csr[0]; a.el[0]=el2[0]; a.er[0]=er2[0]; a.zs[0]=zs2[0];
    a.st[1]=ba.st[5]; a.en[1]=ba.en[5]; a.csr[1]=ba.csr[5]; a.el[1]=el2[1]; a.er[1]=er2[1]; a.zs[1]=zs2[1];
    a.bias = bcomb + 384; a.outb = h2a; a.Nd = NA;
    agg_multi<1, 1, 2, true><<<(NA + 3) / 4, 256, 0, stream>>>(a);
  }
  {
    AggP a = {}; // h2_tag: rel at (csr4)
    a.st[0]=ba.st[4]; a.en[0]=ba.en[4]; a.csr[0]=ba.csr[4]; a.el[0]=el2[2]; a.er[0]=er2[2]; a.zs[0]=zs2[2];
    a.bias = bcomb + 448; a.outb = h2t; a.Nd = NT;
    agg_multi<1, 1, 1, true><<<(NT + 3) / 4, 256, 0, stream>>>(a);
  }

  // ---- predictor ----
  pred_dot<<<(int)(((size_t)(E + EN) * 4 + 255) / 256), 256, 0, stream>>>(
      h2a, h2t, ix[8], ix[9], ix[12], ix[13], (float*)d_out, E, EN);
}

// Round 12
// 198.819 us; speedup vs baseline: 2.1241x; 1.0138x over previous
//
#include <hip/hip_runtime.h>

#define DEVI __device__ __forceinline__

typedef __attribute__((ext_vector_type(8))) short short8v;
typedef __attribute__((ext_vector_type(4))) float f32x4;

DEVI float blo(unsigned u){ return __uint_as_float(u << 16); }
DEVI float bhi(unsigned u){ return __uint_as_float(u & 0xffff0000u); }
DEVI unsigned short f2bu(float f){          // f32 -> bf16 bits, RNE
  unsigned u = __float_as_uint(f);
  return (unsigned short)((u + 0x7fffu + ((u >> 16) & 1u)) >> 16);
}

#define MAXB 160          // max buckets per relation (ceil(20000/128)=157)
#define BKE  4096         // edges per block in bucket passes

// ---------------------------------------------------------------------------
// Bucketed CSR build: contiguous-run global writes only.
// ---------------------------------------------------------------------------
struct BArgs {
  const int* src[6];
  const int* dst[6];
  int* bcnt;
  int* bbase;
  int* gcur;
  unsigned* stage[6];
  int* csr[6];
  int* st[6];
  int* en[6];
  int nb[6];
  int N[6];
  int bpre[6];
};

__global__ __launch_bounds__(256)
void bhist(BArgs a, int E, int ebks) {
  __shared__ int h[MAXB];
  int r = blockIdx.x / ebks;
  int base = (blockIdx.x - r * ebks) * BKE;
  for (int i = threadIdx.x; i < MAXB; i += 256) h[i] = 0;
  __syncthreads();
  const int* dst = a.dst[r];
#pragma unroll
  for (int k = 0; k < 16; ++k) {
    int e = base + threadIdx.x + k * 256;
    if (e < E) atomicAdd(&h[dst[e] >> 7], 1);
  }
  __syncthreads();
  int NB = a.nb[r];
  for (int i = threadIdx.x; i < NB; i += 256)
    if (h[i]) atomicAdd(&a.bcnt[r * MAXB + i], h[i]);
}

__global__ __launch_bounds__(256)
void bscan(BArgs a) {
  __shared__ int ps[256];
  int r = blockIdx.x;
  int NB = a.nb[r];
  int t = threadIdx.x;
  int v = (t < NB) ? a.bcnt[r * MAXB + t] : 0;
  ps[t] = v;
  __syncthreads();
  for (int d = 1; d < 256; d <<= 1) {
    int x = (t >= d) ? ps[t - d] : 0;
    __syncthreads();
    ps[t] += x;
    __syncthreads();
  }
  if (t < NB) a.bbase[r * MAXB + t] = ps[t] - v;
}

__global__ __launch_bounds__(256)
void bscatter(BArgs a, int E, int ebks) {
  __shared__ int hist[MAXB];
  __shared__ int pref[MAXB];
  __shared__ int cur[MAXB];
  __shared__ int runb[MAXB];
  __shared__ int ps[256];
  __shared__ unsigned stag[BKE];
  __shared__ unsigned char dig8[BKE];
  int r = blockIdx.x / ebks;
  int base = (blockIdx.x - r * ebks) * BKE;
  int cnt = min(BKE, E - base);
  int NB = a.nb[r];
  for (int i = threadIdx.x; i < MAXB; i += 256) hist[i] = 0;
  __syncthreads();
  const int* dst = a.dst[r];
  const int* src = a.src[r];
  int ed[16], sd[16];
#pragma unroll
  for (int k = 0; k < 16; ++k) {
    int e = base + threadIdx.x + k * 256;
    if (e < E) { ed[k] = dst[e]; sd[k] = src[e]; atomicAdd(&hist[ed[k] >> 7], 1); }
    else ed[k] = -1;
  }
  __syncthreads();
  {
    int t = threadIdx.x;
    int v = (t < NB) ? hist[t] : 0;
    ps[t] = v;
    __syncthreads();
    for (int d = 1; d < 256; d <<= 1) {
      int x = (t >= d) ? ps[t - d] : 0;
      __syncthreads();
      ps[t] += x;
      __syncthreads();
    }
    if (t < NB) { pref[t] = ps[t] - v; cur[t] = ps[t] - v; }
  }
  __syncthreads();
#pragma unroll
  for (int k = 0; k < 16; ++k) {
    if (ed[k] >= 0) {
      int dg = ed[k] >> 7;
      int pos = atomicAdd(&cur[dg], 1);
      stag[pos] = ((unsigned)sd[k] << 7) | (unsigned)(ed[k] & 127);
      dig8[pos] = (unsigned char)dg;
    }
  }
  __syncthreads();
  for (int i = threadIdx.x; i < NB; i += 256) {
    int len = hist[i];
    runb[i] = len ? (a.bbase[r * MAXB + i] + atomicAdd(&a.gcur[r * MAXB + i], len)) : 0;
  }
  __syncthreads();
  unsigned* sg = a.stage[r];
  for (int i = threadIdx.x; i < cnt; i += 256) {
    int dg = dig8[i];
    sg[runb[dg] + (i - pref[dg])] = stag[i];
  }
}

__global__ __launch_bounds__(256)
void bbuild(BArgs a) {
  __shared__ int hist[128];
  __shared__ int pref[129];
  __shared__ int cur[128];
  __shared__ int ps[256];
  __shared__ int loc[8192];
  int r = 0;
#pragma unroll
  for (int i = 1; i < 6; ++i) if ((int)blockIdx.x >= a.bpre[i]) r = i;
  int b = (int)blockIdx.x - a.bpre[r];
  int cnt = a.bcnt[r * MAXB + b];
  int base = a.bbase[r * MAXB + b];
  int n0 = b << 7;
  int N = a.N[r];
  for (int i = threadIdx.x; i < 128; i += 256) hist[i] = 0;
  __syncthreads();
  const unsigned* sg = a.stage[r] + base;
  for (int i = threadIdx.x; i < cnt; i += 256) atomicAdd(&hist[sg[i] & 127], 1);
  __syncthreads();
  {
    int t = threadIdx.x;
    int v = (t < 128) ? hist[t] : 0;
    ps[t] = v;
    __syncthreads();
    for (int d = 1; d < 128; d <<= 1) {
      int x = (t >= d) ? ps[t - d] : 0;
      __syncthreads();
      ps[t] += x;
      __syncthreads();
    }
    if (t < 128) { pref[t] = ps[t] - v; cur[t] = ps[t] - v; }
    if (t == 127) pref[128] = ps[127];
  }
  __syncthreads();
  for (int i = threadIdx.x; i < cnt; i += 256) {
    unsigned v = sg[i];
    int pos = atomicAdd(&cur[v & 127], 1);
    loc[pos] = (int)(v >> 7);
  }
  __syncthreads();
  int* csr = a.csr[r];
  for (int i = threadIdx.x; i < cnt; i += 256) csr[base + i] = loc[i];
  if (threadIdx.x < 128) {
    int n = n0 + threadIdx.x;
    if (n < N) {
      a.st[r][n] = base + pref[threadIdx.x];
      a.en[r][n] = base + pref[threadIdx.x + 1];
    }
  }
}

// ---------------------------------------------------------------------------
// prep: fold W@ar -> war, W@al -> wal; W -> bf16 MFMA-fragment order; biases.
// Block 10 zeroes the CSR counters/cursors (replaces hipMemsetAsync — the
// rocclr fill kernel cost ~41us per graph replay).
// ---------------------------------------------------------------------------
__global__ __launch_bounds__(256)
void prep(const float* __restrict__ W1, const float* __restrict__ al1,
          const float* __restrict__ ar1, const float* __restrict__ b1,
          const float* __restrict__ W2, const float* __restrict__ al2,
          const float* __restrict__ ar2, const float* __restrict__ b2,
          unsigned short* __restrict__ Wz1, unsigned short* __restrict__ Wz2,
          float* __restrict__ war1, float* __restrict__ wal1,
          float* __restrict__ war2, float* __restrict__ wal2,
          float* __restrict__ bcomb, int* __restrict__ zro, int zn)
{
  int b = blockIdx.x, t = threadIdx.x;
  if (b < 6) {
    const float* W = W1 + b * 16384;
    unsigned short* Wz = Wz1 + b * 16384;
    for (int i = t; i < 16384; i += 256) {
      int j = i & 7, c = (i >> 3) & 127, kc = i >> 10;
      Wz[i] = f2bu(W[(kc * 8 + j) * 128 + c]);
    }
    for (int i = t; i < 512; i += 256) {
      int k = i >> 2, h = i & 3;
      float sr = 0.f, sl = 0.f;
      for (int f = 0; f < 32; ++f) {
        float w = W[k * 128 + h * 32 + f];
        sr += w * ar1[b * 128 + h * 32 + f];
        sl += w * al1[b * 128 + h * 32 + f];
      }
      war1[b * 512 + i] = sr;
      wal1[b * 512 + i] = sl;
    }
  } else if (b < 9) {
    int w = (b == 6) ? 0 : (b == 7) ? 5 : 4;
    const float* W = W2 + w * 8192;
    unsigned short* Wz = Wz2 + (b - 6) * 8192;
    for (int i = t; i < 8192; i += 256) {
      int j = i & 7, c = (i >> 3) & 63, kc = i >> 9;
      Wz[i] = f2bu(W[(kc * 8 + j) * 64 + c]);
    }
    if (t < 128) {
      float sr = 0.f, sl = 0.f;
      for (int f = 0; f < 64; ++f) {
        float x = W[t * 64 + f];
        sr += x * ar2[w * 64 + f];
        sl += x * al2[w * 64 + f];
      }
      war2[(b - 6) * 128 + t] = sr;
      wal2[(b - 6) * 128 + t] = sl;
    }
  } else if (b == 9) {
    if (t < 128) {
      bcomb[t]       = b1[128 + t] + b1[256 + t] + b1[384 + t]; // user
      bcomb[128 + t] = b1[t] + b1[640 + t];                     // artist
      bcomb[256 + t] = b1[512 + t];                             // tag
    } else if (t < 192) {
      int x = t - 128;
      bcomb[384 + x] = b2[x] + b2[320 + x];                     // h2 artist
      bcomb[448 + x] = b2[256 + x];                             // h2 tag
    }
  } else {
    for (int i = t; i < zn; i += 256) zro[i] = 0;   // bcnt + gcur
  }
}

// ---------------------------------------------------------------------------
// MFMA projection GEMM, batched over relations.
// ---------------------------------------------------------------------------
struct GemmM {
  const float* A[6];
  const unsigned short* Wz[6];
  unsigned short* Z[6];
  int N[6];
  int pre[6];
};

template<int KOUT>
__global__ __launch_bounds__(256)
void gemm_mfma(GemmM g)
{
  constexpr int NCT = KOUT / 64;
  int r = 0;
#pragma unroll
  for (int i = 1; i < 6; ++i) if ((int)blockIdx.x >= g.pre[i]) r = i;
  const float* A = g.A[r];
  const short8v* Wp = (const short8v*)g.Wz[r];
  unsigned short* Z = g.Z[r];
  const int N = g.N[r];
  const int row0 = (blockIdx.x - g.pre[r]) * 64;

  __shared__ short8v a_lds[64 * 16];
  for (int i = threadIdx.x; i < 64 * 16; i += 256) {
    int row = i >> 4, c8 = i & 15;
    int grow = row0 + row;
    short8v v;
    if (grow < N) {
      const float4* ap = (const float4*)(A + (size_t)grow * 128 + c8 * 8);
      float4 x0 = ap[0], x1 = ap[1];
      v[0] = (short)f2bu(x0.x); v[1] = (short)f2bu(x0.y);
      v[2] = (short)f2bu(x0.z); v[3] = (short)f2bu(x0.w);
      v[4] = (short)f2bu(x1.x); v[5] = (short)f2bu(x1.y);
      v[6] = (short)f2bu(x1.z); v[7] = (short)f2bu(x1.w);
    } else {
      v = short8v{0, 0, 0, 0, 0, 0, 0, 0};
    }
    a_lds[row * 16 + (c8 ^ (row & 7))] = v;
  }
  __syncthreads();

  const int wv = threadIdx.x >> 6;
  const int lane = threadIdx.x & 63;
  const int lrow = lane & 15, lkg = lane >> 4;

  f32x4 acc[4][NCT];
#pragma unroll
  for (int rt = 0; rt < 4; ++rt)
#pragma unroll
    for (int c = 0; c < NCT; ++c) acc[rt][c] = f32x4{0.f, 0.f, 0.f, 0.f};

#pragma unroll
  for (int ks = 0; ks < 4; ++ks) {
    const int kc = ks * 4 + lkg;
    short8v bfr[NCT];
#pragma unroll
    for (int c = 0; c < NCT; ++c)
      bfr[c] = Wp[kc * KOUT + (wv * NCT + c) * 16 + lrow];
#pragma unroll
    for (int rt = 0; rt < 4; ++rt) {
      int row = rt * 16 + lrow;
      short8v afr = a_lds[row * 16 + (kc ^ (row & 7))];
#pragma unroll
      for (int c = 0; c < NCT; ++c)
        acc[rt][c] = __builtin_amdgcn_mfma_f32_16x16x32_bf16(afr, bfr[c], acc[rt][c], 0, 0, 0);
    }
  }

#pragma unroll
  for (int rt = 0; rt < 4; ++rt)
#pragma unroll
    for (int c = 0; c < NCT; ++c) {
      int col = (wv * NCT + c) * 16 + lrow;
#pragma unroll
      for (int q = 0; q < 4; ++q) {
        int grow = row0 + rt * 16 + lkg * 4 + q;
        if (grow < N) Z[(size_t)grow * KOUT + col] = f2bu(acc[rt][c][q]);
      }
    }
}

// ---------------------------------------------------------------------------
// node_dots: all el/er columns per node type; no cross-lane ops.
// ---------------------------------------------------------------------------
struct DotsB {
  const float* X[3];
  const float* M[3][6];
  float* out[3][6];
  int NG[3];
  int N[3];
  int pre[3];
};

template<int H, int MAXG>
__global__ __launch_bounds__(256)
void node_dots(DotsB g)
{
  int task = 0;
#pragma unroll
  for (int i = 1; i < 3; ++i) if ((int)blockIdx.x >= g.pre[i]) task = i;
  const int NG = g.NG[task];
  const int C = NG * H;
  const float* X = g.X[task];
  const int N = g.N[task];
  const int n0 = (blockIdx.x - g.pre[task]) * 64;

  __shared__ float Xs[64 * 129];
  __shared__ float Ms[128 * MAXG * H];
  for (int i = threadIdx.x; i < 128 * C; i += 256) {
    int k = i / C, c = i - k * C;
    int grp = c / H, h = c - grp * H;
    Ms[i] = g.M[task][grp][k * H + h];
  }
  for (int i = threadIdx.x; i < 64 * 32; i += 256) {
    int row = i >> 5, kk = i & 31;
    int n = n0 + row;
    float4 v;
    if (n < N) v = ((const float4*)(X + (size_t)n * 128))[kk];
    else { v.x = 0.f; v.y = 0.f; v.z = 0.f; v.w = 0.f; }
    float* xp = &Xs[row * 129 + kk * 4];
    xp[0] = v.x; xp[1] = v.y; xp[2] = v.z; xp[3] = v.w;
  }
  __syncthreads();

  const int lane = threadIdx.x & 63;
  const int wv = threadIdx.x >> 6;
  const int n = n0 + lane;
  const float* xp = &Xs[lane * 129];
  for (int c = wv; c < C; c += 4) {
    int grp = c / H, h = c - grp * H;
    const float* mp = &Ms[c];
    float a0 = 0.f, a1 = 0.f;
#pragma unroll 8
    for (int k = 0; k < 128; k += 2) {
      a0 = fmaf(xp[k],     mp[k * C],       a0);
      a1 = fmaf(xp[k + 1], mp[(k + 1) * C], a1);
    }
    if (n < N) g.out[task][grp][(size_t)n * H + h] = a0 + a1;
  }
}

// ---------------------------------------------------------------------------
// Fused multi-relation CSR aggregation, v3: every lane computes exp for its
// own head (broadcast el load), per-lane den; 4-edge ILP. BOUT selects bf16
// output (layer 2 -> predictor tables).
// ---------------------------------------------------------------------------
struct AggP {
  const int* st[3];
  const int* en[3];
  const int* csr[3];
  const float* el[3];
  const float* er[3];
  const unsigned short* zs[3];
  const float* bias;
  float* out;
  unsigned short* outb;
  int Nd;
};

template<int H, int CPL, int NR, bool BOUT>
__global__ __launch_bounds__(256)
void agg_multi(AggP a)
{
  constexpr int ELEMS = 64 * CPL;
  constexpr int F = ELEMS / H;        // cols per head
  constexpr int LPH = F / CPL;        // lanes per head
  const int lane = threadIdx.x & 63;
  const int n = blockIdx.x * 4 + (threadIdx.x >> 6);
  if (n >= a.Nd) return;
  const int hl = lane / LPH;          // this lane's head

  float vout[CPL];
#pragma unroll
  for (int j = 0; j < CPL; ++j) vout[j] = a.bias[CPL * lane + j];

#pragma unroll
  for (int r = 0; r < NR; ++r) {
    const float erl = a.er[r][(size_t)n * H + hl];
    const float* el = a.el[r];
    const int* csr = a.csr[r];
    const unsigned* zp2 = (const unsigned*)a.zs[r];
    const unsigned short* zp1 = a.zs[r];
    float accA[CPL], accB[CPL];
#pragma unroll
    for (int j = 0; j < CPL; ++j) { accA[j] = 0.f; accB[j] = 0.f; }
    float denA = 0.f, denB = 0.f;
    const int e0 = a.st[r][n], e1 = a.en[r][n];
    for (int eb = e0; eb < e1; eb += 64) {
      int sv = (eb + lane < e1) ? csr[eb + lane] : 0;
      int m = min(64, e1 - eb);
      int j = 0;
      for (; j + 4 <= m; j += 4) {
        int s0 = __shfl(sv, j, 64),     s1 = __shfl(sv, j + 1, 64);
        int s2 = __shfl(sv, j + 2, 64), s3 = __shfl(sv, j + 3, 64);
        float q0 = el[s0 * H + hl], q1 = el[s1 * H + hl];
        float q2 = el[s2 * H + hl], q3 = el[s3 * H + hl];
        if (CPL == 2) {
          unsigned z0 = zp2[(size_t)s0 * 64 + lane];
          unsigned z1 = zp2[(size_t)s1 * 64 + lane];
          unsigned z2 = zp2[(size_t)s2 * 64 + lane];
          unsigned z3 = zp2[(size_t)s3 * 64 + lane];
          float v0 = q0 + erl; v0 = v0 > 0.f ? v0 : 0.2f * v0;
          float v1 = q1 + erl; v1 = v1 > 0.f ? v1 : 0.2f * v1;
          float v2 = q2 + erl; v2 = v2 > 0.f ? v2 : 0.2f * v2;
          float v3 = q3 + erl; v3 = v3 > 0.f ? v3 : 0.2f * v3;
          float ex0 = __expf(v0), ex1 = __expf(v1);
          float ex2 = __expf(v2), ex3 = __expf(v3);
          denA += ex0 + ex2; denB += ex1 + ex3;
          accA[0] += ex0 * blo(z0); accA[CPL - 1] += ex0 * bhi(z0);
          accB[0] += ex1 * blo(z1); accB[CPL - 1] += ex1 * bhi(z1);
          accA[0] += ex2 * blo(z2); accA[CPL - 1] += ex2 * bhi(z2);
          accB[0] += ex3 * blo(z3); accB[CPL - 1] += ex3 * bhi(z3);
        } else {
          unsigned z0 = zp1[(size_t)s0 * 64 + lane];
          unsigned z1 = zp1[(size_t)s1 * 64 + lane];
          unsigned z2 = zp1[(size_t)s2 * 64 + lane];
          unsigned z3 = zp1[(size_t)s3 * 64 + lane];
          float v0 = q0 + erl; v0 = v0 > 0.f ? v0 : 0.2f * v0;
          float v1 = q1 + erl; v1 = v1 > 0.f ? v1 : 0.2f * v1;
          float v2 = q2 + erl; v2 = v2 > 0.f ? v2 : 0.2f * v2;
          float v3 = q3 + erl; v3 = v3 > 0.f ? v3 : 0.2f * v3;
          float ex0 = __expf(v0), ex1 = __expf(v1);
          float ex2 = __expf(v2), ex3 = __expf(v3);
          denA += ex0 + ex2; denB += ex1 + ex3;
          accA[0] += ex0 * blo(z0);   // z in low 16 bits; blo() does the <<16
          accB[0] += ex1 * blo(z1);
          accA[0] += ex2 * blo(z2);
          accB[0] += ex3 * blo(z3);
        }
      }
      for (; j < m; ++j) {
        int s0 = __shfl(sv, j, 64);
        float q0 = el[s0 * H + hl];
        float v0 = q0 + erl; v0 = v0 > 0.f ? v0 : 0.2f * v0;
        float ex0 = __expf(v0);
        denA += ex0;
        if (CPL == 2) {
          unsigned z0 = zp2[(size_t)s0 * 64 + lane];
          accA[0] += ex0 * blo(z0); accA[CPL - 1] += ex0 * bhi(z0);
        } else {
          unsigned z0 = zp1[(size_t)s0 * 64 + lane];
          accA[0] += ex0 * blo(z0);
        }
      }
    }
    float dd = denA + denB;   // full per-head denom (every lane has it)
    if (dd > 0.f) {
#pragma unroll
      for (int j = 0; j < CPL; ++j) vout[j] += (accA[j] + accB[j]) / dd;
    }
  }
  if (CPL == 2) {
    float2 o; o.x = vout[0]; o.y = vout[CPL - 1];
    ((float2*)(a.out + (size_t)n * ELEMS))[lane] = o;
  } else {
    if (BOUT) a.outb[(size_t)n * ELEMS + lane] = f2bu(vout[0]);
    else      a.out[(size_t)n * ELEMS + lane] = vout[0];
  }
}

// ---------------------------------------------------------------------------
// Predictor: bf16 tables, 4 lanes per edge, 4x16B loads/thread, 2-hop reduce.
// ---------------------------------------------------------------------------
__global__ __launch_bounds__(256)
void pred_dot(const unsigned short* __restrict__ h2a,
              const unsigned short* __restrict__ h2t,
              const int* __restrict__ ps, const int* __restrict__ pd,
              const int* __restrict__ ns, const int* __restrict__ nd,
              float* __restrict__ out, int Ep, int En)
{
  int t = blockIdx.x * 256 + threadIdx.x;
  int e = t >> 2, q = t & 3;
  if (e >= Ep + En) return;
  int s, d;
  if (e < Ep) { s = ps[e]; d = pd[e]; }
  else        { s = ns[e - Ep]; d = nd[e - Ep]; }
  const uint4* pa = (const uint4*)(h2a + (size_t)s * 64);
  const uint4* pb = (const uint4*)(h2t + (size_t)d * 64);
  uint4 a0 = pa[2 * q], a1 = pa[2 * q + 1];
  uint4 b0 = pb[2 * q], b1 = pb[2 * q + 1];
  float v = blo(a0.x) * blo(b0.x) + bhi(a0.x) * bhi(b0.x)
          + blo(a0.y) * blo(b0.y) + bhi(a0.y) * bhi(b0.y)
          + blo(a0.z) * blo(b0.z) + bhi(a0.z) * bhi(b0.z)
          + blo(a0.w) * blo(b0.w) + bhi(a0.w) * bhi(b0.w)
          + blo(a1.x) * blo(b1.x) + bhi(a1.x) * bhi(b1.x)
          + blo(a1.y) * blo(b1.y) + bhi(a1.y) * bhi(b1.y)
          + blo(a1.z) * blo(b1.z) + bhi(a1.z) * bhi(b1.z)
          + blo(a1.w) * blo(b1.w) + bhi(a1.w) * bhi(b1.w);
  v += __shfl_xor(v, 2, 64);
  v += __shfl_xor(v, 1, 64);
  if (q == 0) out[e] = v;
}

// ---------------------------------------------------------------------------
extern "C" void kernel_launch(void* const* d_in, const int* in_sizes, int n_in,
                              void* d_out, int out_size, void* d_ws, size_t ws_size,
                              hipStream_t stream)
{
  (void)n_in; (void)out_size; (void)ws_size;
  const float* fUser = (const float*)d_in[0];
  const float* fArt  = (const float*)d_in[1];
  const float* fTag  = (const float*)d_in[2];
  const float* W1  = (const float*)d_in[3];
  const float* al1 = (const float*)d_in[4];
  const float* ar1 = (const float*)d_in[5];
  const float* b1  = (const float*)d_in[6];
  const float* W2  = (const float*)d_in[7];
  const float* al2 = (const float*)d_in[8];
  const float* ar2 = (const float*)d_in[9];
  const float* b2  = (const float*)d_in[10];
  const int* ix[14];
  for (int i = 0; i < 14; ++i) ix[i] = (const int*)d_in[11 + i];

  const int NU = in_sizes[0] / 128;
  const int NA = in_sizes[1] / 128;
  const int NT = in_sizes[2] / 128;
  const int E  = in_sizes[11];
  const int EN = in_sizes[23];

  char* p = (char*)d_ws;
  auto alloc = [&](size_t bytes) -> char* {
    char* r = p; p += (bytes + 255) & ~(size_t)255; return r;
  };

  const int dN1[6] = {NA, NU, NU, NU, NT, NA};
  const int sN1[6] = {NU, NA, NU, NU, NA, NT};
  const int sN2[3] = {NU, NT, NA};

  // ---- CSR counters + cursors (zeroed by prep block 10, contiguous) ----
  BArgs ba;
  ba.bcnt = (int*)alloc(6 * MAXB * 4);
  ba.gcur = (int*)alloc(6 * MAXB * 4);   // contiguous after bcnt (both 256B-mult)
  const int zn = 2 * 6 * MAXB;

  // ---- other scratch ----
  ba.bbase = (int*)alloc(6 * MAXB * 4);
  int bpre = 0;
  for (int r = 0; r < 6; ++r) {
    ba.src[r] = ix[2 * r];
    ba.dst[r] = ix[2 * r + 1];
    ba.N[r] = dN1[r];
    ba.nb[r] = (dN1[r] + 127) >> 7;
    ba.bpre[r] = bpre;
    bpre += ba.nb[r];
    ba.stage[r] = (unsigned*)alloc((size_t)E * 4);
    ba.csr[r]   = (int*)alloc((size_t)E * 4);
    ba.st[r]    = (int*)alloc((size_t)dN1[r] * 4);
    ba.en[r]    = (int*)alloc((size_t)dN1[r] * 4);
  }
  unsigned short* Wz1 = (unsigned short*)alloc(6 * 16384 * 2);
  unsigned short* Wz2 = (unsigned short*)alloc(3 * 8192 * 2);
  float* war1  = (float*)alloc(6 * 512 * 4);
  float* wal1  = (float*)alloc(6 * 512 * 4);
  float* war2  = (float*)alloc(3 * 128 * 4);
  float* wal2  = (float*)alloc(3 * 128 * 4);
  float* bcomb = (float*)alloc(512 * 4);
  unsigned short* zs1[6]; float* el1[6]; float* er1[6];
  for (int r = 0; r < 6; ++r) {
    zs1[r] = (unsigned short*)alloc((size_t)sN1[r] * 128 * 2);
    el1[r] = (float*)alloc((size_t)sN1[r] * 4 * 4);
    er1[r] = (float*)alloc((size_t)dN1[r] * 4 * 4);
  }
  float* hU  = (float*)alloc((size_t)NU * 128 * 4);
  float* hA  = (float*)alloc((size_t)NA * 128 * 4);
  float* hT  = (float*)alloc((size_t)NT * 128 * 4);
  unsigned short* zs2[3]; float* el2[3]; float* er2[3];
  const int dN2[3] = {NA, NA, NT};
  for (int r = 0; r < 3; ++r) {
    zs2[r] = (unsigned short*)alloc((size_t)sN2[r] * 64 * 2);
    el2[r] = (float*)alloc((size_t)sN2[r] * 4);
    er2[r] = (float*)alloc((size_t)dN2[r] * 4);
  }
  unsigned short* h2a = (unsigned short*)alloc((size_t)NA * 64 * 2);
  unsigned short* h2t = (unsigned short*)alloc((size_t)NT * 64 * 2);

  // ---- prep (incl. counter zeroing) + bucketed CSR build ----
  prep<<<11, 256, 0, stream>>>(W1, al1, ar1, b1, W2, al2, ar2, b2,
                               Wz1, Wz2, war1, wal1, war2, wal2, bcomb,
                               ba.bcnt, zn);
  const int EBK = (E + BKE - 1) / BKE;
  bhist<<<6 * EBK, 256, 0, stream>>>(ba, E, EBK);
  bscan<<<6, 256, 0, stream>>>(ba);
  bscatter<<<6 * EBK, 256, 0, stream>>>(ba, E, EBK);
  bbuild<<<bpre, 256, 0, stream>>>(ba);

  // ---- layer 1: MFMA projections (Z bf16) ----
  {
    GemmM g;
    const float* sF1[6] = {fUser, fArt, fUser, fUser, fArt, fTag};
    int pre = 0;
    for (int r = 0; r < 6; ++r) {
      g.A[r] = sF1[r];
      g.Wz[r] = Wz1 + (size_t)r * 16384;
      g.Z[r] = zs1[r];
      g.N[r] = sN1[r];
      g.pre[r] = pre;
      pre += (sN1[r] + 63) / 64;
    }
    gemm_mfma<128><<<pre, 256, 0, stream>>>(g);
  }
  // ---- layer 1: all el/er dots ----
  {
    DotsB g = {};
    g.X[0] = fUser; g.N[0] = NU; g.NG[0] = 6;
    g.M[0][0] = wal1 + 0 * 512; g.out[0][0] = el1[0];
    g.M[0][1] = wal1 + 2 * 512; g.out[0][1] = el1[2];
    g.M[0][2] = wal1 + 3 * 512; g.out[0][2] = el1[3];
    g.M[0][3] = war1 + 1 * 512; g.out[0][3] = er1[1];
    g.M[0][4] = war1 + 2 * 512; g.out[0][4] = er1[2];
    g.M[0][5] = war1 + 3 * 512; g.out[0][5] = er1[3];
    g.X[1] = fArt; g.N[1] = NA; g.NG[1] = 4;
    g.M[1][0] = wal1 + 1 * 512; g.out[1][0] = el1[1];
    g.M[1][1] = wal1 + 4 * 512; g.out[1][1] = el1[4];
    g.M[1][2] = war1 + 0 * 512; g.out[1][2] = er1[0];
    g.M[1][3] = war1 + 5 * 512; g.out[1][3] = er1[5];
    g.X[2] = fTag; g.N[2] = NT; g.NG[2] = 2;
    g.M[2][0] = wal1 + 5 * 512; g.out[2][0] = el1[5];
    g.M[2][1] = war1 + 4 * 512; g.out[2][1] = er1[4];
    g.pre[0] = 0;
    g.pre[1] = (NU + 63) / 64;
    g.pre[2] = g.pre[1] + (NA + 63) / 64;
    int total = g.pre[2] + (NT + 63) / 64;
    node_dots<4, 6><<<total, 256, 0, stream>>>(g);
  }

  // ---- layer 1: fused per-dst-type aggregation ----
  {
    AggP a = {}; // artist: rels 0 (ua), 5 (ta)
    a.st[0]=ba.st[0]; a.en[0]=ba.en[0]; a.csr[0]=ba.csr[0]; a.el[0]=el1[0]; a.er[0]=er1[0]; a.zs[0]=zs1[0];
    a.st[1]=ba.st[5]; a.en[1]=ba.en[5]; a.csr[1]=ba.csr[5]; a.el[1]=el1[5]; a.er[1]=er1[5]; a.zs[1]=zs1[5];
    a.bias = bcomb + 128; a.out = hA; a.Nd = NA;
    agg_multi<4, 2, 2, false><<<(NA + 3) / 4, 256, 0, stream>>>(a);
  }
  {
    AggP a = {}; // user: rels 1 (au), 2 (uu0), 3 (uu1)
    a.st[0]=ba.st[1]; a.en[0]=ba.en[1]; a.csr[0]=ba.csr[1]; a.el[0]=el1[1]; a.er[0]=er1[1]; a.zs[0]=zs1[1];
    a.st[1]=ba.st[2]; a.en[1]=ba.en[2]; a.csr[1]=ba.csr[2]; a.el[1]=el1[2]; a.er[1]=er1[2]; a.zs[1]=zs1[2];
    a.st[2]=ba.st[3]; a.en[2]=ba.en[3]; a.csr[2]=ba.csr[3]; a.el[2]=el1[3]; a.er[2]=er1[3]; a.zs[2]=zs1[3];
    a.bias = bcomb; a.out = hU; a.Nd = NU;
    agg_multi<4, 2, 3, false><<<(NU + 3) / 4, 256, 0, stream>>>(a);
  }
  {
    AggP a = {}; // tag: rel 4 (at)
    a.st[0]=ba.st[4]; a.en[0]=ba.en[4]; a.csr[0]=ba.csr[4]; a.el[0]=el1[4]; a.er[0]=er1[4]; a.zs[0]=zs1[4];
    a.bias = bcomb + 256; a.out = hT; a.Nd = NT;
    agg_multi<4, 2, 1, false><<<(NT + 3) / 4, 256, 0, stream>>>(a);
  }

  // ---- layer 2: MFMA projections ----
  {
    GemmM g;
    const float* sF2[3] = {hU, hT, hA};
    int pre = 0;
    for (int r = 0; r < 3; ++r) {
      g.A[r] = sF2[r];
      g.Wz[r] = Wz2 + (size_t)r * 8192;
      g.Z[r] = zs2[r];
      g.N[r] = sN2[r];
      g.pre[r] = pre;
      pre += (sN2[r] + 63) / 64;
    }
    for (int r = 3; r < 6; ++r) {
      g.A[r] = nullptr; g.Wz[r] = nullptr; g.Z[r] = nullptr;
      g.N[r] = 0; g.pre[r] = 0x7fffffff;
    }
    gemm_mfma<64><<<pre, 256, 0, stream>>>(g);
  }
  // ---- layer 2: el/er dots ----
  {
    DotsB g = {};
    g.X[0] = hA; g.N[0] = NA; g.NG[0] = 3;
    g.M[0][0] = wal2 + 2 * 128; g.out[0][0] = el2[2];
    g.M[0][1] = war2 + 0 * 128; g.out[0][1] = er2[0];
    g.M[0][2] = war2 + 1 * 128; g.out[0][2] = er2[1];
    g.X[1] = hU; g.N[1] = NU; g.NG[1] = 1;
    g.M[1][0] = wal2 + 0 * 128; g.out[1][0] = el2[0];
    g.X[2] = hT; g.N[2] = NT; g.NG[2] = 2;
    g.M[2][0] = wal2 + 1 * 128; g.out[2][0] = el2[1];
    g.M[2][1] = war2 + 2 * 128; g.out[2][1] = er2[2];
    g.pre[0] = 0;
    g.pre[1] = (NA + 63) / 64;
    g.pre[2] = g.pre[1] + (NU + 63) / 64;
    int total = g.pre[2] + (NT + 63) / 64;
    node_dots<1, 3><<<total, 256, 0, stream>>>(g);
  }

  // ---- layer 2: fused aggregation (bf16 outputs for the predictor) ----
  {
    AggP a = {}; // h2_artist: rels ua (csr0) + ta (csr5)
    a.st[0]=ba.st[0]; a.en[0]=ba.en[0]; a.csr[0]=ba.csr[0]; a.el[0]=el2[0]; a.er[0]=er2[0]; a.zs[0]=zs2[0];
    a.st[1]=ba.st[5]; a.en[1]=ba.en[5]; a.csr[1]=ba.csr[5]; a.el[1]=el2[1]; a.er[1]=er2[1]; a.zs[1]=zs2[1];
    a.bias = bcomb + 384; a.outb = h2a; a.Nd = NA;
    agg_multi<1, 1, 2, true><<<(NA + 3) / 4, 256, 0, stream>>>(a);
  }
  {
    AggP a = {}; // h2_tag: rel at (csr4)
    a.st[0]=ba.st[4]; a.en[0]=ba.en[4]; a.csr[0]=ba.csr[4]; a.el[0]=el2[2]; a.er[0]=er2[2]; a.zs[0]=zs2[2];
    a.bias = bcomb + 448; a.outb = h2t; a.Nd = NT;
    agg_multi<1, 1, 1, true><<<(NT + 3) / 4, 256, 0, stream>>>(a);
  }

  // ---- predictor ----
  pred_dot<<<(int)(((size_t)(E + EN) * 4 + 255) / 256), 256, 0, stream>>>(
      h2a, h2t, ix[8], ix[9], ix[12], ix[13], (float*)d_out, E, EN);
}

// Round 13
// 180.741 us; speedup vs baseline: 2.3366x; 1.1000x over previous
//
#include <hip/hip_runtime.h>

#define DEVI __device__ __forceinline__

typedef __attribute__((ext_vector_type(8))) short short8v;
typedef __attribute__((ext_vector_type(4))) float f32x4;

DEVI float blo(unsigned u){ return __uint_as_float(u << 16); }
DEVI float bhi(unsigned u){ return __uint_as_float(u & 0xffff0000u); }
DEVI unsigned short f2bu(float f){          // f32 -> bf16 bits, RNE
  unsigned u = __float_as_uint(f);
  return (unsigned short)((u + 0x7fffu + ((u >> 16) & 1u)) >> 16);
}

#define MAXB 160          // max buckets per relation (ceil(20000/128)=157)
#define BKE  4096         // edges per block in bucket passes

// ---------------------------------------------------------------------------
// Bucketed CSR build: contiguous-run global writes only.
// ---------------------------------------------------------------------------
struct BArgs {
  const int* src[6];
  const int* dst[6];
  int* bcnt;
  int* bbase;
  int* gcur;
  unsigned* stage[6];
  int* csr[6];
  int* st[6];
  int* en[6];
  int nb[6];
  int N[6];
  int bpre[6];
};

__global__ __launch_bounds__(256)
void bhist(BArgs a, int E, int ebks) {
  __shared__ int h[MAXB];
  int r = blockIdx.x / ebks;
  int base = (blockIdx.x - r * ebks) * BKE;
  for (int i = threadIdx.x; i < MAXB; i += 256) h[i] = 0;
  __syncthreads();
  const int* dst = a.dst[r];
#pragma unroll
  for (int k = 0; k < 16; ++k) {
    int e = base + threadIdx.x + k * 256;
    if (e < E) atomicAdd(&h[dst[e] >> 7], 1);
  }
  __syncthreads();
  int NB = a.nb[r];
  for (int i = threadIdx.x; i < NB; i += 256)
    if (h[i]) atomicAdd(&a.bcnt[r * MAXB + i], h[i]);
}

__global__ __launch_bounds__(256)
void bscan(BArgs a) {
  __shared__ int ps[256];
  int r = blockIdx.x;
  int NB = a.nb[r];
  int t = threadIdx.x;
  int v = (t < NB) ? a.bcnt[r * MAXB + t] : 0;
  ps[t] = v;
  __syncthreads();
  for (int d = 1; d < 256; d <<= 1) {
    int x = (t >= d) ? ps[t - d] : 0;
    __syncthreads();
    ps[t] += x;
    __syncthreads();
  }
  if (t < NB) a.bbase[r * MAXB + t] = ps[t] - v;
}

__global__ __launch_bounds__(256)
void bscatter(BArgs a, int E, int ebks) {
  __shared__ int hist[MAXB];
  __shared__ int pref[MAXB];
  __shared__ int cur[MAXB];
  __shared__ int runb[MAXB];
  __shared__ int ps[256];
  __shared__ unsigned stag[BKE];
  __shared__ unsigned char dig8[BKE];
  int r = blockIdx.x / ebks;
  int base = (blockIdx.x - r * ebks) * BKE;
  int cnt = min(BKE, E - base);
  int NB = a.nb[r];
  for (int i = threadIdx.x; i < MAXB; i += 256) hist[i] = 0;
  __syncthreads();
  const int* dst = a.dst[r];
  const int* src = a.src[r];
  int ed[16], sd[16];
#pragma unroll
  for (int k = 0; k < 16; ++k) {
    int e = base + threadIdx.x + k * 256;
    if (e < E) { ed[k] = dst[e]; sd[k] = src[e]; atomicAdd(&hist[ed[k] >> 7], 1); }
    else ed[k] = -1;
  }
  __syncthreads();
  {
    int t = threadIdx.x;
    int v = (t < NB) ? hist[t] : 0;
    ps[t] = v;
    __syncthreads();
    for (int d = 1; d < 256; d <<= 1) {
      int x = (t >= d) ? ps[t - d] : 0;
      __syncthreads();
      ps[t] += x;
      __syncthreads();
    }
    if (t < NB) { pref[t] = ps[t] - v; cur[t] = ps[t] - v; }
  }
  __syncthreads();
#pragma unroll
  for (int k = 0; k < 16; ++k) {
    if (ed[k] >= 0) {
      int dg = ed[k] >> 7;
      int pos = atomicAdd(&cur[dg], 1);
      stag[pos] = ((unsigned)sd[k] << 7) | (unsigned)(ed[k] & 127);
      dig8[pos] = (unsigned char)dg;
    }
  }
  __syncthreads();
  for (int i = threadIdx.x; i < NB; i += 256) {
    int len = hist[i];
    runb[i] = len ? (a.bbase[r * MAXB + i] + atomicAdd(&a.gcur[r * MAXB + i], len)) : 0;
  }
  __syncthreads();
  unsigned* sg = a.stage[r];
  for (int i = threadIdx.x; i < cnt; i += 256) {
    int dg = dig8[i];
    sg[runb[dg] + (i - pref[dg])] = stag[i];
  }
}

__global__ __launch_bounds__(256)
void bbuild(BArgs a) {
  __shared__ int hist[128];
  __shared__ int pref[129];
  __shared__ int cur[128];
  __shared__ int ps[256];
  __shared__ int loc[8192];
  int r = 0;
#pragma unroll
  for (int i = 1; i < 6; ++i) if ((int)blockIdx.x >= a.bpre[i]) r = i;
  int b = (int)blockIdx.x - a.bpre[r];
  int cnt = a.bcnt[r * MAXB + b];
  int base = a.bbase[r * MAXB + b];
  int n0 = b << 7;
  int N = a.N[r];
  for (int i = threadIdx.x; i < 128; i += 256) hist[i] = 0;
  __syncthreads();
  const unsigned* sg = a.stage[r] + base;
  for (int i = threadIdx.x; i < cnt; i += 256) atomicAdd(&hist[sg[i] & 127], 1);
  __syncthreads();
  {
    int t = threadIdx.x;
    int v = (t < 128) ? hist[t] : 0;
    ps[t] = v;
    __syncthreads();
    for (int d = 1; d < 128; d <<= 1) {
      int x = (t >= d) ? ps[t - d] : 0;
      __syncthreads();
      ps[t] += x;
      __syncthreads();
    }
    if (t < 128) { pref[t] = ps[t] - v; cur[t] = ps[t] - v; }
    if (t == 127) pref[128] = ps[127];
  }
  __syncthreads();
  for (int i = threadIdx.x; i < cnt; i += 256) {
    unsigned v = sg[i];
    int pos = atomicAdd(&cur[v & 127], 1);
    loc[pos] = (int)(v >> 7);
  }
  __syncthreads();
  int* csr = a.csr[r];
  for (int i = threadIdx.x; i < cnt; i += 256) csr[base + i] = loc[i];
  if (threadIdx.x < 128) {
    int n = n0 + threadIdx.x;
    if (n < N) {
      a.st[r][n] = base + pref[threadIdx.x];
      a.en[r][n] = base + pref[threadIdx.x + 1];
    }
  }
}

// ---------------------------------------------------------------------------
// prep: fold W@ar -> war, W@al -> wal; W -> bf16 MFMA-fragment order; biases.
// Block 10 zeroes the CSR counters/cursors.
// ---------------------------------------------------------------------------
__global__ __launch_bounds__(256)
void prep(const float* __restrict__ W1, const float* __restrict__ al1,
          const float* __restrict__ ar1, const float* __restrict__ b1,
          const float* __restrict__ W2, const float* __restrict__ al2,
          const float* __restrict__ ar2, const float* __restrict__ b2,
          unsigned short* __restrict__ Wz1, unsigned short* __restrict__ Wz2,
          float* __restrict__ war1, float* __restrict__ wal1,
          float* __restrict__ war2, float* __restrict__ wal2,
          float* __restrict__ bcomb, int* __restrict__ zro, int zn)
{
  int b = blockIdx.x, t = threadIdx.x;
  if (b < 6) {
    const float* W = W1 + b * 16384;
    unsigned short* Wz = Wz1 + b * 16384;
    for (int i = t; i < 16384; i += 256) {
      int j = i & 7, c = (i >> 3) & 127, kc = i >> 10;
      Wz[i] = f2bu(W[(kc * 8 + j) * 128 + c]);
    }
    for (int i = t; i < 512; i += 256) {
      int k = i >> 2, h = i & 3;
      float sr = 0.f, sl = 0.f;
      for (int f = 0; f < 32; ++f) {
        float w = W[k * 128 + h * 32 + f];
        sr += w * ar1[b * 128 + h * 32 + f];
        sl += w * al1[b * 128 + h * 32 + f];
      }
      war1[b * 512 + i] = sr;
      wal1[b * 512 + i] = sl;
    }
  } else if (b < 9) {
    int w = (b == 6) ? 0 : (b == 7) ? 5 : 4;
    const float* W = W2 + w * 8192;
    unsigned short* Wz = Wz2 + (b - 6) * 8192;
    for (int i = t; i < 8192; i += 256) {
      int j = i & 7, c = (i >> 3) & 63, kc = i >> 9;
      Wz[i] = f2bu(W[(kc * 8 + j) * 64 + c]);
    }
    if (t < 128) {
      float sr = 0.f, sl = 0.f;
      for (int f = 0; f < 64; ++f) {
        float x = W[t * 64 + f];
        sr += x * ar2[w * 64 + f];
        sl += x * al2[w * 64 + f];
      }
      war2[(b - 6) * 128 + t] = sr;
      wal2[(b - 6) * 128 + t] = sl;
    }
  } else if (b == 9) {
    if (t < 128) {
      bcomb[t]       = b1[128 + t] + b1[256 + t] + b1[384 + t]; // user
      bcomb[128 + t] = b1[t] + b1[640 + t];                     // artist
      bcomb[256 + t] = b1[512 + t];                             // tag
    } else if (t < 192) {
      int x = t - 128;
      bcomb[384 + x] = b2[x] + b2[320 + x];                     // h2 artist
      bcomb[448 + x] = b2[256 + x];                             // h2 tag
    }
  } else {
    for (int i = t; i < zn; i += 256) zro[i] = 0;   // bcnt + gcur
  }
}

// ---------------------------------------------------------------------------
// MFMA projection GEMM, batched over relations.
// ---------------------------------------------------------------------------
struct GemmM {
  const float* A[6];
  const unsigned short* Wz[6];
  unsigned short* Z[6];
  int N[6];
  int pre[6];
};

template<int KOUT>
__global__ __launch_bounds__(256)
void gemm_mfma(GemmM g)
{
  constexpr int NCT = KOUT / 64;
  int r = 0;
#pragma unroll
  for (int i = 1; i < 6; ++i) if ((int)blockIdx.x >= g.pre[i]) r = i;
  const float* A = g.A[r];
  const short8v* Wp = (const short8v*)g.Wz[r];
  unsigned short* Z = g.Z[r];
  const int N = g.N[r];
  const int row0 = (blockIdx.x - g.pre[r]) * 64;

  __shared__ short8v a_lds[64 * 16];
  for (int i = threadIdx.x; i < 64 * 16; i += 256) {
    int row = i >> 4, c8 = i & 15;
    int grow = row0 + row;
    short8v v;
    if (grow < N) {
      const float4* ap = (const float4*)(A + (size_t)grow * 128 + c8 * 8);
      float4 x0 = ap[0], x1 = ap[1];
      v[0] = (short)f2bu(x0.x); v[1] = (short)f2bu(x0.y);
      v[2] = (short)f2bu(x0.z); v[3] = (short)f2bu(x0.w);
      v[4] = (short)f2bu(x1.x); v[5] = (short)f2bu(x1.y);
      v[6] = (short)f2bu(x1.z); v[7] = (short)f2bu(x1.w);
    } else {
      v = short8v{0, 0, 0, 0, 0, 0, 0, 0};
    }
    a_lds[row * 16 + (c8 ^ (row & 7))] = v;
  }
  __syncthreads();

  const int wv = threadIdx.x >> 6;
  const int lane = threadIdx.x & 63;
  const int lrow = lane & 15, lkg = lane >> 4;

  f32x4 acc[4][NCT];
#pragma unroll
  for (int rt = 0; rt < 4; ++rt)
#pragma unroll
    for (int c = 0; c < NCT; ++c) acc[rt][c] = f32x4{0.f, 0.f, 0.f, 0.f};

#pragma unroll
  for (int ks = 0; ks < 4; ++ks) {
    const int kc = ks * 4 + lkg;
    short8v bfr[NCT];
#pragma unroll
    for (int c = 0; c < NCT; ++c)
      bfr[c] = Wp[kc * KOUT + (wv * NCT + c) * 16 + lrow];
#pragma unroll
    for (int rt = 0; rt < 4; ++rt) {
      int row = rt * 16 + lrow;
      short8v afr = a_lds[row * 16 + (kc ^ (row & 7))];
#pragma unroll
      for (int c = 0; c < NCT; ++c)
        acc[rt][c] = __builtin_amdgcn_mfma_f32_16x16x32_bf16(afr, bfr[c], acc[rt][c], 0, 0, 0);
    }
  }

#pragma unroll
  for (int rt = 0; rt < 4; ++rt)
#pragma unroll
    for (int c = 0; c < NCT; ++c) {
      int col = (wv * NCT + c) * 16 + lrow;
#pragma unroll
      for (int q = 0; q < 4; ++q) {
        int grow = row0 + rt * 16 + lkg * 4 + q;
        if (grow < N) Z[(size_t)grow * KOUT + col] = f2bu(acc[rt][c][q]);
      }
    }
}

// ---------------------------------------------------------------------------
// node_dots: all el/er columns per node type; no cross-lane ops.
// ---------------------------------------------------------------------------
struct DotsB {
  const float* X[3];
  const float* M[3][6];
  float* out[3][6];
  int NG[3];
  int N[3];
  int pre[3];
};

template<int H, int MAXG>
__global__ __launch_bounds__(256)
void node_dots(DotsB g)
{
  int task = 0;
#pragma unroll
  for (int i = 1; i < 3; ++i) if ((int)blockIdx.x >= g.pre[i]) task = i;
  const int NG = g.NG[task];
  const int C = NG * H;
  const float* X = g.X[task];
  const int N = g.N[task];
  const int n0 = (blockIdx.x - g.pre[task]) * 64;

  __shared__ float Xs[64 * 129];
  __shared__ float Ms[128 * MAXG * H];
  for (int i = threadIdx.x; i < 128 * C; i += 256) {
    int k = i / C, c = i - k * C;
    int grp = c / H, h = c - grp * H;
    Ms[i] = g.M[task][grp][k * H + h];
  }
  for (int i = threadIdx.x; i < 64 * 32; i += 256) {
    int row = i >> 5, kk = i & 31;
    int n = n0 + row;
    float4 v;
    if (n < N) v = ((const float4*)(X + (size_t)n * 128))[kk];
    else { v.x = 0.f; v.y = 0.f; v.z = 0.f; v.w = 0.f; }
    float* xp = &Xs[row * 129 + kk * 4];
    xp[0] = v.x; xp[1] = v.y; xp[2] = v.z; xp[3] = v.w;
  }
  __syncthreads();

  const int lane = threadIdx.x & 63;
  const int wv = threadIdx.x >> 6;
  const int n = n0 + lane;
  const float* xp = &Xs[lane * 129];
  for (int c = wv; c < C; c += 4) {
    int grp = c / H, h = c - grp * H;
    const float* mp = &Ms[c];
    float a0 = 0.f, a1 = 0.f;
#pragma unroll 8
    for (int k = 0; k < 128; k += 2) {
      a0 = fmaf(xp[k],     mp[k * C],       a0);
      a1 = fmaf(xp[k + 1], mp[(k + 1) * C], a1);
    }
    if (n < N) g.out[task][grp][(size_t)n * H + h] = a0 + a1;
  }
}

// ---------------------------------------------------------------------------
// Batched multi-relation CSR aggregation: ALL dst types of a layer in ONE
// launch (block -> task prefix). Per-edge math identical to round 12; NR is
// a runtime loop (kernel-arg pointer loads are SGPR-safe, accs stay static).
// ---------------------------------------------------------------------------
struct AggT {
  const int* st;
  const int* en;
  const int* csr;
  const float* el;
  const float* er;
  const unsigned short* zs;
};
struct AggB {
  AggT t[3][3];              // [task][rel]
  const float* bias[3];
  float* out[3];
  unsigned short* outb[3];
  int NR[3];
  int Nd[3];
  int pre[3];
};

template<int H, int CPL, bool BOUT>
__global__ __launch_bounds__(256)
void agg_batch(AggB a)
{
  constexpr int ELEMS = 64 * CPL;
  constexpr int F = ELEMS / H;        // cols per head
  constexpr int LPH = F / CPL;        // lanes per head
  int task = 0;
#pragma unroll
  for (int i = 1; i < 3; ++i) if ((int)blockIdx.x >= a.pre[i]) task = i;
  const int lane = threadIdx.x & 63;
  const int n = (blockIdx.x - a.pre[task]) * 4 + (threadIdx.x >> 6);
  if (n >= a.Nd[task]) return;
  const int hl = lane / LPH;          // this lane's head
  const int NR = a.NR[task];

  float vout[CPL];
#pragma unroll
  for (int j = 0; j < CPL; ++j) vout[j] = a.bias[task][CPL * lane + j];

  for (int r = 0; r < NR; ++r) {
    const AggT tt = a.t[task][r];
    const float erl = tt.er[(size_t)n * H + hl];
    const float* el = tt.el;
    const int* csr = tt.csr;
    const unsigned* zp2 = (const unsigned*)tt.zs;
    const unsigned short* zp1 = tt.zs;
    float accA[CPL], accB[CPL];
#pragma unroll
    for (int j = 0; j < CPL; ++j) { accA[j] = 0.f; accB[j] = 0.f; }
    float denA = 0.f, denB = 0.f;
    const int e0 = tt.st[n], e1 = tt.en[n];
    for (int eb = e0; eb < e1; eb += 64) {
      int sv = (eb + lane < e1) ? csr[eb + lane] : 0;
      int m = min(64, e1 - eb);
      int j = 0;
      for (; j + 4 <= m; j += 4) {
        int s0 = __shfl(sv, j, 64),     s1 = __shfl(sv, j + 1, 64);
        int s2 = __shfl(sv, j + 2, 64), s3 = __shfl(sv, j + 3, 64);
        float q0 = el[s0 * H + hl], q1 = el[s1 * H + hl];
        float q2 = el[s2 * H + hl], q3 = el[s3 * H + hl];
        if (CPL == 2) {
          unsigned z0 = zp2[(size_t)s0 * 64 + lane];
          unsigned z1 = zp2[(size_t)s1 * 64 + lane];
          unsigned z2 = zp2[(size_t)s2 * 64 + lane];
          unsigned z3 = zp2[(size_t)s3 * 64 + lane];
          float v0 = q0 + erl; v0 = v0 > 0.f ? v0 : 0.2f * v0;
          float v1 = q1 + erl; v1 = v1 > 0.f ? v1 : 0.2f * v1;
          float v2 = q2 + erl; v2 = v2 > 0.f ? v2 : 0.2f * v2;
          float v3 = q3 + erl; v3 = v3 > 0.f ? v3 : 0.2f * v3;
          float ex0 = __expf(v0), ex1 = __expf(v1);
          float ex2 = __expf(v2), ex3 = __expf(v3);
          denA += ex0 + ex2; denB += ex1 + ex3;
          accA[0] += ex0 * blo(z0); accA[CPL - 1] += ex0 * bhi(z0);
          accB[0] += ex1 * blo(z1); accB[CPL - 1] += ex1 * bhi(z1);
          accA[0] += ex2 * blo(z2); accA[CPL - 1] += ex2 * bhi(z2);
          accB[0] += ex3 * blo(z3); accB[CPL - 1] += ex3 * bhi(z3);
        } else {
          unsigned z0 = zp1[(size_t)s0 * 64 + lane];
          unsigned z1 = zp1[(size_t)s1 * 64 + lane];
          unsigned z2 = zp1[(size_t)s2 * 64 + lane];
          unsigned z3 = zp1[(size_t)s3 * 64 + lane];
          float v0 = q0 + erl; v0 = v0 > 0.f ? v0 : 0.2f * v0;
          float v1 = q1 + erl; v1 = v1 > 0.f ? v1 : 0.2f * v1;
          float v2 = q2 + erl; v2 = v2 > 0.f ? v2 : 0.2f * v2;
          float v3 = q3 + erl; v3 = v3 > 0.f ? v3 : 0.2f * v3;
          float ex0 = __expf(v0), ex1 = __expf(v1);
          float ex2 = __expf(v2), ex3 = __expf(v3);
          denA += ex0 + ex2; denB += ex1 + ex3;
          accA[0] += ex0 * blo(z0);   // z in low 16 bits; blo() does the <<16
          accB[0] += ex1 * blo(z1);
          accA[0] += ex2 * blo(z2);
          accB[0] += ex3 * blo(z3);
        }
      }
      for (; j < m; ++j) {
        int s0 = __shfl(sv, j, 64);
        float q0 = el[s0 * H + hl];
        float v0 = q0 + erl; v0 = v0 > 0.f ? v0 : 0.2f * v0;
        float ex0 = __expf(v0);
        denA += ex0;
        if (CPL == 2) {
          unsigned z0 = zp2[(size_t)s0 * 64 + lane];
          accA[0] += ex0 * blo(z0); accA[CPL - 1] += ex0 * bhi(z0);
        } else {
          unsigned z0 = zp1[(size_t)s0 * 64 + lane];
          accA[0] += ex0 * blo(z0);
        }
      }
    }
    float dd = denA + denB;   // full per-head denom (every lane has it)
    if (dd > 0.f) {
#pragma unroll
      for (int j = 0; j < CPL; ++j) vout[j] += (accA[j] + accB[j]) / dd;
    }
  }
  if (CPL == 2) {
    float2 o; o.x = vout[0]; o.y = vout[CPL - 1];
    ((float2*)(a.out[task] + (size_t)n * ELEMS))[lane] = o;
  } else {
    if (BOUT) a.outb[task][(size_t)n * ELEMS + lane] = f2bu(vout[0]);
    else      a.out[task][(size_t)n * ELEMS + lane] = vout[0];
  }
}

// ---------------------------------------------------------------------------
// Predictor: bf16 tables, 4 lanes per edge, 4x16B loads/thread, 2-hop reduce.
// ---------------------------------------------------------------------------
__global__ __launch_bounds__(256)
void pred_dot(const unsigned short* __restrict__ h2a,
              const unsigned short* __restrict__ h2t,
              const int* __restrict__ ps, const int* __restrict__ pd,
              const int* __restrict__ ns, const int* __restrict__ nd,
              float* __restrict__ out, int Ep, int En)
{
  int t = blockIdx.x * 256 + threadIdx.x;
  int e = t >> 2, q = t & 3;
  if (e >= Ep + En) return;
  int s, d;
  if (e < Ep) { s = ps[e]; d = pd[e]; }
  else        { s = ns[e - Ep]; d = nd[e - Ep]; }
  const uint4* pa = (const uint4*)(h2a + (size_t)s * 64);
  const uint4* pb = (const uint4*)(h2t + (size_t)d * 64);
  uint4 a0 = pa[2 * q], a1 = pa[2 * q + 1];
  uint4 b0 = pb[2 * q], b1 = pb[2 * q + 1];
  float v = blo(a0.x) * blo(b0.x) + bhi(a0.x) * bhi(b0.x)
          + blo(a0.y) * blo(b0.y) + bhi(a0.y) * bhi(b0.y)
          + blo(a0.z) * blo(b0.z) + bhi(a0.z) * bhi(b0.z)
          + blo(a0.w) * blo(b0.w) + bhi(a0.w) * bhi(b0.w)
          + blo(a1.x) * blo(b1.x) + bhi(a1.x) * bhi(b1.x)
          + blo(a1.y) * blo(b1.y) + bhi(a1.y) * bhi(b1.y)
          + blo(a1.z) * blo(b1.z) + bhi(a1.z) * bhi(b1.z)
          + blo(a1.w) * blo(b1.w) + bhi(a1.w) * bhi(b1.w);
  v += __shfl_xor(v, 2, 64);
  v += __shfl_xor(v, 1, 64);
  if (q == 0) out[e] = v;
}

// ---------------------------------------------------------------------------
extern "C" void kernel_launch(void* const* d_in, const int* in_sizes, int n_in,
                              void* d_out, int out_size, void* d_ws, size_t ws_size,
                              hipStream_t stream)
{
  (void)n_in; (void)out_size; (void)ws_size;
  const float* fUser = (const float*)d_in[0];
  const float* fArt  = (const float*)d_in[1];
  const float* fTag  = (const float*)d_in[2];
  const float* W1  = (const float*)d_in[3];
  const float* al1 = (const float*)d_in[4];
  const float* ar1 = (const float*)d_in[5];
  const float* b1  = (const float*)d_in[6];
  const float* W2  = (const float*)d_in[7];
  const float* al2 = (const float*)d_in[8];
  const float* ar2 = (const float*)d_in[9];
  const float* b2  = (const float*)d_in[10];
  const int* ix[14];
  for (int i = 0; i < 14; ++i) ix[i] = (const int*)d_in[11 + i];

  const int NU = in_sizes[0] / 128;
  const int NA = in_sizes[1] / 128;
  const int NT = in_sizes[2] / 128;
  const int E  = in_sizes[11];
  const int EN = in_sizes[23];

  char* p = (char*)d_ws;
  auto alloc = [&](size_t bytes) -> char* {
    char* r = p; p += (bytes + 255) & ~(size_t)255; return r;
  };

  const int dN1[6] = {NA, NU, NU, NU, NT, NA};
  const int sN1[6] = {NU, NA, NU, NU, NA, NT};
  const int sN2[3] = {NU, NT, NA};

  // ---- CSR counters + cursors (zeroed by prep block 10, contiguous) ----
  BArgs ba;
  ba.bcnt = (int*)alloc(6 * MAXB * 4);
  ba.gcur = (int*)alloc(6 * MAXB * 4);   // contiguous after bcnt (both 256B-mult)
  const int zn = 2 * 6 * MAXB;

  // ---- other scratch ----
  ba.bbase = (int*)alloc(6 * MAXB * 4);
  int bpre = 0;
  for (int r = 0; r < 6; ++r) {
    ba.src[r] = ix[2 * r];
    ba.dst[r] = ix[2 * r + 1];
    ba.N[r] = dN1[r];
    ba.nb[r] = (dN1[r] + 127) >> 7;
    ba.bpre[r] = bpre;
    bpre += ba.nb[r];
    ba.stage[r] = (unsigned*)alloc((size_t)E * 4);
    ba.csr[r]   = (int*)alloc((size_t)E * 4);
    ba.st[r]    = (int*)alloc((size_t)dN1[r] * 4);
    ba.en[r]    = (int*)alloc((size_t)dN1[r] * 4);
  }
  unsigned short* Wz1 = (unsigned short*)alloc(6 * 16384 * 2);
  unsigned short* Wz2 = (unsigned short*)alloc(3 * 8192 * 2);
  float* war1  = (float*)alloc(6 * 512 * 4);
  float* wal1  = (float*)alloc(6 * 512 * 4);
  float* war2  = (float*)alloc(3 * 128 * 4);
  float* wal2  = (float*)alloc(3 * 128 * 4);
  float* bcomb = (float*)alloc(512 * 4);
  unsigned short* zs1[6]; float* el1[6]; float* er1[6];
  for (int r = 0; r < 6; ++r) {
    zs1[r] = (unsigned short*)alloc((size_t)sN1[r] * 128 * 2);
    el1[r] = (float*)alloc((size_t)sN1[r] * 4 * 4);
    er1[r] = (float*)alloc((size_t)dN1[r] * 4 * 4);
  }
  float* hU  = (float*)alloc((size_t)NU * 128 * 4);
  float* hA  = (float*)alloc((size_t)NA * 128 * 4);
  float* hT  = (float*)alloc((size_t)NT * 128 * 4);
  unsigned short* zs2[3]; float* el2[3]; float* er2[3];
  const int dN2[3] = {NA, NA, NT};
  for (int r = 0; r < 3; ++r) {
    zs2[r] = (unsigned short*)alloc((size_t)sN2[r] * 64 * 2);
    el2[r] = (float*)alloc((size_t)sN2[r] * 4);
    er2[r] = (float*)alloc((size_t)dN2[r] * 4);
  }
  unsigned short* h2a = (unsigned short*)alloc((size_t)NA * 64 * 2);
  unsigned short* h2t = (unsigned short*)alloc((size_t)NT * 64 * 2);

  // ---- prep (incl. counter zeroing) + bucketed CSR build ----
  prep<<<11, 256, 0, stream>>>(W1, al1, ar1, b1, W2, al2, ar2, b2,
                               Wz1, Wz2, war1, wal1, war2, wal2, bcomb,
                               ba.bcnt, zn);
  const int EBK = (E + BKE - 1) / BKE;
  bhist<<<6 * EBK, 256, 0, stream>>>(ba, E, EBK);
  bscan<<<6, 256, 0, stream>>>(ba);
  bscatter<<<6 * EBK, 256, 0, stream>>>(ba, E, EBK);
  bbuild<<<bpre, 256, 0, stream>>>(ba);

  // ---- layer 1: MFMA projections (Z bf16) ----
  {
    GemmM g;
    const float* sF1[6] = {fUser, fArt, fUser, fUser, fArt, fTag};
    int pre = 0;
    for (int r = 0; r < 6; ++r) {
      g.A[r] = sF1[r];
      g.Wz[r] = Wz1 + (size_t)r * 16384;
      g.Z[r] = zs1[r];
      g.N[r] = sN1[r];
      g.pre[r] = pre;
      pre += (sN1[r] + 63) / 64;
    }
    gemm_mfma<128><<<pre, 256, 0, stream>>>(g);
  }
  // ---- layer 1: all el/er dots ----
  {
    DotsB g = {};
    g.X[0] = fUser; g.N[0] = NU; g.NG[0] = 6;
    g.M[0][0] = wal1 + 0 * 512; g.out[0][0] = el1[0];
    g.M[0][1] = wal1 + 2 * 512; g.out[0][1] = el1[2];
    g.M[0][2] = wal1 + 3 * 512; g.out[0][2] = el1[3];
    g.M[0][3] = war1 + 1 * 512; g.out[0][3] = er1[1];
    g.M[0][4] = war1 + 2 * 512; g.out[0][4] = er1[2];
    g.M[0][5] = war1 + 3 * 512; g.out[0][5] = er1[3];
    g.X[1] = fArt; g.N[1] = NA; g.NG[1] = 4;
    g.M[1][0] = wal1 + 1 * 512; g.out[1][0] = el1[1];
    g.M[1][1] = wal1 + 4 * 512; g.out[1][1] = el1[4];
    g.M[1][2] = war1 + 0 * 512; g.out[1][2] = er1[0];
    g.M[1][3] = war1 + 5 * 512; g.out[1][3] = er1[5];
    g.X[2] = fTag; g.N[2] = NT; g.NG[2] = 2;
    g.M[2][0] = wal1 + 5 * 512; g.out[2][0] = el1[5];
    g.M[2][1] = war1 + 4 * 512; g.out[2][1] = er1[4];
    g.pre[0] = 0;
    g.pre[1] = (NU + 63) / 64;
    g.pre[2] = g.pre[1] + (NA + 63) / 64;
    int total = g.pre[2] + (NT + 63) / 64;
    node_dots<4, 6><<<total, 256, 0, stream>>>(g);
  }

  // ---- layer 1: ALL dst-type aggregations in ONE launch ----
  {
    AggB a = {};
    // task 0: artist (rels 0 ua, 5 ta)
    a.t[0][0] = {ba.st[0], ba.en[0], ba.csr[0], el1[0], er1[0], zs1[0]};
    a.t[0][1] = {ba.st[5], ba.en[5], ba.csr[5], el1[5], er1[5], zs1[5]};
    a.bias[0] = bcomb + 128; a.out[0] = hA; a.NR[0] = 2; a.Nd[0] = NA;
    // task 1: user (rels 1 au, 2 uu0, 3 uu1)
    a.t[1][0] = {ba.st[1], ba.en[1], ba.csr[1], el1[1], er1[1], zs1[1]};
    a.t[1][1] = {ba.st[2], ba.en[2], ba.csr[2], el1[2], er1[2], zs1[2]};
    a.t[1][2] = {ba.st[3], ba.en[3], ba.csr[3], el1[3], er1[3], zs1[3]};
    a.bias[1] = bcomb; a.out[1] = hU; a.NR[1] = 3; a.Nd[1] = NU;
    // task 2: tag (rel 4 at)
    a.t[2][0] = {ba.st[4], ba.en[4], ba.csr[4], el1[4], er1[4], zs1[4]};
    a.bias[2] = bcomb + 256; a.out[2] = hT; a.NR[2] = 1; a.Nd[2] = NT;
    a.pre[0] = 0;
    a.pre[1] = (NA + 3) / 4;
    a.pre[2] = a.pre[1] + (NU + 3) / 4;
    int total = a.pre[2] + (NT + 3) / 4;
    agg_batch<4, 2, false><<<total, 256, 0, stream>>>(a);
  }

  // ---- layer 2: MFMA projections ----
  {
    GemmM g;
    const float* sF2[3] = {hU, hT, hA};
    int pre = 0;
    for (int r = 0; r < 3; ++r) {
      g.A[r] = sF2[r];
      g.Wz[r] = Wz2 + (size_t)r * 8192;
      g.Z[r] = zs2[r];
      g.N[r] = sN2[r];
      g.pre[r] = pre;
      pre += (sN2[r] + 63) / 64;
    }
    for (int r = 3; r < 6; ++r) {
      g.A[r] = nullptr; g.Wz[r] = nullptr; g.Z[r] = nullptr;
      g.N[r] = 0; g.pre[r] = 0x7fffffff;
    }
    gemm_mfma<64><<<pre, 256, 0, stream>>>(g);
  }
  // ---- layer 2: el/er dots ----
  {
    DotsB g = {};
    g.X[0] = hA; g.N[0] = NA; g.NG[0] = 3;
    g.M[0][0] = wal2 + 2 * 128; g.out[0][0] = el2[2];
    g.M[0][1] = war2 + 0 * 128; g.out[0][1] = er2[0];
    g.M[0][2] = war2 + 1 * 128; g.out[0][2] = er2[1];
    g.X[1] = hU; g.N[1] = NU; g.NG[1] = 1;
    g.M[1][0] = wal2 + 0 * 128; g.out[1][0] = el2[0];
    g.X[2] = hT; g.N[2] = NT; g.NG[2] = 2;
    g.M[2][0] = wal2 + 1 * 128; g.out[2][0] = el2[1];
    g.M[2][1] = war2 + 2 * 128; g.out[2][1] = er2[2];
    g.pre[0] = 0;
    g.pre[1] = (NA + 63) / 64;
    g.pre[2] = g.pre[1] + (NU + 63) / 64;
    int total = g.pre[2] + (NT + 63) / 64;
    node_dots<1, 3><<<total, 256, 0, stream>>>(g);
  }

  // ---- layer 2: both aggregations in ONE launch (bf16 outputs) ----
  {
    AggB a = {};
    // task 0: h2_artist (rels ua csr0, ta csr5)
    a.t[0][0] = {ba.st[0], ba.en[0], ba.csr[0], el2[0], er2[0], zs2[0]};
    a.t[0][1] = {ba.st[5], ba.en[5], ba.csr[5], el2[1], er2[1], zs2[1]};
    a.bias[0] = bcomb + 384; a.outb[0] = h2a; a.NR[0] = 2; a.Nd[0] = NA;
    // task 1: h2_tag (rel at csr4)
    a.t[1][0] = {ba.st[4], ba.en[4], ba.csr[4], el2[2], er2[2], zs2[2]};
    a.bias[1] = bcomb + 448; a.outb[1] = h2t; a.NR[1] = 1; a.Nd[1] = NT;
    a.pre[0] = 0;
    a.pre[1] = (NA + 3) / 4;
    a.pre[2] = 0x7fffffff;
    int total = a.pre[1] + (NT + 3) / 4;
    agg_batch<1, 1, true><<<total, 256, 0, stream>>>(a);
  }

  // ---- predictor ----
  pred_dot<<<(int)(((size_t)(E + EN) * 4 + 255) / 256), 256, 0, stream>>>(
      h2a, h2t, ix[8], ix[9], ix[12], ix[13], (float*)d_out, E, EN);
}